// Round 10
// baseline (379.172 us; speedup 1.0000x reference)
//
#include <hip/hip_runtime.h>

#define SEQ   2048
#define EMB   2048
#define NHEAD 16
#define HDIM  128
#define ROWSM 4096  // B*SEQ

typedef float  f32x4   __attribute__((ext_vector_type(4)));
typedef float  f32x16  __attribute__((ext_vector_type(16)));
typedef __bf16 bf16x8  __attribute__((ext_vector_type(8)));

__device__ __forceinline__ unsigned short f2bf(float f) {
  union { float f; unsigned int u; } v; v.f = f;
  return (unsigned short)((v.u + 0x7fffu + ((v.u >> 16) & 1u)) >> 16);
}
__device__ __forceinline__ unsigned int pk2(float a, float b) {
  return (unsigned int)f2bf(a) | ((unsigned int)f2bf(b) << 16);
}

__device__ __forceinline__ void gload16(const void* g, void* l) {
  __builtin_amdgcn_global_load_lds(
      (__attribute__((address_space(1))) const unsigned int*)g,
      (__attribute__((address_space(3))) unsigned int*)l,
      16, 0, 0);
}

// fp32 -> bf16 bulk convert, 4 elems/thread
__global__ void cvt_bf16(const float* __restrict__ in,
                         unsigned short* __restrict__ out, int n4) {
  int i = blockIdx.x * 256 + threadIdx.x;
  if (i >= n4) return;
  float4 v = ((const float4*)in)[i];
  ushort4 o;
  o.x = f2bf(v.x); o.y = f2bf(v.y); o.z = f2bf(v.z); o.w = f2bf(v.w);
  ((ushort4*)out)[i] = o;
}

// three same-size fp32->bf16 converts in one launch (z selects)
__global__ void cvt_bf16_3(const float* __restrict__ i0, const float* __restrict__ i1,
                           const float* __restrict__ i2, unsigned short* __restrict__ o0,
                           unsigned short* __restrict__ o1, unsigned short* __restrict__ o2,
                           int n4) {
  const float* in = (blockIdx.z == 0) ? i0 : (blockIdx.z == 1) ? i1 : i2;
  unsigned short* out = (blockIdx.z == 0) ? o0 : (blockIdx.z == 1) ? o1 : o2;
  int i = blockIdx.x * 256 + threadIdx.x;
  if (i >= n4) return;
  float4 v = ((const float4*)in)[i];
  ushort4 o;
  o.x = f2bf(v.x); o.y = f2bf(v.y); o.z = f2bf(v.z); o.w = f2bf(v.w);
  ((ushort4*)out)[i] = o;
}

// Phase-split GEMM: C = A @ B^T. BM=256, BN=128, BK=64, 8 waves (512 thr),
// per-wave output 128x32. Two phases per K-tile; raw s_barrier (NO
// __syncthreads -> no forced vmcnt(0) drain); stage next tile's A in phase 0,
// B in phase 1; single counted drain vmcnt(0) at the K-tile boundary so loads
// span ~a full K-tile of compute (T3/T4). T2 st_16x32 swizzle both-sides
// (pre-swizzled gload_lds source + swizzled ds_read). T5 setprio round MFMA.
// z selects among 3 B matrices / output slices (QKV); z=0 single for P.
template <int STORE_F32>
__global__ __launch_bounds__(512, 1) void gemm_big(
    const unsigned short* __restrict__ A,
    const unsigned short* __restrict__ B0, const unsigned short* __restrict__ B1,
    const unsigned short* __restrict__ B2,
    void* __restrict__ Cbase, const float* __restrict__ bias, int K) {
  __shared__ __align__(16) unsigned short Abuf[2][256 * 64];  // 64KB
  __shared__ __align__(16) unsigned short Bbuf[2][128 * 64];  // 32KB

  const unsigned short* Bm = (blockIdx.z == 0) ? B0 : (blockIdx.z == 1) ? B1 : B2;

  const int tid  = threadIdx.x;
  const int lane = tid & 63;
  const int w    = tid >> 6;        // 0..7
  const int lg   = lane >> 4;       // 0..3
  const int lc   = lane & 15;
  const int m0 = blockIdx.y * 256;
  const int n0 = blockIdx.x * 128;
  const int wm = (w >> 2) * 128;    // wave m-offset: 0 / 128
  const int wn = (w & 3) * 32;      // wave n-offset: 0..96

  // stage: chunk = 1KB = 8 rows x 128B; lane l -> row c*8+(l>>3), slot l&7.
  // source slot pre-swizzled: s ^ ((r&4)>>1)  (st_16x32 inverse == forward)
  auto stageA = [&](int buf, int k0) {
#pragma unroll
    for (int ii = 0; ii < 4; ++ii) {
      int c = w * 4 + ii;                       // 32 chunks
      int r = c * 8 + (lane >> 3);
      int s = (lane & 7) ^ ((r & 4) >> 1);
      gload16(A + (size_t)(m0 + r) * K + k0 + s * 8, (char*)&Abuf[buf][0] + c * 1024);
    }
  };
  auto stageB = [&](int buf, int k0) {
#pragma unroll
    for (int ii = 0; ii < 2; ++ii) {
      int c = w * 2 + ii;                       // 16 chunks
      int r = c * 8 + (lane >> 3);
      int s = (lane & 7) ^ ((r & 4) >> 1);
      gload16(Bm + (size_t)(n0 + r) * K + k0 + s * 8, (char*)&Bbuf[buf][0] + c * 1024);
    }
  };

  f32x4 acc[8][2] = {};

  // prologue: tile 0 fully staged
  stageA(0, 0);
  stageB(0, 0);
  asm volatile("s_waitcnt vmcnt(0)" ::: "memory");
  __builtin_amdgcn_s_barrier();

  const int NT = K / 64;
  for (int t = 0; t < NT; ++t) {
    const int buf = t & 1;
    const char* ab = (const char*)&Abuf[buf][0];
    const char* bb = (const char*)&Bbuf[buf][0];
    const int k0n = (t + 1) * 64;
    const bool pf = (t + 1 < NT);

    // ---------- phase 0: m-frags 0..3 ----------
    if (pf) stageA(buf ^ 1, k0n);
    bf16x8 bfr[2][2], afr[4][2];
#pragma unroll
    for (int ni = 0; ni < 2; ++ni)
#pragma unroll
      for (int kk = 0; kk < 2; ++kk) {
        int row = wn + ni * 16 + lc;
        int o = kk * 4 + lg;
        bfr[ni][kk] = *(const bf16x8*)(bb + row * 128 + ((o ^ ((row & 4) >> 1)) << 4));
      }
#pragma unroll
    for (int mi = 0; mi < 4; ++mi)
#pragma unroll
      for (int kk = 0; kk < 2; ++kk) {
        int row = wm + mi * 16 + lc;
        int o = kk * 4 + lg;
        afr[mi][kk] = *(const bf16x8*)(ab + row * 128 + ((o ^ ((row & 4) >> 1)) << 4));
      }
    __builtin_amdgcn_s_barrier();
    __builtin_amdgcn_s_setprio(1);
#pragma unroll
    for (int mi = 0; mi < 4; ++mi)
#pragma unroll
      for (int ni = 0; ni < 2; ++ni)
#pragma unroll
        for (int kk = 0; kk < 2; ++kk)
          acc[mi][ni] = __builtin_amdgcn_mfma_f32_16x16x32_bf16(
              afr[mi][kk], bfr[ni][kk], acc[mi][ni], 0, 0, 0);
    __builtin_amdgcn_s_setprio(0);
    __builtin_amdgcn_s_barrier();

    // ---------- phase 1: m-frags 4..7 ----------
    if (pf) stageB(buf ^ 1, k0n);
#pragma unroll
    for (int mi = 0; mi < 4; ++mi)
#pragma unroll
      for (int kk = 0; kk < 2; ++kk) {
        int row = wm + 64 + mi * 16 + lc;
        int o = kk * 4 + lg;
        afr[mi][kk] = *(const bf16x8*)(ab + row * 128 + ((o ^ ((row & 4) >> 1)) << 4));
      }
    __builtin_amdgcn_s_barrier();
    __builtin_amdgcn_s_setprio(1);
#pragma unroll
    for (int mi = 0; mi < 4; ++mi)
#pragma unroll
      for (int ni = 0; ni < 2; ++ni)
#pragma unroll
        for (int kk = 0; kk < 2; ++kk)
          acc[4 + mi][ni] = __builtin_amdgcn_mfma_f32_16x16x32_bf16(
              afr[mi][kk], bfr[ni][kk], acc[4 + mi][ni], 0, 0, 0);
    __builtin_amdgcn_s_setprio(0);
    // K-tile boundary: retire next-tile staging (issued 1-2 phases ago)
    asm volatile("s_waitcnt vmcnt(0)" ::: "memory");
    __builtin_amdgcn_s_barrier();
  }

  // epilogue (verified 16x16 C-layout: row = lg*4+rr, col = lc)
  const int rb = lg * 4;
#pragma unroll
  for (int mi = 0; mi < 8; ++mi)
#pragma unroll
    for (int ni = 0; ni < 2; ++ni) {
      int col = n0 + wn + ni * 16 + lc;
#pragma unroll
      for (int rr = 0; rr < 4; ++rr) {
        int row = m0 + wm + mi * 16 + rb + rr;
        if (STORE_F32) {
          ((float*)Cbase)[(size_t)row * EMB + col] = acc[mi][ni][rr] + bias[col];
        } else {
          ((unsigned short*)Cbase + (size_t)blockIdx.z * ROWSM * EMB)
              [(size_t)row * EMB + col] = f2bf(acc[mi][ni][rr]);
        }
      }
    }
}

// Causal flash attention, swapped-QK form, KVBLK=128 — round-9 proven, verbatim.
__global__ __launch_bounds__(256, 2) void attn_causal(
    const unsigned short* __restrict__ Pq, const unsigned short* __restrict__ Pk,
    const unsigned short* __restrict__ Pv, unsigned short* __restrict__ ctx) {
  __shared__ __align__(16) unsigned short Ks[128 * 128];
  __shared__ __align__(16) unsigned short Vt[128 * 128];

  const int tid  = threadIdx.x;
  const int lane = tid & 63;
  const int w    = tid >> 6;
  const int ql   = lane & 31;
  const int hi   = lane >> 5;
  const int lg   = lane >> 4;
  const int lc   = lane & 15;

  const int bid = blockIdx.x;
  const int xcd = bid & 7;
  const int jj_ = bid >> 3;
  const int hh  = jj_ >> 4;
  const int bh  = xcd * 4 + hh;
  const int b   = bh >> 4;
  const int h   = bh & 15;
  const int qtr = jj_ & 15;
  const int qt  = (hh >= 2) ? (15 - qtr) : qtr;
  const int q0 = qt * 128;
  const int qw = q0 + w * 32;
  const int qg = qw + ql;

  const size_t hoff = (size_t)bh * SEQ * HDIM;
  const unsigned short* Q  = Pq + hoff;
  const unsigned short* Kh = Pk + hoff;
  const unsigned short* Vh = Pv + hoff;

  bf16x8 bq[8];
#pragma unroll
  for (int d8 = 0; d8 < 8; ++d8)
    bq[d8] = *(const bf16x8*)(Q + (size_t)qg * HDIM + d8 * 16 + hi * 8);

  const float NEG = -3.0e38f;
  f32x16 o[4];
#pragma unroll
  for (int dt = 0; dt < 4; ++dt)
#pragma unroll
    for (int r = 0; r < 16; ++r) o[dt][r] = 0.f;
  float m_r = NEG, l_r = 0.f;

  const float Cs   = 0.12753123161692858f;
  const float TDEF = 62.7f;

  const int nt128 = qt + 1;
  for (int tt = 0; tt < nt128; ++tt) {
    const int kv0 = tt * 128;
    if (tt) __syncthreads();
#pragma unroll
    for (int ii = 0; ii < 8; ++ii) {
      int i = w * 8 + ii;
      int r = i * 4 + lg;
      int sd = lc ^ (r & 7);
      gload16(Kh + (size_t)(kv0 + r) * HDIM + sd * 8, (char*)Ks + i * 1024);
    }
#pragma unroll 1
    for (int hv = 0; hv < 2; ++hv) {
      uint4 vr[4];
      const unsigned short* Vs = Vh + (size_t)(kv0 + hv * 64) * HDIM;
#pragma unroll
      for (int uu = 0; uu < 2; ++uu) {
        int u = tid + uu * 256;
        int kp = u >> 4, dg = u & 15;
        int k = kp * 2, d0 = dg * 8;
        vr[uu * 2]     = *(const uint4*)(Vs + (size_t)k * HDIM + d0);
        vr[uu * 2 + 1] = *(const uint4*)(Vs + (size_t)(k + 1) * HDIM + d0);
      }
#pragma unroll
      for (int uu = 0; uu < 2; ++uu) {
        int u = tid + uu * 256;
        int kp = u >> 4, dg = u & 15;
        int k = kp * 2, d0 = dg * 8;
        const unsigned short* e0 = (const unsigned short*)&vr[uu * 2];
        const unsigned short* e1 = (const unsigned short*)&vr[uu * 2 + 1];
#pragma unroll
        for (int jj = 0; jj < 8; ++jj) {
          int d = d0 + jj;
          int slot = ((hv << 3) | (k >> 3)) ^ jj ^ (dg & 7);
          int byteoff = d * 256 + (slot << 4) + (k & 7) * 2;
          *(unsigned int*)((char*)Vt + byteoff) =
              (unsigned int)e0[jj] | ((unsigned int)e1[jj] << 16);
        }
      }
    }
    __syncthreads();

#pragma unroll 1
    for (int hf = 0; hf < 2; ++hf) {
      const int kv0h = kv0 + hf * 64;
      if (kv0h > qw + 31) continue;
      const bool s1on = (kv0h + 32 <= qw + 31);
      const bool diag = (kv0h + 63 > qw);
      const char* ksb = (const char*)Ks + hf * 64 * 256;

      f32x16 c0, c1;
#pragma unroll
      for (int r = 0; r < 16; ++r) { c0[r] = 0.f; c1[r] = s1on ? 0.f : NEG; }
      __builtin_amdgcn_s_setprio(1);
#pragma unroll
      for (int d8 = 0; d8 < 8; ++d8) {
        bf16x8 ak = *(const bf16x8*)(ksb + ql * 256 +
                                     (((d8 * 2 + hi) ^ (ql & 7)) << 4));
        c0 = __builtin_amdgcn_mfma_f32_32x32x16_bf16(ak, bq[d8], c0, 0, 0, 0);
      }
      if (s1on) {
#pragma unroll
        for (int d8 = 0; d8 < 8; ++d8) {
          bf16x8 ak = *(const bf16x8*)(ksb + (32 + ql) * 256 +
                                       (((d8 * 2 + hi) ^ (ql & 7)) << 4));
          c1 = __builtin_amdgcn_mfma_f32_32x32x16_bf16(ak, bq[d8], c1, 0, 0, 0);
        }
      }
      __builtin_amdgcn_s_setprio(0);

      if (diag) {
#pragma unroll
        for (int r = 0; r < 16; ++r) {
          int kvl = (r & 3) + 8 * (r >> 2) + 4 * hi;
          if (kv0h + kvl > qg) c0[r] = NEG;
          if (s1on && kv0h + 32 + kvl > qg) c1[r] = NEG;
        }
      }
      float rm = c0[0];
#pragma unroll
      for (int r = 1; r < 16; ++r) rm = fmaxf(rm, c0[r]);
#pragma unroll
      for (int r = 0; r < 16; ++r) rm = fmaxf(rm, c1[r]);
      rm = fmaxf(rm, __shfl_xor(rm, 32));

      if (__any(rm > m_r + TDEF)) {
        float mnew = fmaxf(m_r, rm);
        float alpha = exp2f((m_r - mnew) * Cs);
        m_r = mnew;
        l_r *= alpha;
#pragma unroll
        for (int r = 0; r < 16; ++r) {
          float ar = __shfl(alpha, (r & 3) + 8 * (r >> 2) + 4 * hi);
#pragma unroll
          for (int dt = 0; dt < 4; ++dt) o[dt][r] *= ar;
        }
      }
#pragma unroll
      for (int r = 0; r < 16; ++r) {
        c0[r] = exp2f((c0[r] - m_r) * Cs);
        c1[r] = exp2f((c1[r] - m_r) * Cs);
      }
      float ps = 0.f;
#pragma unroll
      for (int r = 0; r < 16; ++r) ps += c0[r] + c1[r];
      ps += __shfl_xor(ps, 32);
      l_r += ps;

      bf16x8 pa[4];
#pragma unroll
      for (int t4 = 0; t4 < 4; ++t4) {
        const f32x16& cc = (t4 < 2) ? c0 : c1;
        const int rA = (t4 & 1) * 8;
        unsigned int pkL0 = pk2(cc[rA + 0], cc[rA + 1]);
        unsigned int pkL1 = pk2(cc[rA + 2], cc[rA + 3]);
        unsigned int pkH0 = pk2(cc[rA + 4], cc[rA + 5]);
        unsigned int pkH1 = pk2(cc[rA + 6], cc[rA + 7]);
        unsigned int give0 = hi ? pkL0 : pkH0;
        unsigned int give1 = hi ? pkL1 : pkH1;
        unsigned int keep0 = hi ? pkH0 : pkL0;
        unsigned int keep1 = hi ? pkH1 : pkL1;
        unsigned int recv0 = __shfl_xor(give0, 32);
        unsigned int recv1 = __shfl_xor(give1, 32);
        union { unsigned int u[4]; bf16x8 v; } pu;
        pu.u[0] = hi ? recv0 : keep0;
        pu.u[1] = hi ? recv1 : keep1;
        pu.u[2] = hi ? keep0 : recv0;
        pu.u[3] = hi ? keep1 : recv1;
        pa[t4] = pu.v;
      }
      __builtin_amdgcn_s_setprio(1);
#pragma unroll
      for (int t4 = 0; t4 < 4; ++t4) {
        if (diag && kv0h + t4 * 16 > qw + 31) continue;
#pragma unroll
        for (int dt = 0; dt < 4; ++dt) {
          int d = dt * 32 + ql;
          int slot = ((hf << 3) | (t4 << 1) | hi) ^ (d & 7) ^ ((d >> 3) & 7);
          bf16x8 bv = *(const bf16x8*)((const char*)Vt + d * 256 + (slot << 4));
          o[dt] = __builtin_amdgcn_mfma_f32_32x32x16_bf16(pa[t4], bv, o[dt], 0, 0, 0);
        }
      }
      __builtin_amdgcn_s_setprio(0);
    }
  }

  float linv = 1.0f / l_r;
  unsigned short* outp = ctx + (size_t)b * SEQ * EMB + (size_t)h * HDIM;
#pragma unroll
  for (int r = 0; r < 16; ++r) {
    int kvl = (r & 3) + 8 * (r >> 2) + 4 * hi;
    float lr = __shfl(linv, kvl);
    int qrow = qw + kvl;
#pragma unroll
    for (int dt = 0; dt < 4; ++dt)
      outp[(size_t)qrow * EMB + dt * 32 + ql] = f2bf(o[dt][r] * lr);
  }
}

extern "C" void kernel_launch(void* const* d_in, const int* in_sizes, int n_in,
                              void* d_out, int out_size, void* d_ws, size_t ws_size,
                              hipStream_t stream) {
  const float* x  = (const float*)d_in[0];
  const float* Wq = (const float*)d_in[1];
  const float* Wk = (const float*)d_in[2];
  const float* Wv = (const float*)d_in[3];
  const float* Wp = (const float*)d_in[4];
  const float* bp = (const float*)d_in[5];

  char* ws = (char*)d_ws;
  unsigned short* xb = (unsigned short*)ws;                         // 16MB, reused as ctx
  unsigned short* Wb = (unsigned short*)(ws + (size_t)(16u << 20)); // 8MB (Wq, then Wp)
  unsigned short* Pq = (unsigned short*)(ws + (size_t)(24u << 20)); // 3x16MB contiguous
  unsigned short* Pk = (unsigned short*)(ws + (size_t)(40u << 20));
  unsigned short* Pv = (unsigned short*)(ws + (size_t)(56u << 20));
  // d_out (33.5MB fp32) is fully rewritten by the final GEMM -> first 16MB
  // doubles as scratch for Wv/Wk bf16 during the QKV phase.
  unsigned short* WvS = (unsigned short*)d_out;
  unsigned short* WkS = (unsigned short*)d_out + (size_t)4 * 1024 * 1024;

  const int nX4 = ROWSM * EMB / 4;
  const int nW4 = EMB * EMB / 4;

  cvt_bf16<<<nX4 / 256, 256, 0, stream>>>(x, xb, nX4);
  cvt_bf16_3<<<dim3(nW4 / 256, 1, 3), 256, 0, stream>>>(Wq, Wk, Wv, Wb, WkS, WvS, nW4);

  // QKV: 16 x 16 x 3 = 768 blocks = exactly 3 rounds of 256 CUs
  gemm_big<0><<<dim3(EMB / 128, ROWSM / 256, 3), 512, 0, stream>>>(
      xb, Wb, WkS, WvS, Pq, nullptr, EMB);

  attn_causal<<<512, 256, 0, stream>>>(Pq, Pk, Pv, xb);

  cvt_bf16<<<nW4 / 256, 256, 0, stream>>>(Wp, Wb, nW4);
  // P: 16 x 16 = 256 blocks = exactly 1 round
  gemm_big<1><<<dim3(EMB / 128, ROWSM / 256, 1), 512, 0, stream>>>(
      xb, Wb, Wb, Wb, d_out, bp, EMB);
}

// Round 11
// 288.555 us; speedup vs baseline: 1.3140x; 1.3140x over previous
//
#include <hip/hip_runtime.h>

#define SEQ   2048
#define EMB   2048
#define NHEAD 16
#define HDIM  128
#define ROWSM 4096  // B*SEQ

typedef float  f32x4   __attribute__((ext_vector_type(4)));
typedef float  f32x16  __attribute__((ext_vector_type(16)));
typedef __bf16 bf16x8  __attribute__((ext_vector_type(8)));

__device__ __forceinline__ unsigned short f2bf(float f) {
  union { float f; unsigned int u; } v; v.f = f;
  return (unsigned short)((v.u + 0x7fffu + ((v.u >> 16) & 1u)) >> 16);
}
__device__ __forceinline__ unsigned int pk2(float a, float b) {
  return (unsigned int)f2bf(a) | ((unsigned int)f2bf(b) << 16);
}

__device__ __forceinline__ void gload16(const void* g, void* l) {
  __builtin_amdgcn_global_load_lds(
      (__attribute__((address_space(1))) const unsigned int*)g,
      (__attribute__((address_space(3))) unsigned int*)l,
      16, 0, 0);
}

// fp32 -> bf16 bulk convert, 4 elems/thread
__global__ void cvt_bf16(const float* __restrict__ in,
                         unsigned short* __restrict__ out, int n4) {
  int i = blockIdx.x * 256 + threadIdx.x;
  if (i >= n4) return;
  float4 v = ((const float4*)in)[i];
  ushort4 o;
  o.x = f2bf(v.x); o.y = f2bf(v.y); o.z = f2bf(v.z); o.w = f2bf(v.w);
  ((ushort4*)out)[i] = o;
}

// three same-size fp32->bf16 converts in one launch (z selects)
__global__ void cvt_bf16_3(const float* __restrict__ i0, const float* __restrict__ i1,
                           const float* __restrict__ i2, unsigned short* __restrict__ o0,
                           unsigned short* __restrict__ o1, unsigned short* __restrict__ o2,
                           int n4) {
  const float* in = (blockIdx.z == 0) ? i0 : (blockIdx.z == 1) ? i1 : i2;
  unsigned short* out = (blockIdx.z == 0) ? o0 : (blockIdx.z == 1) ? o1 : o2;
  int i = blockIdx.x * 256 + threadIdx.x;
  if (i >= n4) return;
  float4 v = ((const float4*)in)[i];
  ushort4 o;
  o.x = f2bf(v.x); o.y = f2bf(v.y); o.z = f2bf(v.z); o.w = f2bf(v.w);
  ((ushort4*)out)[i] = o;
}

// Round-9 proven 128x128/BK64/4-wave GEMM body + T4 counted-vmcnt pipeline:
// double-buffered LDS (64KB -> still 2 blocks/CU), prologue stages tiles 0,1;
// per tile: vmcnt(8) retires ONLY tile t's 8 loads (t+1's stay in flight) ->
// raw barrier -> unchanged compute -> lgkmcnt(0)+barrier (buf reads done) ->
// stage tile t+2 into the freed buf. NO vmcnt(0) in the main loop (round-10
// post-mortem: drain-at-boundary stalled ~600cy/tile with 1 block/CU).
// z selects among 3 B matrices / output slices (QKV); single-z for P.
// launch_bounds(256,2): VGPR cap 128 (ladder), kernel uses ~80.
template <int STORE_F32>
__global__ __launch_bounds__(256, 2) void gemm_pipe(
    const unsigned short* __restrict__ A,
    const unsigned short* __restrict__ B0, const unsigned short* __restrict__ B1,
    const unsigned short* __restrict__ B2,
    void* __restrict__ Cbase, const float* __restrict__ bias) {
  __shared__ __align__(16) unsigned short As[2][128 * 64];
  __shared__ __align__(16) unsigned short Bs[2][128 * 64];
  const unsigned short* Bm = (blockIdx.z == 0) ? B0 : (blockIdx.z == 1) ? B1 : B2;

  const int tid  = threadIdx.x;
  const int lane = tid & 63;
  const int w    = tid >> 6;
  const int m0 = blockIdx.y * 128;
  const int n0 = blockIdx.x * 128;
  const int wm = (w >> 1) * 64;
  const int wn = (w & 1) * 64;
  const int lg = lane >> 4;
  const int lc = lane & 15;

  f32x4 acc[4][4] = {};
  const int srow = lane >> 3;
  const int scol = (lane & 7) * 8;

  // 8 loads/lane per stage (4 A-chunks + 4 B-chunks)
  auto stage = [&](int buf, int k0) {
#pragma unroll
    for (int ii = 0; ii < 4; ++ii) {
      int i = w * 4 + ii;
      int r = i * 8 + srow;
      gload16(A  + (size_t)(m0 + r) * EMB + k0 + scol, (char*)&As[buf][0] + i * 1024);
      gload16(Bm + (size_t)(n0 + r) * EMB + k0 + scol, (char*)&Bs[buf][0] + i * 1024);
    }
  };

  // prologue: 2-deep
  stage(0, 0);
  stage(1, 64);

  const int NT = EMB / 64;   // 32
  for (int t = 0; t < NT; ++t) {
    const int buf = t & 1;
    // retire tile t's loads only; keep t+1's 8 in flight (T4)
    if (t + 1 < NT) asm volatile("s_waitcnt vmcnt(8)" ::: "memory");
    else            asm volatile("s_waitcnt vmcnt(0)" ::: "memory");
    __builtin_amdgcn_s_barrier();

    const unsigned short* as = &As[buf][0];
    const unsigned short* bs = &Bs[buf][0];
#pragma unroll
    for (int kk = 0; kk < 2; ++kk) {
      const int co = kk * 32 + lg * 8;
      bf16x8 a[4], b[4];
#pragma unroll
      for (int i = 0; i < 4; ++i)
        a[i] = *(const bf16x8*)(as + (wm + i * 16 + lc) * 64 + co);
#pragma unroll
      for (int j = 0; j < 4; ++j)
        b[j] = *(const bf16x8*)(bs + (wn + j * 16 + lc) * 64 + co);
#pragma unroll
      for (int i = 0; i < 4; ++i)
#pragma unroll
        for (int j = 0; j < 4; ++j)
          acc[i][j] = __builtin_amdgcn_mfma_f32_16x16x32_bf16(a[i], b[j], acc[i][j], 0, 0, 0);
    }
    // all reads of buf done (block-wide) -> safe to overwrite with tile t+2
    asm volatile("s_waitcnt lgkmcnt(0)" ::: "memory");
    __builtin_amdgcn_s_barrier();
    if (t + 2 < NT) stage(buf, (t + 2) * 64);
  }

  const int rb = lg * 4;
#pragma unroll
  for (int i = 0; i < 4; ++i)
#pragma unroll
    for (int j = 0; j < 4; ++j) {
      int col = n0 + wn + j * 16 + lc;
#pragma unroll
      for (int r = 0; r < 4; ++r) {
        int row = m0 + wm + i * 16 + rb + r;
        if (STORE_F32) {
          ((float*)Cbase)[(size_t)row * EMB + col] = acc[i][j][r] + bias[col];
        } else {
          ((unsigned short*)Cbase + (size_t)blockIdx.z * ROWSM * EMB)
              [(size_t)row * EMB + col] = f2bf(acc[i][j][r]);
        }
      }
    }
}

// Causal flash attention, swapped-QK form, KVBLK=128 — round-9 proven, verbatim.
__global__ __launch_bounds__(256, 2) void attn_causal(
    const unsigned short* __restrict__ Pq, const unsigned short* __restrict__ Pk,
    const unsigned short* __restrict__ Pv, unsigned short* __restrict__ ctx) {
  __shared__ __align__(16) unsigned short Ks[128 * 128];
  __shared__ __align__(16) unsigned short Vt[128 * 128];

  const int tid  = threadIdx.x;
  const int lane = tid & 63;
  const int w    = tid >> 6;
  const int ql   = lane & 31;
  const int hi   = lane >> 5;
  const int lg   = lane >> 4;
  const int lc   = lane & 15;

  const int bid = blockIdx.x;
  const int xcd = bid & 7;
  const int jj_ = bid >> 3;
  const int hh  = jj_ >> 4;
  const int bh  = xcd * 4 + hh;
  const int b   = bh >> 4;
  const int h   = bh & 15;
  const int qtr = jj_ & 15;
  const int qt  = (hh >= 2) ? (15 - qtr) : qtr;
  const int q0 = qt * 128;
  const int qw = q0 + w * 32;
  const int qg = qw + ql;

  const size_t hoff = (size_t)bh * SEQ * HDIM;
  const unsigned short* Q  = Pq + hoff;
  const unsigned short* Kh = Pk + hoff;
  const unsigned short* Vh = Pv + hoff;

  bf16x8 bq[8];
#pragma unroll
  for (int d8 = 0; d8 < 8; ++d8)
    bq[d8] = *(const bf16x8*)(Q + (size_t)qg * HDIM + d8 * 16 + hi * 8);

  const float NEG = -3.0e38f;
  f32x16 o[4];
#pragma unroll
  for (int dt = 0; dt < 4; ++dt)
#pragma unroll
    for (int r = 0; r < 16; ++r) o[dt][r] = 0.f;
  float m_r = NEG, l_r = 0.f;

  const float Cs   = 0.12753123161692858f;
  const float TDEF = 62.7f;

  const int nt128 = qt + 1;
  for (int tt = 0; tt < nt128; ++tt) {
    const int kv0 = tt * 128;
    if (tt) __syncthreads();
#pragma unroll
    for (int ii = 0; ii < 8; ++ii) {
      int i = w * 8 + ii;
      int r = i * 4 + lg;
      int sd = lc ^ (r & 7);
      gload16(Kh + (size_t)(kv0 + r) * HDIM + sd * 8, (char*)Ks + i * 1024);
    }
#pragma unroll 1
    for (int hv = 0; hv < 2; ++hv) {
      uint4 vr[4];
      const unsigned short* Vs = Vh + (size_t)(kv0 + hv * 64) * HDIM;
#pragma unroll
      for (int uu = 0; uu < 2; ++uu) {
        int u = tid + uu * 256;
        int kp = u >> 4, dg = u & 15;
        int k = kp * 2, d0 = dg * 8;
        vr[uu * 2]     = *(const uint4*)(Vs + (size_t)k * HDIM + d0);
        vr[uu * 2 + 1] = *(const uint4*)(Vs + (size_t)(k + 1) * HDIM + d0);
      }
#pragma unroll
      for (int uu = 0; uu < 2; ++uu) {
        int u = tid + uu * 256;
        int kp = u >> 4, dg = u & 15;
        int k = kp * 2, d0 = dg * 8;
        const unsigned short* e0 = (const unsigned short*)&vr[uu * 2];
        const unsigned short* e1 = (const unsigned short*)&vr[uu * 2 + 1];
#pragma unroll
        for (int jj = 0; jj < 8; ++jj) {
          int d = d0 + jj;
          int slot = ((hv << 3) | (k >> 3)) ^ jj ^ (dg & 7);
          int byteoff = d * 256 + (slot << 4) + (k & 7) * 2;
          *(unsigned int*)((char*)Vt + byteoff) =
              (unsigned int)e0[jj] | ((unsigned int)e1[jj] << 16);
        }
      }
    }
    __syncthreads();

#pragma unroll 1
    for (int hf = 0; hf < 2; ++hf) {
      const int kv0h = kv0 + hf * 64;
      if (kv0h > qw + 31) continue;
      const bool s1on = (kv0h + 32 <= qw + 31);
      const bool diag = (kv0h + 63 > qw);
      const char* ksb = (const char*)Ks + hf * 64 * 256;

      f32x16 c0, c1;
#pragma unroll
      for (int r = 0; r < 16; ++r) { c0[r] = 0.f; c1[r] = s1on ? 0.f : NEG; }
      __builtin_amdgcn_s_setprio(1);
#pragma unroll
      for (int d8 = 0; d8 < 8; ++d8) {
        bf16x8 ak = *(const bf16x8*)(ksb + ql * 256 +
                                     (((d8 * 2 + hi) ^ (ql & 7)) << 4));
        c0 = __builtin_amdgcn_mfma_f32_32x32x16_bf16(ak, bq[d8], c0, 0, 0, 0);
      }
      if (s1on) {
#pragma unroll
        for (int d8 = 0; d8 < 8; ++d8) {
          bf16x8 ak = *(const bf16x8*)(ksb + (32 + ql) * 256 +
                                       (((d8 * 2 + hi) ^ (ql & 7)) << 4));
          c1 = __builtin_amdgcn_mfma_f32_32x32x16_bf16(ak, bq[d8], c1, 0, 0, 0);
        }
      }
      __builtin_amdgcn_s_setprio(0);

      if (diag) {
#pragma unroll
        for (int r = 0; r < 16; ++r) {
          int kvl = (r & 3) + 8 * (r >> 2) + 4 * hi;
          if (kv0h + kvl > qg) c0[r] = NEG;
          if (s1on && kv0h + 32 + kvl > qg) c1[r] = NEG;
        }
      }
      float rm = c0[0];
#pragma unroll
      for (int r = 1; r < 16; ++r) rm = fmaxf(rm, c0[r]);
#pragma unroll
      for (int r = 0; r < 16; ++r) rm = fmaxf(rm, c1[r]);
      rm = fmaxf(rm, __shfl_xor(rm, 32));

      if (__any(rm > m_r + TDEF)) {
        float mnew = fmaxf(m_r, rm);
        float alpha = exp2f((m_r - mnew) * Cs);
        m_r = mnew;
        l_r *= alpha;
#pragma unroll
        for (int r = 0; r < 16; ++r) {
          float ar = __shfl(alpha, (r & 3) + 8 * (r >> 2) + 4 * hi);
#pragma unroll
          for (int dt = 0; dt < 4; ++dt) o[dt][r] *= ar;
        }
      }
#pragma unroll
      for (int r = 0; r < 16; ++r) {
        c0[r] = exp2f((c0[r] - m_r) * Cs);
        c1[r] = exp2f((c1[r] - m_r) * Cs);
      }
      float ps = 0.f;
#pragma unroll
      for (int r = 0; r < 16; ++r) ps += c0[r] + c1[r];
      ps += __shfl_xor(ps, 32);
      l_r += ps;

      bf16x8 pa[4];
#pragma unroll
      for (int t4 = 0; t4 < 4; ++t4) {
        const f32x16& cc = (t4 < 2) ? c0 : c1;
        const int rA = (t4 & 1) * 8;
        unsigned int pkL0 = pk2(cc[rA + 0], cc[rA + 1]);
        unsigned int pkL1 = pk2(cc[rA + 2], cc[rA + 3]);
        unsigned int pkH0 = pk2(cc[rA + 4], cc[rA + 5]);
        unsigned int pkH1 = pk2(cc[rA + 6], cc[rA + 7]);
        unsigned int give0 = hi ? pkL0 : pkH0;
        unsigned int give1 = hi ? pkL1 : pkH1;
        unsigned int keep0 = hi ? pkH0 : pkL0;
        unsigned int keep1 = hi ? pkH1 : pkL1;
        unsigned int recv0 = __shfl_xor(give0, 32);
        unsigned int recv1 = __shfl_xor(give1, 32);
        union { unsigned int u[4]; bf16x8 v; } pu;
        pu.u[0] = hi ? recv0 : keep0;
        pu.u[1] = hi ? recv1 : keep1;
        pu.u[2] = hi ? keep0 : recv0;
        pu.u[3] = hi ? keep1 : recv1;
        pa[t4] = pu.v;
      }
      __builtin_amdgcn_s_setprio(1);
#pragma unroll
      for (int t4 = 0; t4 < 4; ++t4) {
        if (diag && kv0h + t4 * 16 > qw + 31) continue;
#pragma unroll
        for (int dt = 0; dt < 4; ++dt) {
          int d = dt * 32 + ql;
          int slot = ((hf << 3) | (t4 << 1) | hi) ^ (d & 7) ^ ((d >> 3) & 7);
          bf16x8 bv = *(const bf16x8*)((const char*)Vt + d * 256 + (slot << 4));
          o[dt] = __builtin_amdgcn_mfma_f32_32x32x16_bf16(pa[t4], bv, o[dt], 0, 0, 0);
        }
      }
      __builtin_amdgcn_s_setprio(0);
    }
  }

  float linv = 1.0f / l_r;
  unsigned short* outp = ctx + (size_t)b * SEQ * EMB + (size_t)h * HDIM;
#pragma unroll
  for (int r = 0; r < 16; ++r) {
    int kvl = (r & 3) + 8 * (r >> 2) + 4 * hi;
    float lr = __shfl(linv, kvl);
    int qrow = qw + kvl;
#pragma unroll
    for (int dt = 0; dt < 4; ++dt)
      outp[(size_t)qrow * EMB + dt * 32 + ql] = f2bf(o[dt][r] * lr);
  }
}

extern "C" void kernel_launch(void* const* d_in, const int* in_sizes, int n_in,
                              void* d_out, int out_size, void* d_ws, size_t ws_size,
                              hipStream_t stream) {
  const float* x  = (const float*)d_in[0];
  const float* Wq = (const float*)d_in[1];
  const float* Wk = (const float*)d_in[2];
  const float* Wv = (const float*)d_in[3];
  const float* Wp = (const float*)d_in[4];
  const float* bp = (const float*)d_in[5];

  char* ws = (char*)d_ws;
  unsigned short* xb = (unsigned short*)ws;                         // 16MB, reused as ctx
  unsigned short* Wb = (unsigned short*)(ws + (size_t)(16u << 20)); // 8MB (Wq, then Wp)
  unsigned short* Pq = (unsigned short*)(ws + (size_t)(24u << 20)); // 3x16MB contiguous
  unsigned short* Pk = (unsigned short*)(ws + (size_t)(40u << 20));
  unsigned short* Pv = (unsigned short*)(ws + (size_t)(56u << 20));
  // d_out (33.5MB fp32) is fully rewritten by the final GEMM -> first 16MB
  // doubles as scratch for Wv/Wk bf16 during the QKV phase.
  unsigned short* WvS = (unsigned short*)d_out;
  unsigned short* WkS = (unsigned short*)d_out + (size_t)4 * 1024 * 1024;

  const int nX4 = ROWSM * EMB / 4;
  const int nW4 = EMB * EMB / 4;

  cvt_bf16<<<nX4 / 256, 256, 0, stream>>>(x, xb, nX4);
  cvt_bf16_3<<<dim3(nW4 / 256, 1, 3), 256, 0, stream>>>(Wq, Wk, Wv, Wb, WkS, WvS, nW4);

  // QKV: 16 x 32 x 3 = 1536 blocks (128^2 tiles)
  gemm_pipe<0><<<dim3(EMB / 128, ROWSM / 128, 3), 256, 0, stream>>>(
      xb, Wb, WkS, WvS, Pq, nullptr);

  attn_causal<<<512, 256, 0, stream>>>(Pq, Pk, Pv, xb);

  cvt_bf16<<<nW4 / 256, 256, 0, stream>>>(Wp, Wb, nW4);
  gemm_pipe<1><<<dim3(EMB / 128, ROWSM / 128, 1), 256, 0, stream>>>(
      xb, Wb, Wb, Wb, d_out, bp);
}

// Round 12
// 276.256 us; speedup vs baseline: 1.3725x; 1.0445x over previous
//
#include <hip/hip_runtime.h>

#define SEQ   2048
#define EMB   2048
#define NHEAD 16
#define HDIM  128
#define ROWSM 4096  // B*SEQ

typedef float  f32x4   __attribute__((ext_vector_type(4)));
typedef float  f32x16  __attribute__((ext_vector_type(16)));
typedef __bf16 bf16x8  __attribute__((ext_vector_type(8)));

__device__ __forceinline__ unsigned short f2bf(float f) {
  union { float f; unsigned int u; } v; v.f = f;
  return (unsigned short)((v.u + 0x7fffu + ((v.u >> 16) & 1u)) >> 16);
}
__device__ __forceinline__ unsigned int pk2(float a, float b) {
  return (unsigned int)f2bf(a) | ((unsigned int)f2bf(b) << 16);
}

__device__ __forceinline__ void gload16(const void* g, void* l) {
  __builtin_amdgcn_global_load_lds(
      (__attribute__((address_space(1))) const unsigned int*)g,
      (__attribute__((address_space(3))) unsigned int*)l,
      16, 0, 0);
}

// fp32 -> bf16 bulk convert, 4 elems/thread
__global__ void cvt_bf16(const float* __restrict__ in,
                         unsigned short* __restrict__ out, int n4) {
  int i = blockIdx.x * 256 + threadIdx.x;
  if (i >= n4) return;
  float4 v = ((const float4*)in)[i];
  ushort4 o;
  o.x = f2bf(v.x); o.y = f2bf(v.y); o.z = f2bf(v.z); o.w = f2bf(v.w);
  ((ushort4*)out)[i] = o;
}

// three same-size fp32->bf16 converts in one launch (z selects)
__global__ void cvt_bf16_3(const float* __restrict__ i0, const float* __restrict__ i1,
                           const float* __restrict__ i2, unsigned short* __restrict__ o0,
                           unsigned short* __restrict__ o1, unsigned short* __restrict__ o2,
                           int n4) {
  const float* in = (blockIdx.z == 0) ? i0 : (blockIdx.z == 1) ? i1 : i2;
  unsigned short* out = (blockIdx.z == 0) ? o0 : (blockIdx.z == 1) ? o1 : o2;
  int i = blockIdx.x * 256 + threadIdx.x;
  if (i >= n4) return;
  float4 v = ((const float4*)in)[i];
  ushort4 o;
  o.x = f2bf(v.x); o.y = f2bf(v.y); o.z = f2bf(v.z); o.w = f2bf(v.w);
  ((ushort4*)out)[i] = o;
}

// ============ 8-phase 256x256 GEMM (m201-template port), QKV only ============
// 8 waves (512 thr), per-wave out 128x64 (wr=w>>2, wc=w&3). BK=64.
// LDS 128KB: At[2][256][64] + Bt[2][256][64] (2 K-tile dbuf). 1 block/CU.
// Half-tile = 128 rows x 64 cols (16KB) = 2 gload16/thread (wave covers chunks
// w, w+8; chunk = 8 rows x 128B). Stage ledger: tile t's halves staged at
// global phases 4t-5..4t-2 in order A0,B0,B1,A1; compute phase 4t+p consumes
// quadrants (A0B0),(A0B1),(A1B1),(A1B0) -> each phase needs exactly one half
// staged >=4 phases earlier -> vmcnt(6) (3 halves in flight) at every phase
// top guarantees it; NEVER vmcnt(0) in-loop (round-10 lesson). Only phase 3
// stages into the active buffer (A0 region: readers finished 2 barriers ago,
// phase 3 itself reads nothing from LDS). T2 swizzle: source slot ^= row&7
// (full 8-way; round-10's (row&4)>>1 was only 2-way), read slot o^(lc&7).
// lgkmcnt(0) + sched_barrier(0) before MFMA (rule #18: hipcc hoists MFMA past
// inline-asm lgkmcnt otherwise).
__global__ __launch_bounds__(512, 1) void gemm8_qkv(
    const unsigned short* __restrict__ A,
    const unsigned short* __restrict__ B0, const unsigned short* __restrict__ B1,
    const unsigned short* __restrict__ B2, unsigned short* __restrict__ Cb) {
  __shared__ __align__(16) unsigned short At[2][256 * 64];
  __shared__ __align__(16) unsigned short Bt[2][256 * 64];
  const unsigned short* Bm = (blockIdx.z == 0) ? B0 : (blockIdx.z == 1) ? B1 : B2;
  unsigned short* C = Cb + (size_t)blockIdx.z * ROWSM * EMB;

  const int tid  = threadIdx.x;
  const int lane = tid & 63;
  const int w    = tid >> 6;        // 0..7
  const int wr   = w >> 2;          // 0..1 (M half)
  const int wc   = w & 3;           // 0..3 (N quarter)
  const int lg   = lane >> 4;
  const int lc   = lane & 15;
  const int m0 = blockIdx.y * 256;
  const int n0 = blockIdx.x * 256;

  const int srow8 = lane >> 3;            // row within 8-row chunk
  const int sslot = (lane & 7) ^ srow8;   // pre-swizzled global 16B slot
  const int NT = EMB / 64;                // 32 K-tiles

  // stage slot g: tile ts=(g+5)>>2, half hh=(g+5)&3 (0:A0 1:B0 2:B1 3:A1)
  auto stage_slot = [&](int g) {
    int ts = (g + 5) >> 2;
    if (ts >= NT) return;
    int hh  = (g + 5) & 3;
    int buf = ts & 1;
    int k0  = ts * 64;
    bool isA = (hh == 0 || hh == 3);
    bool upper = (hh == 2 || hh == 3);
    const unsigned short* src = isA ? A : Bm;
    int rbase = (isA ? m0 : n0) + (upper ? 128 : 0);
    char* dst = (isA ? (char*)&At[buf][0] : (char*)&Bt[buf][0]) + (upper ? 16384 : 0);
#pragma unroll
    for (int rr = 0; rr < 2; ++rr) {
      int c = w + rr * 8;
      int row = c * 8 + srow8;
      gload16(src + (size_t)(rbase + row) * EMB + k0 + sslot * 8, dst + c * 1024);
    }
  };

  f32x4 acc[8][4] = {};
  bf16x8 afr[4][2], bfr0[2][2], bfr1[2][2];

  // prologue: slots -5..-1 (t0 A0,B0,B1,A1; t1 A0)
  stage_slot(-5); stage_slot(-4); stage_slot(-3); stage_slot(-2); stage_slot(-1);

  for (int t = 0; t < NT; ++t) {
    const char* ab = (const char*)&At[t & 1][0];
    const char* bb = (const char*)&Bt[t & 1][0];
    const int g = t * 4;

    // ---- phase 0: quadrant (m0-3, n0-1) ----
    asm volatile("s_waitcnt vmcnt(6)" ::: "memory");
#pragma unroll
    for (int mi = 0; mi < 4; ++mi)
#pragma unroll
      for (int kk = 0; kk < 2; ++kk)
        afr[mi][kk] = *(const bf16x8*)(ab + (wr * 128 + mi * 16 + lc) * 128 +
                                       ((((kk << 2) | lg) ^ (lc & 7)) << 4));
#pragma unroll
    for (int ni = 0; ni < 2; ++ni)
#pragma unroll
      for (int kk = 0; kk < 2; ++kk)
        bfr0[ni][kk] = *(const bf16x8*)(bb + (wc * 64 + ni * 16 + lc) * 128 +
                                        ((((kk << 2) | lg) ^ (lc & 7)) << 4));
    stage_slot(g);
    __builtin_amdgcn_s_barrier();
    asm volatile("s_waitcnt lgkmcnt(0)" ::: "memory");
    __builtin_amdgcn_sched_barrier(0);
    __builtin_amdgcn_s_setprio(1);
#pragma unroll
    for (int mi = 0; mi < 4; ++mi)
#pragma unroll
      for (int ni = 0; ni < 2; ++ni)
#pragma unroll
        for (int kk = 0; kk < 2; ++kk)
          acc[mi][ni] = __builtin_amdgcn_mfma_f32_16x16x32_bf16(
              afr[mi][kk], bfr0[ni][kk], acc[mi][ni], 0, 0, 0);
    __builtin_amdgcn_s_setprio(0);
    __builtin_amdgcn_s_barrier();

    // ---- phase 1: quadrant (m0-3, n2-3) ----
    asm volatile("s_waitcnt vmcnt(6)" ::: "memory");
#pragma unroll
    for (int ni = 0; ni < 2; ++ni)
#pragma unroll
      for (int kk = 0; kk < 2; ++kk)
        bfr1[ni][kk] = *(const bf16x8*)(bb + (wc * 64 + (2 + ni) * 16 + lc) * 128 +
                                        ((((kk << 2) | lg) ^ (lc & 7)) << 4));
    stage_slot(g + 1);
    __builtin_amdgcn_s_barrier();
    asm volatile("s_waitcnt lgkmcnt(0)" ::: "memory");
    __builtin_amdgcn_sched_barrier(0);
    __builtin_amdgcn_s_setprio(1);
#pragma unroll
    for (int mi = 0; mi < 4; ++mi)
#pragma unroll
      for (int ni = 0; ni < 2; ++ni)
#pragma unroll
        for (int kk = 0; kk < 2; ++kk)
          acc[mi][2 + ni] = __builtin_amdgcn_mfma_f32_16x16x32_bf16(
              afr[mi][kk], bfr1[ni][kk], acc[mi][2 + ni], 0, 0, 0);
    __builtin_amdgcn_s_setprio(0);
    __builtin_amdgcn_s_barrier();

    // ---- phase 2: quadrant (m4-7, n2-3) ----
    asm volatile("s_waitcnt vmcnt(6)" ::: "memory");
#pragma unroll
    for (int mi = 0; mi < 4; ++mi)
#pragma unroll
      for (int kk = 0; kk < 2; ++kk)
        afr[mi][kk] = *(const bf16x8*)(ab + (wr * 128 + 64 + mi * 16 + lc) * 128 +
                                       ((((kk << 2) | lg) ^ (lc & 7)) << 4));
    stage_slot(g + 2);
    __builtin_amdgcn_s_barrier();
    asm volatile("s_waitcnt lgkmcnt(0)" ::: "memory");
    __builtin_amdgcn_sched_barrier(0);
    __builtin_amdgcn_s_setprio(1);
#pragma unroll
    for (int mi = 0; mi < 4; ++mi)
#pragma unroll
      for (int ni = 0; ni < 2; ++ni)
#pragma unroll
        for (int kk = 0; kk < 2; ++kk)
          acc[4 + mi][2 + ni] = __builtin_amdgcn_mfma_f32_16x16x32_bf16(
              afr[mi][kk], bfr1[ni][kk], acc[4 + mi][2 + ni], 0, 0, 0);
    __builtin_amdgcn_s_setprio(0);
    __builtin_amdgcn_s_barrier();

    // ---- phase 3: quadrant (m4-7, n0-1) — all frags in regs, no LDS reads ----
    stage_slot(g + 3);
    __builtin_amdgcn_s_setprio(1);
#pragma unroll
    for (int mi = 0; mi < 4; ++mi)
#pragma unroll
      for (int ni = 0; ni < 2; ++ni)
#pragma unroll
        for (int kk = 0; kk < 2; ++kk)
          acc[4 + mi][ni] = __builtin_amdgcn_mfma_f32_16x16x32_bf16(
              afr[mi][kk], bfr0[ni][kk], acc[4 + mi][ni], 0, 0, 0);
    __builtin_amdgcn_s_setprio(0);
    __builtin_amdgcn_s_barrier();
  }
  asm volatile("s_waitcnt vmcnt(0)" ::: "memory");

  // epilogue: C-layout per 16x16 frag: row = lg*4+rr, col = lc
#pragma unroll
  for (int mi = 0; mi < 8; ++mi)
#pragma unroll
    for (int ni = 0; ni < 4; ++ni) {
      int col = n0 + wc * 64 + ni * 16 + lc;
#pragma unroll
      for (int rr = 0; rr < 4; ++rr) {
        int row = m0 + wr * 128 + mi * 16 + lg * 4 + rr;
        C[(size_t)row * EMB + col] = f2bf(acc[mi][ni][rr]);
      }
    }
}

// Final projection GEMM: C_f32 = A @ B^T + bias (round-9 proven body).
__global__ __launch_bounds__(256, 2) void gemm_p(
    const unsigned short* __restrict__ A, const unsigned short* __restrict__ B,
    float* __restrict__ Cout, const float* __restrict__ bias) {
  __shared__ __align__(16) unsigned short As[128 * 64];
  __shared__ __align__(16) unsigned short Bs[128 * 64];
  const int tid  = threadIdx.x;
  const int lane = tid & 63;
  const int w    = tid >> 6;
  const int m0 = blockIdx.y * 128;
  const int n0 = blockIdx.x * 128;
  const int wm = (w >> 1) * 64;
  const int wn = (w & 1) * 64;
  const int lg = lane >> 4;
  const int lc = lane & 15;

  f32x4 acc[4][4] = {};
  const int srow = lane >> 3;
  const int scol = (lane & 7) * 8;

  for (int k0 = 0; k0 < EMB; k0 += 64) {
    if (k0) __syncthreads();
#pragma unroll
    for (int ii = 0; ii < 4; ++ii) {
      int i = w * 4 + ii;
      int r = i * 8 + srow;
      gload16(A + (size_t)(m0 + r) * EMB + k0 + scol, (char*)As + i * 1024);
      gload16(B + (size_t)(n0 + r) * EMB + k0 + scol, (char*)Bs + i * 1024);
    }
    __syncthreads();
#pragma unroll
    for (int kk = 0; kk < 2; ++kk) {
      const int co = kk * 32 + lg * 8;
      bf16x8 a[4], b[4];
#pragma unroll
      for (int i = 0; i < 4; ++i)
        a[i] = *(const bf16x8*)(As + (wm + i * 16 + lc) * 64 + co);
#pragma unroll
      for (int j = 0; j < 4; ++j)
        b[j] = *(const bf16x8*)(Bs + (wn + j * 16 + lc) * 64 + co);
#pragma unroll
      for (int i = 0; i < 4; ++i)
#pragma unroll
        for (int j = 0; j < 4; ++j)
          acc[i][j] = __builtin_amdgcn_mfma_f32_16x16x32_bf16(a[i], b[j], acc[i][j], 0, 0, 0);
    }
  }

  const int rb = lg * 4;
#pragma unroll
  for (int i = 0; i < 4; ++i)
#pragma unroll
    for (int j = 0; j < 4; ++j) {
      int col = n0 + wn + j * 16 + lc;
#pragma unroll
      for (int r = 0; r < 4; ++r) {
        int row = m0 + wm + i * 16 + rb + r;
        Cout[(size_t)row * EMB + col] = acc[i][j][r] + bias[col];
      }
    }
}

// Causal flash attention, swapped-QK form, KVBLK=128 — round-9 proven, verbatim.
__global__ __launch_bounds__(256, 2) void attn_causal(
    const unsigned short* __restrict__ Pq, const unsigned short* __restrict__ Pk,
    const unsigned short* __restrict__ Pv, unsigned short* __restrict__ ctx) {
  __shared__ __align__(16) unsigned short Ks[128 * 128];
  __shared__ __align__(16) unsigned short Vt[128 * 128];

  const int tid  = threadIdx.x;
  const int lane = tid & 63;
  const int w    = tid >> 6;
  const int ql   = lane & 31;
  const int hi   = lane >> 5;
  const int lg   = lane >> 4;
  const int lc   = lane & 15;

  const int bid = blockIdx.x;
  const int xcd = bid & 7;
  const int jj_ = bid >> 3;
  const int hh  = jj_ >> 4;
  const int bh  = xcd * 4 + hh;
  const int b   = bh >> 4;
  const int h   = bh & 15;
  const int qtr = jj_ & 15;
  const int qt  = (hh >= 2) ? (15 - qtr) : qtr;
  const int q0 = qt * 128;
  const int qw = q0 + w * 32;
  const int qg = qw + ql;

  const size_t hoff = (size_t)bh * SEQ * HDIM;
  const unsigned short* Q  = Pq + hoff;
  const unsigned short* Kh = Pk + hoff;
  const unsigned short* Vh = Pv + hoff;

  bf16x8 bq[8];
#pragma unroll
  for (int d8 = 0; d8 < 8; ++d8)
    bq[d8] = *(const bf16x8*)(Q + (size_t)qg * HDIM + d8 * 16 + hi * 8);

  const float NEG = -3.0e38f;
  f32x16 o[4];
#pragma unroll
  for (int dt = 0; dt < 4; ++dt)
#pragma unroll
    for (int r = 0; r < 16; ++r) o[dt][r] = 0.f;
  float m_r = NEG, l_r = 0.f;

  const float Cs   = 0.12753123161692858f;
  const float TDEF = 62.7f;

  const int nt128 = qt + 1;
  for (int tt = 0; tt < nt128; ++tt) {
    const int kv0 = tt * 128;
    if (tt) __syncthreads();
#pragma unroll
    for (int ii = 0; ii < 8; ++ii) {
      int i = w * 8 + ii;
      int r = i * 4 + lg;
      int sd = lc ^ (r & 7);
      gload16(Kh + (size_t)(kv0 + r) * HDIM + sd * 8, (char*)Ks + i * 1024);
    }
#pragma unroll 1
    for (int hv = 0; hv < 2; ++hv) {
      uint4 vr[4];
      const unsigned short* Vs = Vh + (size_t)(kv0 + hv * 64) * HDIM;
#pragma unroll
      for (int uu = 0; uu < 2; ++uu) {
        int u = tid + uu * 256;
        int kp = u >> 4, dg = u & 15;
        int k = kp * 2, d0 = dg * 8;
        vr[uu * 2]     = *(const uint4*)(Vs + (size_t)k * HDIM + d0);
        vr[uu * 2 + 1] = *(const uint4*)(Vs + (size_t)(k + 1) * HDIM + d0);
      }
#pragma unroll
      for (int uu = 0; uu < 2; ++uu) {
        int u = tid + uu * 256;
        int kp = u >> 4, dg = u & 15;
        int k = kp * 2, d0 = dg * 8;
        const unsigned short* e0 = (const unsigned short*)&vr[uu * 2];
        const unsigned short* e1 = (const unsigned short*)&vr[uu * 2 + 1];
#pragma unroll
        for (int jj = 0; jj < 8; ++jj) {
          int d = d0 + jj;
          int slot = ((hv << 3) | (k >> 3)) ^ jj ^ (dg & 7);
          int byteoff = d * 256 + (slot << 4) + (k & 7) * 2;
          *(unsigned int*)((char*)Vt + byteoff) =
              (unsigned int)e0[jj] | ((unsigned int)e1[jj] << 16);
        }
      }
    }
    __syncthreads();

#pragma unroll 1
    for (int hf = 0; hf < 2; ++hf) {
      const int kv0h = kv0 + hf * 64;
      if (kv0h > qw + 31) continue;
      const bool s1on = (kv0h + 32 <= qw + 31);
      const bool diag = (kv0h + 63 > qw);
      const char* ksb = (const char*)Ks + hf * 64 * 256;

      f32x16 c0, c1;
#pragma unroll
      for (int r = 0; r < 16; ++r) { c0[r] = 0.f; c1[r] = s1on ? 0.f : NEG; }
      __builtin_amdgcn_s_setprio(1);
#pragma unroll
      for (int d8 = 0; d8 < 8; ++d8) {
        bf16x8 ak = *(const bf16x8*)(ksb + ql * 256 +
                                     (((d8 * 2 + hi) ^ (ql & 7)) << 4));
        c0 = __builtin_amdgcn_mfma_f32_32x32x16_bf16(ak, bq[d8], c0, 0, 0, 0);
      }
      if (s1on) {
#pragma unroll
        for (int d8 = 0; d8 < 8; ++d8) {
          bf16x8 ak = *(const bf16x8*)(ksb + (32 + ql) * 256 +
                                       (((d8 * 2 + hi) ^ (ql & 7)) << 4));
          c1 = __builtin_amdgcn_mfma_f32_32x32x16_bf16(ak, bq[d8], c1, 0, 0, 0);
        }
      }
      __builtin_amdgcn_s_setprio(0);

      if (diag) {
#pragma unroll
        for (int r = 0; r < 16; ++r) {
          int kvl = (r & 3) + 8 * (r >> 2) + 4 * hi;
          if (kv0h + kvl > qg) c0[r] = NEG;
          if (s1on && kv0h + 32 + kvl > qg) c1[r] = NEG;
        }
      }
      float rm = c0[0];
#pragma unroll
      for (int r = 1; r < 16; ++r) rm = fmaxf(rm, c0[r]);
#pragma unroll
      for (int r = 0; r < 16; ++r) rm = fmaxf(rm, c1[r]);
      rm = fmaxf(rm, __shfl_xor(rm, 32));

      if (__any(rm > m_r + TDEF)) {
        float mnew = fmaxf(m_r, rm);
        float alpha = exp2f((m_r - mnew) * Cs);
        m_r = mnew;
        l_r *= alpha;
#pragma unroll
        for (int r = 0; r < 16; ++r) {
          float ar = __shfl(alpha, (r & 3) + 8 * (r >> 2) + 4 * hi);
#pragma unroll
          for (int dt = 0; dt < 4; ++dt) o[dt][r] *= ar;
        }
      }
#pragma unroll
      for (int r = 0; r < 16; ++r) {
        c0[r] = exp2f((c0[r] - m_r) * Cs);
        c1[r] = exp2f((c1[r] - m_r) * Cs);
      }
      float ps = 0.f;
#pragma unroll
      for (int r = 0; r < 16; ++r) ps += c0[r] + c1[r];
      ps += __shfl_xor(ps, 32);
      l_r += ps;

      bf16x8 pa[4];
#pragma unroll
      for (int t4 = 0; t4 < 4; ++t4) {
        const f32x16& cc = (t4 < 2) ? c0 : c1;
        const int rA = (t4 & 1) * 8;
        unsigned int pkL0 = pk2(cc[rA + 0], cc[rA + 1]);
        unsigned int pkL1 = pk2(cc[rA + 2], cc[rA + 3]);
        unsigned int pkH0 = pk2(cc[rA + 4], cc[rA + 5]);
        unsigned int pkH1 = pk2(cc[rA + 6], cc[rA + 7]);
        unsigned int give0 = hi ? pkL0 : pkH0;
        unsigned int give1 = hi ? pkL1 : pkH1;
        unsigned int keep0 = hi ? pkH0 : pkL0;
        unsigned int keep1 = hi ? pkH1 : pkL1;
        unsigned int recv0 = __shfl_xor(give0, 32);
        unsigned int recv1 = __shfl_xor(give1, 32);
        union { unsigned int u[4]; bf16x8 v; } pu;
        pu.u[0] = hi ? recv0 : keep0;
        pu.u[1] = hi ? recv1 : keep1;
        pu.u[2] = hi ? keep0 : recv0;
        pu.u[3] = hi ? keep1 : recv1;
        pa[t4] = pu.v;
      }
      __builtin_amdgcn_s_setprio(1);
#pragma unroll
      for (int t4 = 0; t4 < 4; ++t4) {
        if (diag && kv0h + t4 * 16 > qw + 31) continue;
#pragma unroll
        for (int dt = 0; dt < 4; ++dt) {
          int d = dt * 32 + ql;
          int slot = ((hf << 3) | (t4 << 1) | hi) ^ (d & 7) ^ ((d >> 3) & 7);
          bf16x8 bv = *(const bf16x8*)((const char*)Vt + d * 256 + (slot << 4));
          o[dt] = __builtin_amdgcn_mfma_f32_32x32x16_bf16(pa[t4], bv, o[dt], 0, 0, 0);
        }
      }
      __builtin_amdgcn_s_setprio(0);
    }
  }

  float linv = 1.0f / l_r;
  unsigned short* outp = ctx + (size_t)b * SEQ * EMB + (size_t)h * HDIM;
#pragma unroll
  for (int r = 0; r < 16; ++r) {
    int kvl = (r & 3) + 8 * (r >> 2) + 4 * hi;
    float lr = __shfl(linv, kvl);
    int qrow = qw + kvl;
#pragma unroll
    for (int dt = 0; dt < 4; ++dt)
      outp[(size_t)qrow * EMB + dt * 32 + ql] = f2bf(o[dt][r] * lr);
  }
}

extern "C" void kernel_launch(void* const* d_in, const int* in_sizes, int n_in,
                              void* d_out, int out_size, void* d_ws, size_t ws_size,
                              hipStream_t stream) {
  const float* x  = (const float*)d_in[0];
  const float* Wq = (const float*)d_in[1];
  const float* Wk = (const float*)d_in[2];
  const float* Wv = (const float*)d_in[3];
  const float* Wp = (const float*)d_in[4];
  const float* bp = (const float*)d_in[5];

  char* ws = (char*)d_ws;
  unsigned short* xb = (unsigned short*)ws;                         // 16MB, reused as ctx
  unsigned short* Wb = (unsigned short*)(ws + (size_t)(16u << 20)); // 8MB (Wq, then Wp)
  unsigned short* Pq = (unsigned short*)(ws + (size_t)(24u << 20)); // 3x16MB contiguous
  unsigned short* Pk = (unsigned short*)(ws + (size_t)(40u << 20));
  unsigned short* Pv = (unsigned short*)(ws + (size_t)(56u << 20));
  // d_out (33.5MB fp32) fully rewritten by final GEMM -> first 16MB doubles as
  // scratch for Wv/Wk bf16 during the QKV phase.
  unsigned short* WvS = (unsigned short*)d_out;
  unsigned short* WkS = (unsigned short*)d_out + (size_t)4 * 1024 * 1024;

  const int nX4 = ROWSM * EMB / 4;
  const int nW4 = EMB * EMB / 4;

  cvt_bf16<<<nX4 / 256, 256, 0, stream>>>(x, xb, nX4);
  cvt_bf16_3<<<dim3(nW4 / 256, 1, 3), 256, 0, stream>>>(Wq, Wk, Wv, Wb, WkS, WvS, nW4);

  // QKV: 256x256 tiles, 8 x 16 x 3 = 384 blocks
  gemm8_qkv<<<dim3(EMB / 256, ROWSM / 256, 3), 512, 0, stream>>>(
      xb, Wb, WkS, WvS, Pq);

  attn_causal<<<512, 256, 0, stream>>>(Pq, Pk, Pv, xb);

  cvt_bf16<<<nW4 / 256, 256, 0, stream>>>(Wp, Wb, nW4);
  gemm_p<<<dim3(EMB / 128, ROWSM / 128), 256, 0, stream>>>(xb, Wb, (float*)d_out, bp);
}

// Round 13
// 267.495 us; speedup vs baseline: 1.4175x; 1.0328x over previous
//
#include <hip/hip_runtime.h>

#define SEQ   2048
#define EMB   2048
#define NHEAD 16
#define HDIM  128
#define ROWSM 4096  // B*SEQ

typedef float  f32x4   __attribute__((ext_vector_type(4)));
typedef float  f32x16  __attribute__((ext_vector_type(16)));
typedef __bf16 bf16x8  __attribute__((ext_vector_type(8)));

__device__ __forceinline__ unsigned short f2bf(float f) {
  union { float f; unsigned int u; } v; v.f = f;
  return (unsigned short)((v.u + 0x7fffu + ((v.u >> 16) & 1u)) >> 16);
}
__device__ __forceinline__ unsigned int pk2(float a, float b) {
  return (unsigned int)f2bf(a) | ((unsigned int)f2bf(b) << 16);
}

__device__ __forceinline__ void gload16(const void* g, void* l) {
  __builtin_amdgcn_global_load_lds(
      (__attribute__((address_space(1))) const unsigned int*)g,
      (__attribute__((address_space(3))) unsigned int*)l,
      16, 0, 0);
}

// fp32 -> bf16 bulk convert, 4 elems/thread
__global__ void cvt_bf16(const float* __restrict__ in,
                         unsigned short* __restrict__ out, int n4) {
  int i = blockIdx.x * 256 + threadIdx.x;
  if (i >= n4) return;
  float4 v = ((const float4*)in)[i];
  ushort4 o;
  o.x = f2bf(v.x); o.y = f2bf(v.y); o.z = f2bf(v.z); o.w = f2bf(v.w);
  ((ushort4*)out)[i] = o;
}

// three same-size fp32->bf16 converts in one launch (z selects)
__global__ void cvt_bf16_3(const float* __restrict__ i0, const float* __restrict__ i1,
                           const float* __restrict__ i2, unsigned short* __restrict__ o0,
                           unsigned short* __restrict__ o1, unsigned short* __restrict__ o2,
                           int n4) {
  const float* in = (blockIdx.z == 0) ? i0 : (blockIdx.z == 1) ? i1 : i2;
  unsigned short* out = (blockIdx.z == 0) ? o0 : (blockIdx.z == 1) ? o1 : o2;
  int i = blockIdx.x * 256 + threadIdx.x;
  if (i >= n4) return;
  float4 v = ((const float4*)in)[i];
  ushort4 o;
  o.x = f2bf(v.x); o.y = f2bf(v.y); o.z = f2bf(v.z); o.w = f2bf(v.w);
  ((ushort4*)out)[i] = o;
}

// ====== 8-phase BM=256 x BN=128 GEMM (exact-round grids: 768 QKV / 256 P) ====
// 8 waves (512 thr), per-wave out 128x32 (wr=w>>2, wc=w&3). BK=64. LDS 96KB:
// At[2][256][64] + Bt[2][128][64] -> 1 block/CU. 2 phases/K-tile, 16 MFMA each.
// Region-safe 2-deep staging (no 3rd buffer needed):
//   phase0(t): reads A rows wr*128+[0,64) (A-even regions) + all B; stages
//              A-odd(t+1) (rows 64-127,192-255 — last read in phase1 of the
//              same-parity tile, whose closing barrier already passed).
//   phase1(t): reads A rows wr*128+[64,128) (A-odd); stages A-even(t+2)+B(t+2)
//              (their last readers finished at phase0(t)'s closing barrier).
// vmcnt is at END of each phase, BEFORE the closing barrier -> every wave's
// retire precedes every other wave's reads (cross-wave visibility via barrier;
// round-12's top-of-phase placement was only timing-safe). Ledger (2-load
// units, oldest-first): end-ph0 outstanding [Aodd(t)2, AeB(t+1)4, Aodd(t+1)2]
// -> vmcnt(6) retires Aodd(t); end-ph1 [AeB(t+1)4, Aodd(t+1)2, AeB(t+2)4]
// -> vmcnt(6) retires AeB(t+1). Tail: 2 -> 0. NEVER a mid-loop drain (T4).
// T2 swizzle both-sides: source slot (lane&7)^(row&7), read slot o^(lc&7).
template <int STORE_F32>
__global__ __launch_bounds__(512, 1) void gemm8(
    const unsigned short* __restrict__ A,
    const unsigned short* __restrict__ B0, const unsigned short* __restrict__ B1,
    const unsigned short* __restrict__ B2,
    void* __restrict__ Cbase, const float* __restrict__ bias) {
  __shared__ __align__(16) unsigned short At[2][256 * 64];  // 64KB
  __shared__ __align__(16) unsigned short Bt[2][128 * 64];  // 32KB
  const unsigned short* Bm = (blockIdx.z == 0) ? B0 : (blockIdx.z == 1) ? B1 : B2;

  const int tid  = threadIdx.x;
  const int lane = tid & 63;
  const int w    = tid >> 6;        // 0..7
  const int wr   = w >> 2;          // 0..1 (m half of 256)
  const int wc   = w & 3;           // 0..3 (n quarter of 128)
  const int lg   = lane >> 4;
  const int lc   = lane & 15;
  const int m0 = blockIdx.y * 256;
  const int n0 = blockIdx.x * 128;

  const int srow8 = lane >> 3;            // row within 8-row chunk
  const int sslot = (lane & 7) ^ srow8;   // pre-swizzled global 16B slot
  const int NT = EMB / 64;                // 32 K-tiles

  // chunk c = 8 rows x 128B at byte offset c*1024
  auto stageAeven = [&](int ts) {         // rows 0-63 (chunks 0-7) + 128-191 (16-23)
    if (ts >= NT) return;
    int buf = ts & 1, k0 = ts * 64;
    {
      int c = w;        int row = c * 8 + srow8;
      gload16(A + (size_t)(m0 + row) * EMB + k0 + sslot * 8, (char*)&At[buf][0] + c * 1024);
    }
    {
      int c = 16 + w;   int row = c * 8 + srow8;
      gload16(A + (size_t)(m0 + row) * EMB + k0 + sslot * 8, (char*)&At[buf][0] + c * 1024);
    }
  };
  auto stageAodd = [&](int ts) {          // rows 64-127 (chunks 8-15) + 192-255 (24-31)
    if (ts >= NT) return;
    int buf = ts & 1, k0 = ts * 64;
    {
      int c = 8 + w;    int row = c * 8 + srow8;
      gload16(A + (size_t)(m0 + row) * EMB + k0 + sslot * 8, (char*)&At[buf][0] + c * 1024);
    }
    {
      int c = 24 + w;   int row = c * 8 + srow8;
      gload16(A + (size_t)(m0 + row) * EMB + k0 + sslot * 8, (char*)&At[buf][0] + c * 1024);
    }
  };
  auto stageB = [&](int ts) {             // 128 rows (chunks 0-15)
    if (ts >= NT) return;
    int buf = ts & 1, k0 = ts * 64;
    {
      int c = w;        int row = c * 8 + srow8;
      gload16(Bm + (size_t)(n0 + row) * EMB + k0 + sslot * 8, (char*)&Bt[buf][0] + c * 1024);
    }
    {
      int c = 8 + w;    int row = c * 8 + srow8;
      gload16(Bm + (size_t)(n0 + row) * EMB + k0 + sslot * 8, (char*)&Bt[buf][0] + c * 1024);
    }
  };

  f32x4 acc[8][2] = {};
  bf16x8 afr[4][2], bfr[2][2];

  // prologue: AeB(0), Aodd(0), AeB(1) = 10 loads; retire AeB(0); barrier
  stageAeven(0); stageB(0); stageAodd(0); stageAeven(1); stageB(1);
  asm volatile("s_waitcnt vmcnt(6)" ::: "memory");
  __builtin_amdgcn_s_barrier();

  for (int t = 0; t < NT; ++t) {
    const char* ab = (const char*)&At[t & 1][0];
    const char* bb = (const char*)&Bt[t & 1][0];

    // ---------- phase 0: mi 0-3 (A-even region) x full B ----------
#pragma unroll
    for (int ni = 0; ni < 2; ++ni)
#pragma unroll
      for (int kk = 0; kk < 2; ++kk) {
        int row = wc * 32 + ni * 16 + lc;
        bfr[ni][kk] = *(const bf16x8*)(bb + row * 128 + ((((kk << 2) | lg) ^ (lc & 7)) << 4));
      }
#pragma unroll
    for (int mi = 0; mi < 4; ++mi)
#pragma unroll
      for (int kk = 0; kk < 2; ++kk) {
        int row = wr * 128 + mi * 16 + lc;
        afr[mi][kk] = *(const bf16x8*)(ab + row * 128 + ((((kk << 2) | lg) ^ (lc & 7)) << 4));
      }
    stageAodd(t + 1);
    __builtin_amdgcn_s_barrier();
    asm volatile("s_waitcnt lgkmcnt(0)" ::: "memory");
    __builtin_amdgcn_sched_barrier(0);
    __builtin_amdgcn_s_setprio(1);
#pragma unroll
    for (int mi = 0; mi < 4; ++mi)
#pragma unroll
      for (int ni = 0; ni < 2; ++ni)
#pragma unroll
        for (int kk = 0; kk < 2; ++kk)
          acc[mi][ni] = __builtin_amdgcn_mfma_f32_16x16x32_bf16(
              afr[mi][kk], bfr[ni][kk], acc[mi][ni], 0, 0, 0);
    __builtin_amdgcn_s_setprio(0);
    if (t + 1 < NT) asm volatile("s_waitcnt vmcnt(6)" ::: "memory");
    else            asm volatile("s_waitcnt vmcnt(0)" ::: "memory");
    __builtin_amdgcn_s_barrier();

    // ---------- phase 1: mi 4-7 (A-odd region) x B (regs) ----------
#pragma unroll
    for (int mi = 0; mi < 4; ++mi)
#pragma unroll
      for (int kk = 0; kk < 2; ++kk) {
        int row = wr * 128 + 64 + mi * 16 + lc;
        afr[mi][kk] = *(const bf16x8*)(ab + row * 128 + ((((kk << 2) | lg) ^ (lc & 7)) << 4));
      }
    stageAeven(t + 2); stageB(t + 2);
    __builtin_amdgcn_s_barrier();
    asm volatile("s_waitcnt lgkmcnt(0)" ::: "memory");
    __builtin_amdgcn_sched_barrier(0);
    __builtin_amdgcn_s_setprio(1);
#pragma unroll
    for (int mi = 0; mi < 4; ++mi)
#pragma unroll
      for (int ni = 0; ni < 2; ++ni)
#pragma unroll
        for (int kk = 0; kk < 2; ++kk)
          acc[4 + mi][ni] = __builtin_amdgcn_mfma_f32_16x16x32_bf16(
              afr[mi][kk], bfr[ni][kk], acc[4 + mi][ni], 0, 0, 0);
    __builtin_amdgcn_s_setprio(0);
    if (t + 2 < NT)      asm volatile("s_waitcnt vmcnt(6)" ::: "memory");
    else if (t + 1 < NT) asm volatile("s_waitcnt vmcnt(2)" ::: "memory");
    __builtin_amdgcn_s_barrier();
  }

  // epilogue (verified C-layout: row = lg*4+rr, col = lc within each 16x16)
#pragma unroll
  for (int mi = 0; mi < 8; ++mi)
#pragma unroll
    for (int ni = 0; ni < 2; ++ni) {
      int col = n0 + wc * 32 + ni * 16 + lc;
#pragma unroll
      for (int rr = 0; rr < 4; ++rr) {
        int row = m0 + wr * 128 + mi * 16 + lg * 4 + rr;
        if (STORE_F32) {
          ((float*)Cbase)[(size_t)row * EMB + col] = acc[mi][ni][rr] + bias[col];
        } else {
          ((unsigned short*)Cbase + (size_t)blockIdx.z * ROWSM * EMB)
              [(size_t)row * EMB + col] = f2bf(acc[mi][ni][rr]);
        }
      }
    }
}

// Causal flash attention, swapped-QK form, KVBLK=128 — round-9 proven, verbatim.
__global__ __launch_bounds__(256, 2) void attn_causal(
    const unsigned short* __restrict__ Pq, const unsigned short* __restrict__ Pk,
    const unsigned short* __restrict__ Pv, unsigned short* __restrict__ ctx) {
  __shared__ __align__(16) unsigned short Ks[128 * 128];
  __shared__ __align__(16) unsigned short Vt[128 * 128];

  const int tid  = threadIdx.x;
  const int lane = tid & 63;
  const int w    = tid >> 6;
  const int ql   = lane & 31;
  const int hi   = lane >> 5;
  const int lg   = lane >> 4;
  const int lc   = lane & 15;

  const int bid = blockIdx.x;
  const int xcd = bid & 7;
  const int jj_ = bid >> 3;
  const int hh  = jj_ >> 4;
  const int bh  = xcd * 4 + hh;
  const int b   = bh >> 4;
  const int h   = bh & 15;
  const int qtr = jj_ & 15;
  const int qt  = (hh >= 2) ? (15 - qtr) : qtr;
  const int q0 = qt * 128;
  const int qw = q0 + w * 32;
  const int qg = qw + ql;

  const size_t hoff = (size_t)bh * SEQ * HDIM;
  const unsigned short* Q  = Pq + hoff;
  const unsigned short* Kh = Pk + hoff;
  const unsigned short* Vh = Pv + hoff;

  bf16x8 bq[8];
#pragma unroll
  for (int d8 = 0; d8 < 8; ++d8)
    bq[d8] = *(const bf16x8*)(Q + (size_t)qg * HDIM + d8 * 16 + hi * 8);

  const float NEG = -3.0e38f;
  f32x16 o[4];
#pragma unroll
  for (int dt = 0; dt < 4; ++dt)
#pragma unroll
    for (int r = 0; r < 16; ++r) o[dt][r] = 0.f;
  float m_r = NEG, l_r = 0.f;

  const float Cs   = 0.12753123161692858f;
  const float TDEF = 62.7f;

  const int nt128 = qt + 1;
  for (int tt = 0; tt < nt128; ++tt) {
    const int kv0 = tt * 128;
    if (tt) __syncthreads();
#pragma unroll
    for (int ii = 0; ii < 8; ++ii) {
      int i = w * 8 + ii;
      int r = i * 4 + lg;
      int sd = lc ^ (r & 7);
      gload16(Kh + (size_t)(kv0 + r) * HDIM + sd * 8, (char*)Ks + i * 1024);
    }
#pragma unroll 1
    for (int hv = 0; hv < 2; ++hv) {
      uint4 vr[4];
      const unsigned short* Vs = Vh + (size_t)(kv0 + hv * 64) * HDIM;
#pragma unroll
      for (int uu = 0; uu < 2; ++uu) {
        int u = tid + uu * 256;
        int kp = u >> 4, dg = u & 15;
        int k = kp * 2, d0 = dg * 8;
        vr[uu * 2]     = *(const uint4*)(Vs + (size_t)k * HDIM + d0);
        vr[uu * 2 + 1] = *(const uint4*)(Vs + (size_t)(k + 1) * HDIM + d0);
      }
#pragma unroll
      for (int uu = 0; uu < 2; ++uu) {
        int u = tid + uu * 256;
        int kp = u >> 4, dg = u & 15;
        int k = kp * 2, d0 = dg * 8;
        const unsigned short* e0 = (const unsigned short*)&vr[uu * 2];
        const unsigned short* e1 = (const unsigned short*)&vr[uu * 2 + 1];
#pragma unroll
        for (int jj = 0; jj < 8; ++jj) {
          int d = d0 + jj;
          int slot = ((hv << 3) | (k >> 3)) ^ jj ^ (dg & 7);
          int byteoff = d * 256 + (slot << 4) + (k & 7) * 2;
          *(unsigned int*)((char*)Vt + byteoff) =
              (unsigned int)e0[jj] | ((unsigned int)e1[jj] << 16);
        }
      }
    }
    __syncthreads();

#pragma unroll 1
    for (int hf = 0; hf < 2; ++hf) {
      const int kv0h = kv0 + hf * 64;
      if (kv0h > qw + 31) continue;
      const bool s1on = (kv0h + 32 <= qw + 31);
      const bool diag = (kv0h + 63 > qw);
      const char* ksb = (const char*)Ks + hf * 64 * 256;

      f32x16 c0, c1;
#pragma unroll
      for (int r = 0; r < 16; ++r) { c0[r] = 0.f; c1[r] = s1on ? 0.f : NEG; }
      __builtin_amdgcn_s_setprio(1);
#pragma unroll
      for (int d8 = 0; d8 < 8; ++d8) {
        bf16x8 ak = *(const bf16x8*)(ksb + ql * 256 +
                                     (((d8 * 2 + hi) ^ (ql & 7)) << 4));
        c0 = __builtin_amdgcn_mfma_f32_32x32x16_bf16(ak, bq[d8], c0, 0, 0, 0);
      }
      if (s1on) {
#pragma unroll
        for (int d8 = 0; d8 < 8; ++d8) {
          bf16x8 ak = *(const bf16x8*)(ksb + (32 + ql) * 256 +
                                       (((d8 * 2 + hi) ^ (ql & 7)) << 4));
          c1 = __builtin_amdgcn_mfma_f32_32x32x16_bf16(ak, bq[d8], c1, 0, 0, 0);
        }
      }
      __builtin_amdgcn_s_setprio(0);

      if (diag) {
#pragma unroll
        for (int r = 0; r < 16; ++r) {
          int kvl = (r & 3) + 8 * (r >> 2) + 4 * hi;
          if (kv0h + kvl > qg) c0[r] = NEG;
          if (s1on && kv0h + 32 + kvl > qg) c1[r] = NEG;
        }
      }
      float rm = c0[0];
#pragma unroll
      for (int r = 1; r < 16; ++r) rm = fmaxf(rm, c0[r]);
#pragma unroll
      for (int r = 0; r < 16; ++r) rm = fmaxf(rm, c1[r]);
      rm = fmaxf(rm, __shfl_xor(rm, 32));

      if (__any(rm > m_r + TDEF)) {
        float mnew = fmaxf(m_r, rm);
        float alpha = exp2f((m_r - mnew) * Cs);
        m_r = mnew;
        l_r *= alpha;
#pragma unroll
        for (int r = 0; r < 16; ++r) {
          float ar = __shfl(alpha, (r & 3) + 8 * (r >> 2) + 4 * hi);
#pragma unroll
          for (int dt = 0; dt < 4; ++dt) o[dt][r] *= ar;
        }
      }
#pragma unroll
      for (int r = 0; r < 16; ++r) {
        c0[r] = exp2f((c0[r] - m_r) * Cs);
        c1[r] = exp2f((c1[r] - m_r) * Cs);
      }
      float ps = 0.f;
#pragma unroll
      for (int r = 0; r < 16; ++r) ps += c0[r] + c1[r];
      ps += __shfl_xor(ps, 32);
      l_r += ps;

      bf16x8 pa[4];
#pragma unroll
      for (int t4 = 0; t4 < 4; ++t4) {
        const f32x16& cc = (t4 < 2) ? c0 : c1;
        const int rA = (t4 & 1) * 8;
        unsigned int pkL0 = pk2(cc[rA + 0], cc[rA + 1]);
        unsigned int pkL1 = pk2(cc[rA + 2], cc[rA + 3]);
        unsigned int pkH0 = pk2(cc[rA + 4], cc[rA + 5]);
        unsigned int pkH1 = pk2(cc[rA + 6], cc[rA + 7]);
        unsigned int give0 = hi ? pkL0 : pkH0;
        unsigned int give1 = hi ? pkL1 : pkH1;
        unsigned int keep0 = hi ? pkH0 : pkL0;
        unsigned int keep1 = hi ? pkH1 : pkL1;
        unsigned int recv0 = __shfl_xor(give0, 32);
        unsigned int recv1 = __shfl_xor(give1, 32);
        union { unsigned int u[4]; bf16x8 v; } pu;
        pu.u[0] = hi ? recv0 : keep0;
        pu.u[1] = hi ? recv1 : keep1;
        pu.u[2] = hi ? keep0 : recv0;
        pu.u[3] = hi ? keep1 : recv1;
        pa[t4] = pu.v;
      }
      __builtin_amdgcn_s_setprio(1);
#pragma unroll
      for (int t4 = 0; t4 < 4; ++t4) {
        if (diag && kv0h + t4 * 16 > qw + 31) continue;
#pragma unroll
        for (int dt = 0; dt < 4; ++dt) {
          int d = dt * 32 + ql;
          int slot = ((hf << 3) | (t4 << 1) | hi) ^ (d & 7) ^ ((d >> 3) & 7);
          bf16x8 bv = *(const bf16x8*)((const char*)Vt + d * 256 + (slot << 4));
          o[dt] = __builtin_amdgcn_mfma_f32_32x32x16_bf16(pa[t4], bv, o[dt], 0, 0, 0);
        }
      }
      __builtin_amdgcn_s_setprio(0);
    }
  }

  float linv = 1.0f / l_r;
  unsigned short* outp = ctx + (size_t)b * SEQ * EMB + (size_t)h * HDIM;
#pragma unroll
  for (int r = 0; r < 16; ++r) {
    int kvl = (r & 3) + 8 * (r >> 2) + 4 * hi;
    float lr = __shfl(linv, kvl);
    int qrow = qw + kvl;
#pragma unroll
    for (int dt = 0; dt < 4; ++dt)
      outp[(size_t)qrow * EMB + dt * 32 + ql] = f2bf(o[dt][r] * lr);
  }
}

extern "C" void kernel_launch(void* const* d_in, const int* in_sizes, int n_in,
                              void* d_out, int out_size, void* d_ws, size_t ws_size,
                              hipStream_t stream) {
  const float* x  = (const float*)d_in[0];
  const float* Wq = (const float*)d_in[1];
  const float* Wk = (const float*)d_in[2];
  const float* Wv = (const float*)d_in[3];
  const float* Wp = (const float*)d_in[4];
  const float* bp = (const float*)d_in[5];

  char* ws = (char*)d_ws;
  unsigned short* xb = (unsigned short*)ws;                         // 16MB, reused as ctx
  unsigned short* Wb = (unsigned short*)(ws + (size_t)(16u << 20)); // 8MB (Wq, then Wp)
  unsigned short* Pq = (unsigned short*)(ws + (size_t)(24u << 20)); // 3x16MB contiguous
  unsigned short* Pk = (unsigned short*)(ws + (size_t)(40u << 20));
  unsigned short* Pv = (unsigned short*)(ws + (size_t)(56u << 20));
  // d_out (33.5MB fp32) fully rewritten by final GEMM -> first 16MB doubles as
  // scratch for Wv/Wk bf16 during the QKV phase.
  unsigned short* WvS = (unsigned short*)d_out;
  unsigned short* WkS = (unsigned short*)d_out + (size_t)4 * 1024 * 1024;

  const int nX4 = ROWSM * EMB / 4;
  const int nW4 = EMB * EMB / 4;

  cvt_bf16<<<nX4 / 256, 256, 0, stream>>>(x, xb, nX4);
  cvt_bf16_3<<<dim3(nW4 / 256, 1, 3), 256, 0, stream>>>(Wq, Wk, Wv, Wb, WkS, WvS, nW4);

  // QKV: 256x128 tiles -> 16 x 16 x 3 = 768 blocks = exactly 3 full rounds
  gemm8<0><<<dim3(EMB / 128, ROWSM / 256, 3), 512, 0, stream>>>(
      xb, Wb, WkS, WvS, Pq, nullptr);

  attn_causal<<<512, 256, 0, stream>>>(Pq, Pk, Pv, xb);

  cvt_bf16<<<nW4 / 256, 256, 0, stream>>>(Wp, Wb, nW4);
  // P: 16 x 16 = 256 blocks = exactly 1 full round
  gemm8<1><<<dim3(EMB / 128, ROWSM / 256, 1), 512, 0, stream>>>(
      xb, Wb, Wb, Wb, d_out, bp);
}

// Round 14
// 263.938 us; speedup vs baseline: 1.4366x; 1.0135x over previous
//
#include <hip/hip_runtime.h>

#define SEQ   2048
#define EMB   2048
#define NHEAD 16
#define HDIM  128
#define ROWSM 4096  // B*SEQ

typedef float  f32x4   __attribute__((ext_vector_type(4)));
typedef float  f32x16  __attribute__((ext_vector_type(16)));
typedef __bf16 bf16x8  __attribute__((ext_vector_type(8)));

__device__ __forceinline__ unsigned short f2bf(float f) {
  union { float f; unsigned int u; } v; v.f = f;
  return (unsigned short)((v.u + 0x7fffu + ((v.u >> 16) & 1u)) >> 16);
}
__device__ __forceinline__ unsigned int pk2(float a, float b) {
  return (unsigned int)f2bf(a) | ((unsigned int)f2bf(b) << 16);
}

__device__ __forceinline__ void gload16(const void* g, void* l) {
  __builtin_amdgcn_global_load_lds(
      (__attribute__((address_space(1))) const unsigned int*)g,
      (__attribute__((address_space(3))) unsigned int*)l,
      16, 0, 0);
}

// fp32 -> bf16 bulk convert, 4 elems/thread
__global__ void cvt_bf16(const float* __restrict__ in,
                         unsigned short* __restrict__ out, int n4) {
  int i = blockIdx.x * 256 + threadIdx.x;
  if (i >= n4) return;
  float4 v = ((const float4*)in)[i];
  ushort4 o;
  o.x = f2bf(v.x); o.y = f2bf(v.y); o.z = f2bf(v.z); o.w = f2bf(v.w);
  ((ushort4*)out)[i] = o;
}

// three same-size fp32->bf16 converts in one launch (z selects)
__global__ void cvt_bf16_3(const float* __restrict__ i0, const float* __restrict__ i1,
                           const float* __restrict__ i2, unsigned short* __restrict__ o0,
                           unsigned short* __restrict__ o1, unsigned short* __restrict__ o2,
                           int n4) {
  const float* in = (blockIdx.z == 0) ? i0 : (blockIdx.z == 1) ? i1 : i2;
  unsigned short* out = (blockIdx.z == 0) ? o0 : (blockIdx.z == 1) ? o1 : o2;
  int i = blockIdx.x * 256 + threadIdx.x;
  if (i >= n4) return;
  float4 v = ((const float4*)in)[i];
  ushort4 o;
  o.x = f2bf(v.x); o.y = f2bf(v.y); o.z = f2bf(v.z); o.w = f2bf(v.w);
  ((ushort4*)out)[i] = o;
}

// ====== 8-phase BM=256 x BN=128 GEMM with XCD m-band swizzle ======
// Grid: (256, 1, z). bid=blockIdx.x: xcd=bid&7, j=bid>>3, mt=xcd*2+(j>>4),
// nt=j&15 -> each XCD owns 2 m-tiles; its 32 resident blocks share 2 A-panels
// (2MB, L2-fits) and stream B. Round-13 FETCH showed A re-fetched 8x (209MB vs
// 40MB unique) because n-fastest order spread each A-panel across all XCDs.
// Round-6's failed swizzle chunked the N axis (all B on every XCD) — this pins
// the A (M) axis instead. Bijective: 256 blocks per z, 256%8==0.
// Schedule (round-13 proven): 2 phases/K-tile, region-safe 2-deep staging,
// vmcnt at END of phase before closing barrier, never a mid-loop drain (T4);
// T2 swizzle both-sides; T5 setprio; lgkmcnt(0)+sched_barrier(0) (rule #18).
template <int STORE_F32>
__global__ __launch_bounds__(512, 1) void gemm8(
    const unsigned short* __restrict__ A,
    const unsigned short* __restrict__ B0, const unsigned short* __restrict__ B1,
    const unsigned short* __restrict__ B2,
    void* __restrict__ Cbase, const float* __restrict__ bias) {
  __shared__ __align__(16) unsigned short At[2][256 * 64];  // 64KB
  __shared__ __align__(16) unsigned short Bt[2][128 * 64];  // 32KB
  const unsigned short* Bm = (blockIdx.z == 0) ? B0 : (blockIdx.z == 1) ? B1 : B2;

  const int tid  = threadIdx.x;
  const int lane = tid & 63;
  const int w    = tid >> 6;        // 0..7
  const int wr   = w >> 2;          // 0..1 (m half of 256)
  const int wc   = w & 3;           // 0..3 (n quarter of 128)
  const int lg   = lane >> 4;
  const int lc   = lane & 15;

  // XCD m-band decode
  const int bid = blockIdx.x;
  const int xcd = bid & 7;
  const int j   = bid >> 3;         // 0..31
  const int mt  = xcd * 2 + (j >> 4);
  const int nt  = j & 15;
  const int m0 = mt * 256;
  const int n0 = nt * 128;

  const int srow8 = lane >> 3;            // row within 8-row chunk
  const int sslot = (lane & 7) ^ srow8;   // pre-swizzled global 16B slot
  const int NT = EMB / 64;                // 32 K-tiles

  // chunk c = 8 rows x 128B at byte offset c*1024
  auto stageAeven = [&](int ts) {         // rows 0-63 (chunks 0-7) + 128-191 (16-23)
    if (ts >= NT) return;
    int buf = ts & 1, k0 = ts * 64;
    {
      int c = w;        int row = c * 8 + srow8;
      gload16(A + (size_t)(m0 + row) * EMB + k0 + sslot * 8, (char*)&At[buf][0] + c * 1024);
    }
    {
      int c = 16 + w;   int row = c * 8 + srow8;
      gload16(A + (size_t)(m0 + row) * EMB + k0 + sslot * 8, (char*)&At[buf][0] + c * 1024);
    }
  };
  auto stageAodd = [&](int ts) {          // rows 64-127 (chunks 8-15) + 192-255 (24-31)
    if (ts >= NT) return;
    int buf = ts & 1, k0 = ts * 64;
    {
      int c = 8 + w;    int row = c * 8 + srow8;
      gload16(A + (size_t)(m0 + row) * EMB + k0 + sslot * 8, (char*)&At[buf][0] + c * 1024);
    }
    {
      int c = 24 + w;   int row = c * 8 + srow8;
      gload16(A + (size_t)(m0 + row) * EMB + k0 + sslot * 8, (char*)&At[buf][0] + c * 1024);
    }
  };
  auto stageB = [&](int ts) {             // 128 rows (chunks 0-15)
    if (ts >= NT) return;
    int buf = ts & 1, k0 = ts * 64;
    {
      int c = w;        int row = c * 8 + srow8;
      gload16(Bm + (size_t)(n0 + row) * EMB + k0 + sslot * 8, (char*)&Bt[buf][0] + c * 1024);
    }
    {
      int c = 8 + w;    int row = c * 8 + srow8;
      gload16(Bm + (size_t)(n0 + row) * EMB + k0 + sslot * 8, (char*)&Bt[buf][0] + c * 1024);
    }
  };

  f32x4 acc[8][2] = {};
  bf16x8 afr[4][2], bfr[2][2];

  // prologue: AeB(0), Aodd(0), AeB(1) = 10 loads; retire AeB(0); barrier
  stageAeven(0); stageB(0); stageAodd(0); stageAeven(1); stageB(1);
  asm volatile("s_waitcnt vmcnt(6)" ::: "memory");
  __builtin_amdgcn_s_barrier();

  for (int t = 0; t < NT; ++t) {
    const char* ab = (const char*)&At[t & 1][0];
    const char* bb = (const char*)&Bt[t & 1][0];

    // ---------- phase 0: mi 0-3 (A-even region) x full B ----------
#pragma unroll
    for (int ni = 0; ni < 2; ++ni)
#pragma unroll
      for (int kk = 0; kk < 2; ++kk) {
        int row = wc * 32 + ni * 16 + lc;
        bfr[ni][kk] = *(const bf16x8*)(bb + row * 128 + ((((kk << 2) | lg) ^ (lc & 7)) << 4));
      }
#pragma unroll
    for (int mi = 0; mi < 4; ++mi)
#pragma unroll
      for (int kk = 0; kk < 2; ++kk) {
        int row = wr * 128 + mi * 16 + lc;
        afr[mi][kk] = *(const bf16x8*)(ab + row * 128 + ((((kk << 2) | lg) ^ (lc & 7)) << 4));
      }
    stageAodd(t + 1);
    __builtin_amdgcn_s_barrier();
    asm volatile("s_waitcnt lgkmcnt(0)" ::: "memory");
    __builtin_amdgcn_sched_barrier(0);
    __builtin_amdgcn_s_setprio(1);
#pragma unroll
    for (int mi = 0; mi < 4; ++mi)
#pragma unroll
      for (int ni = 0; ni < 2; ++ni)
#pragma unroll
        for (int kk = 0; kk < 2; ++kk)
          acc[mi][ni] = __builtin_amdgcn_mfma_f32_16x16x32_bf16(
              afr[mi][kk], bfr[ni][kk], acc[mi][ni], 0, 0, 0);
    __builtin_amdgcn_s_setprio(0);
    if (t + 1 < NT) asm volatile("s_waitcnt vmcnt(6)" ::: "memory");
    else            asm volatile("s_waitcnt vmcnt(0)" ::: "memory");
    __builtin_amdgcn_s_barrier();

    // ---------- phase 1: mi 4-7 (A-odd region) x B (regs) ----------
#pragma unroll
    for (int mi = 0; mi < 4; ++mi)
#pragma unroll
      for (int kk = 0; kk < 2; ++kk) {
        int row = wr * 128 + 64 + mi * 16 + lc;
        afr[mi][kk] = *(const bf16x8*)(ab + row * 128 + ((((kk << 2) | lg) ^ (lc & 7)) << 4));
      }
    stageAeven(t + 2); stageB(t + 2);
    __builtin_amdgcn_s_barrier();
    asm volatile("s_waitcnt lgkmcnt(0)" ::: "memory");
    __builtin_amdgcn_sched_barrier(0);
    __builtin_amdgcn_s_setprio(1);
#pragma unroll
    for (int mi = 0; mi < 4; ++mi)
#pragma unroll
      for (int ni = 0; ni < 2; ++ni)
#pragma unroll
        for (int kk = 0; kk < 2; ++kk)
          acc[4 + mi][ni] = __builtin_amdgcn_mfma_f32_16x16x32_bf16(
              afr[mi][kk], bfr[ni][kk], acc[4 + mi][ni], 0, 0, 0);
    __builtin_amdgcn_s_setprio(0);
    if (t + 2 < NT)      asm volatile("s_waitcnt vmcnt(6)" ::: "memory");
    else if (t + 1 < NT) asm volatile("s_waitcnt vmcnt(2)" ::: "memory");
    __builtin_amdgcn_s_barrier();
  }

  // epilogue (verified C-layout: row = lg*4+rr, col = lc within each 16x16)
#pragma unroll
  for (int mi = 0; mi < 8; ++mi)
#pragma unroll
    for (int ni = 0; ni < 2; ++ni) {
      int col = n0 + wc * 32 + ni * 16 + lc;
#pragma unroll
      for (int rr = 0; rr < 4; ++rr) {
        int row = m0 + wr * 128 + mi * 16 + lg * 4 + rr;
        if (STORE_F32) {
          ((float*)Cbase)[(size_t)row * EMB + col] = acc[mi][ni][rr] + bias[col];
        } else {
          ((unsigned short*)Cbase + (size_t)blockIdx.z * ROWSM * EMB)
              [(size_t)row * EMB + col] = f2bf(acc[mi][ni][rr]);
        }
      }
    }
}

// Causal flash attention, swapped-QK form, KVBLK=128 — round-9 proven, verbatim.
__global__ __launch_bounds__(256, 2) void attn_causal(
    const unsigned short* __restrict__ Pq, const unsigned short* __restrict__ Pk,
    const unsigned short* __restrict__ Pv, unsigned short* __restrict__ ctx) {
  __shared__ __align__(16) unsigned short Ks[128 * 128];
  __shared__ __align__(16) unsigned short Vt[128 * 128];

  const int tid  = threadIdx.x;
  const int lane = tid & 63;
  const int w    = tid >> 6;
  const int ql   = lane & 31;
  const int hi   = lane >> 5;
  const int lg   = lane >> 4;
  const int lc   = lane & 15;

  const int bid = blockIdx.x;
  const int xcd = bid & 7;
  const int jj_ = bid >> 3;
  const int hh  = jj_ >> 4;
  const int bh  = xcd * 4 + hh;
  const int b   = bh >> 4;
  const int h   = bh & 15;
  const int qtr = jj_ & 15;
  const int qt  = (hh >= 2) ? (15 - qtr) : qtr;
  const int q0 = qt * 128;
  const int qw = q0 + w * 32;
  const int qg = qw + ql;

  const size_t hoff = (size_t)bh * SEQ * HDIM;
  const unsigned short* Q  = Pq + hoff;
  const unsigned short* Kh = Pk + hoff;
  const unsigned short* Vh = Pv + hoff;

  bf16x8 bq[8];
#pragma unroll
  for (int d8 = 0; d8 < 8; ++d8)
    bq[d8] = *(const bf16x8*)(Q + (size_t)qg * HDIM + d8 * 16 + hi * 8);

  const float NEG = -3.0e38f;
  f32x16 o[4];
#pragma unroll
  for (int dt = 0; dt < 4; ++dt)
#pragma unroll
    for (int r = 0; r < 16; ++r) o[dt][r] = 0.f;
  float m_r = NEG, l_r = 0.f;

  const float Cs   = 0.12753123161692858f;
  const float TDEF = 62.7f;

  const int nt128 = qt + 1;
  for (int tt = 0; tt < nt128; ++tt) {
    const int kv0 = tt * 128;
    if (tt) __syncthreads();
#pragma unroll
    for (int ii = 0; ii < 8; ++ii) {
      int i = w * 8 + ii;
      int r = i * 4 + lg;
      int sd = lc ^ (r & 7);
      gload16(Kh + (size_t)(kv0 + r) * HDIM + sd * 8, (char*)Ks + i * 1024);
    }
#pragma unroll 1
    for (int hv = 0; hv < 2; ++hv) {
      uint4 vr[4];
      const unsigned short* Vs = Vh + (size_t)(kv0 + hv * 64) * HDIM;
#pragma unroll
      for (int uu = 0; uu < 2; ++uu) {
        int u = tid + uu * 256;
        int kp = u >> 4, dg = u & 15;
        int k = kp * 2, d0 = dg * 8;
        vr[uu * 2]     = *(const uint4*)(Vs + (size_t)k * HDIM + d0);
        vr[uu * 2 + 1] = *(const uint4*)(Vs + (size_t)(k + 1) * HDIM + d0);
      }
#pragma unroll
      for (int uu = 0; uu < 2; ++uu) {
        int u = tid + uu * 256;
        int kp = u >> 4, dg = u & 15;
        int k = kp * 2, d0 = dg * 8;
        const unsigned short* e0 = (const unsigned short*)&vr[uu * 2];
        const unsigned short* e1 = (const unsigned short*)&vr[uu * 2 + 1];
#pragma unroll
        for (int jj = 0; jj < 8; ++jj) {
          int d = d0 + jj;
          int slot = ((hv << 3) | (k >> 3)) ^ jj ^ (dg & 7);
          int byteoff = d * 256 + (slot << 4) + (k & 7) * 2;
          *(unsigned int*)((char*)Vt + byteoff) =
              (unsigned int)e0[jj] | ((unsigned int)e1[jj] << 16);
        }
      }
    }
    __syncthreads();

#pragma unroll 1
    for (int hf = 0; hf < 2; ++hf) {
      const int kv0h = kv0 + hf * 64;
      if (kv0h > qw + 31) continue;
      const bool s1on = (kv0h + 32 <= qw + 31);
      const bool diag = (kv0h + 63 > qw);
      const char* ksb = (const char*)Ks + hf * 64 * 256;

      f32x16 c0, c1;
#pragma unroll
      for (int r = 0; r < 16; ++r) { c0[r] = 0.f; c1[r] = s1on ? 0.f : NEG; }
      __builtin_amdgcn_s_setprio(1);
#pragma unroll
      for (int d8 = 0; d8 < 8; ++d8) {
        bf16x8 ak = *(const bf16x8*)(ksb + ql * 256 +
                                     (((d8 * 2 + hi) ^ (ql & 7)) << 4));
        c0 = __builtin_amdgcn_mfma_f32_32x32x16_bf16(ak, bq[d8], c0, 0, 0, 0);
      }
      if (s1on) {
#pragma unroll
        for (int d8 = 0; d8 < 8; ++d8) {
          bf16x8 ak = *(const bf16x8*)(ksb + (32 + ql) * 256 +
                                       (((d8 * 2 + hi) ^ (ql & 7)) << 4));
          c1 = __builtin_amdgcn_mfma_f32_32x32x16_bf16(ak, bq[d8], c1, 0, 0, 0);
        }
      }
      __builtin_amdgcn_s_setprio(0);

      if (diag) {
#pragma unroll
        for (int r = 0; r < 16; ++r) {
          int kvl = (r & 3) + 8 * (r >> 2) + 4 * hi;
          if (kv0h + kvl > qg) c0[r] = NEG;
          if (s1on && kv0h + 32 + kvl > qg) c1[r] = NEG;
        }
      }
      float rm = c0[0];
#pragma unroll
      for (int r = 1; r < 16; ++r) rm = fmaxf(rm, c0[r]);
#pragma unroll
      for (int r = 0; r < 16; ++r) rm = fmaxf(rm, c1[r]);
      rm = fmaxf(rm, __shfl_xor(rm, 32));

      if (__any(rm > m_r + TDEF)) {
        float mnew = fmaxf(m_r, rm);
        float alpha = exp2f((m_r - mnew) * Cs);
        m_r = mnew;
        l_r *= alpha;
#pragma unroll
        for (int r = 0; r < 16; ++r) {
          float ar = __shfl(alpha, (r & 3) + 8 * (r >> 2) + 4 * hi);
#pragma unroll
          for (int dt = 0; dt < 4; ++dt) o[dt][r] *= ar;
        }
      }
#pragma unroll
      for (int r = 0; r < 16; ++r) {
        c0[r] = exp2f((c0[r] - m_r) * Cs);
        c1[r] = exp2f((c1[r] - m_r) * Cs);
      }
      float ps = 0.f;
#pragma unroll
      for (int r = 0; r < 16; ++r) ps += c0[r] + c1[r];
      ps += __shfl_xor(ps, 32);
      l_r += ps;

      bf16x8 pa[4];
#pragma unroll
      for (int t4 = 0; t4 < 4; ++t4) {
        const f32x16& cc = (t4 < 2) ? c0 : c1;
        const int rA = (t4 & 1) * 8;
        unsigned int pkL0 = pk2(cc[rA + 0], cc[rA + 1]);
        unsigned int pkL1 = pk2(cc[rA + 2], cc[rA + 3]);
        unsigned int pkH0 = pk2(cc[rA + 4], cc[rA + 5]);
        unsigned int pkH1 = pk2(cc[rA + 6], cc[rA + 7]);
        unsigned int give0 = hi ? pkL0 : pkH0;
        unsigned int give1 = hi ? pkL1 : pkH1;
        unsigned int keep0 = hi ? pkH0 : pkL0;
        unsigned int keep1 = hi ? pkH1 : pkL1;
        unsigned int recv0 = __shfl_xor(give0, 32);
        unsigned int recv1 = __shfl_xor(give1, 32);
        union { unsigned int u[4]; bf16x8 v; } pu;
        pu.u[0] = hi ? recv0 : keep0;
        pu.u[1] = hi ? recv1 : keep1;
        pu.u[2] = hi ? keep0 : recv0;
        pu.u[3] = hi ? keep1 : recv1;
        pa[t4] = pu.v;
      }
      __builtin_amdgcn_s_setprio(1);
#pragma unroll
      for (int t4 = 0; t4 < 4; ++t4) {
        if (diag && kv0h + t4 * 16 > qw + 31) continue;
#pragma unroll
        for (int dt = 0; dt < 4; ++dt) {
          int d = dt * 32 + ql;
          int slot = ((hf << 3) | (t4 << 1) | hi) ^ (d & 7) ^ ((d >> 3) & 7);
          bf16x8 bv = *(const bf16x8*)((const char*)Vt + d * 256 + (slot << 4));
          o[dt] = __builtin_amdgcn_mfma_f32_32x32x16_bf16(pa[t4], bv, o[dt], 0, 0, 0);
        }
      }
      __builtin_amdgcn_s_setprio(0);
    }
  }

  float linv = 1.0f / l_r;
  unsigned short* outp = ctx + (size_t)b * SEQ * EMB + (size_t)h * HDIM;
#pragma unroll
  for (int r = 0; r < 16; ++r) {
    int kvl = (r & 3) + 8 * (r >> 2) + 4 * hi;
    float lr = __shfl(linv, kvl);
    int qrow = qw + kvl;
#pragma unroll
    for (int dt = 0; dt < 4; ++dt)
      outp[(size_t)qrow * EMB + dt * 32 + ql] = f2bf(o[dt][r] * lr);
  }
}

extern "C" void kernel_launch(void* const* d_in, const int* in_sizes, int n_in,
                              void* d_out, int out_size, void* d_ws, size_t ws_size,
                              hipStream_t stream) {
  const float* x  = (const float*)d_in[0];
  const float* Wq = (const float*)d_in[1];
  const float* Wk = (const float*)d_in[2];
  const float* Wv = (const float*)d_in[3];
  const float* Wp = (const float*)d_in[4];
  const float* bp = (const float*)d_in[5];

  char* ws = (char*)d_ws;
  unsigned short* xb = (unsigned short*)ws;                         // 16MB, reused as ctx
  unsigned short* Wb = (unsigned short*)(ws + (size_t)(16u << 20)); // 8MB (Wq, then Wp)
  unsigned short* Pq = (unsigned short*)(ws + (size_t)(24u << 20)); // 3x16MB contiguous
  unsigned short* Pk = (unsigned short*)(ws + (size_t)(40u << 20));
  unsigned short* Pv = (unsigned short*)(ws + (size_t)(56u << 20));
  // d_out (33.5MB fp32) fully rewritten by final GEMM -> first 16MB doubles as
  // scratch for Wv/Wk bf16 during the QKV phase.
  unsigned short* WvS = (unsigned short*)d_out;
  unsigned short* WkS = (unsigned short*)d_out + (size_t)4 * 1024 * 1024;

  const int nX4 = ROWSM * EMB / 4;
  const int nW4 = EMB * EMB / 4;

  cvt_bf16<<<nX4 / 256, 256, 0, stream>>>(x, xb, nX4);
  cvt_bf16_3<<<dim3(nW4 / 256, 1, 3), 256, 0, stream>>>(Wq, Wk, Wv, Wb, WkS, WvS, nW4);

  // QKV: 256x128 tiles, 1D grid of 256 per z (XCD m-band swizzled in-kernel)
  gemm8<0><<<dim3(256, 1, 3), 512, 0, stream>>>(xb, Wb, WkS, WvS, Pq, nullptr);

  attn_causal<<<512, 256, 0, stream>>>(Pq, Pk, Pv, xb);

  cvt_bf16<<<nW4 / 256, 256, 0, stream>>>(Wp, Wb, nW4);
  // P: 256 blocks, same swizzle
  gemm8<1><<<dim3(256, 1, 1), 512, 0, stream>>>(xb, Wb, Wb, Wb, d_out, bp);
}

// Round 15
// 262.280 us; speedup vs baseline: 1.4457x; 1.0063x over previous
//
#include <hip/hip_runtime.h>

#define SEQ   2048
#define EMB   2048
#define NHEAD 16
#define HDIM  128
#define ROWSM 4096  // B*SEQ

typedef float  f32x4   __attribute__((ext_vector_type(4)));
typedef float  f32x16  __attribute__((ext_vector_type(16)));
typedef __bf16 bf16x8  __attribute__((ext_vector_type(8)));

__device__ __forceinline__ unsigned short f2bf(float f) {
  union { float f; unsigned int u; } v; v.f = f;
  return (unsigned short)((v.u + 0x7fffu + ((v.u >> 16) & 1u)) >> 16);
}
__device__ __forceinline__ unsigned int pk2(float a, float b) {
  return (unsigned int)f2bf(a) | ((unsigned int)f2bf(b) << 16);
}

__device__ __forceinline__ void gload16(const void* g, void* l) {
  __builtin_amdgcn_global_load_lds(
      (__attribute__((address_space(1))) const unsigned int*)g,
      (__attribute__((address_space(3))) unsigned int*)l,
      16, 0, 0);
}

// fp32 -> bf16 bulk convert, 4 elems/thread
__global__ void cvt_bf16(const float* __restrict__ in,
                         unsigned short* __restrict__ out, int n4) {
  int i = blockIdx.x * 256 + threadIdx.x;
  if (i >= n4) return;
  float4 v = ((const float4*)in)[i];
  ushort4 o;
  o.x = f2bf(v.x); o.y = f2bf(v.y); o.z = f2bf(v.z); o.w = f2bf(v.w);
  ((ushort4*)out)[i] = o;
}

// three same-size fp32->bf16 converts in one launch (z selects)
__global__ void cvt_bf16_3(const float* __restrict__ i0, const float* __restrict__ i1,
                           const float* __restrict__ i2, unsigned short* __restrict__ o0,
                           unsigned short* __restrict__ o1, unsigned short* __restrict__ o2,
                           int n4) {
  const float* in = (blockIdx.z == 0) ? i0 : (blockIdx.z == 1) ? i1 : i2;
  unsigned short* out = (blockIdx.z == 0) ? o0 : (blockIdx.z == 1) ? o1 : o2;
  int i = blockIdx.x * 256 + threadIdx.x;
  if (i >= n4) return;
  float4 v = ((const float4*)in)[i];
  ushort4 o;
  o.x = f2bf(v.x); o.y = f2bf(v.y); o.z = f2bf(v.z); o.w = f2bf(v.w);
  ((ushort4*)out)[i] = o;
}

// ====== 8-phase BM=128 x BN=256 GEMM: per-wave 64x64, 0.5 ds_reads/MFMA ======
// Geometry rationale (round-14 post-mortem): ds_read_b128 ~12cy vs MFMA ~4.8cy
// -> per-wave 128x32 (0.625 reads/MFMA) is LDS-pipe-bound at 36% MfmaUtil;
// per-wave 64x64 gives 16 reads/32 MFMA = 0.5. Grid 32x8 = 256 blocks per z ->
// 768 = 3 EXACT rounds (QKV) / 256 = 1 round (P) — round 12's 1.5-round tail
// diluted its counter (true per-block util ~48%, not 36).
// Schedule ISOMORPHIC to round-13's proven ledger (A<->B roles swapped):
//   ph0(t): reads all-A(t) + B-low(t); stages Bhigh(t+1) [2 loads]
//   ph1(t): reads B-high(t) (A,Blow reused from regs); stages A(t+2)+Blow(t+2) [4]
// vmcnt(6) at END of each phase before closing barrier; tail 6->2->0; NEVER a
// mid-loop drain (T4). Region safety: A(t)/Blow(t) fully consumed in ph0 ->
// ph1 may overwrite same-parity A/Blow; Bhigh(t+1) is opposite parity.
// T2 swizzle both-sides; T5 setprio; lgkmcnt(0)+sched_barrier(0) (rule #18).
// XCD m-band: xcd owns 4 m-tiles (512 rows, 2MB A -> L2-fit; round-14 proven).
template <int STORE_F32>
__global__ __launch_bounds__(512, 1) void gemm8(
    const unsigned short* __restrict__ A,
    const unsigned short* __restrict__ B0, const unsigned short* __restrict__ B1,
    const unsigned short* __restrict__ B2,
    void* __restrict__ Cbase, const float* __restrict__ bias) {
  __shared__ __align__(16) unsigned short At[2][128 * 64];  // 32KB
  __shared__ __align__(16) unsigned short Bt[2][256 * 64];  // 64KB
  const unsigned short* Bm = (blockIdx.z == 0) ? B0 : (blockIdx.z == 1) ? B1 : B2;

  const int tid  = threadIdx.x;
  const int lane = tid & 63;
  const int w    = tid >> 6;        // 0..7
  const int wr   = w >> 2;          // 0..1 (m half of 128)
  const int wc   = w & 3;           // 0..3 (n quarter of 256)
  const int lg   = lane >> 4;
  const int lc   = lane & 15;

  // XCD m-band decode: 256 blocks, xcd owns 4 consecutive m-tiles
  const int bid = blockIdx.x;
  const int xcd = bid & 7;
  const int j   = bid >> 3;         // 0..31
  const int mt  = xcd * 4 + (j >> 3);
  const int nt  = j & 7;
  const int m0 = mt * 128;
  const int n0 = nt * 256;

  const int srow8 = lane >> 3;            // row within 8-row chunk
  const int sslot = (lane & 7) ^ srow8;   // pre-swizzled global 16B slot
  const int NT = EMB / 64;                // 32 K-tiles

  // chunk = 8 rows x 128B at byte offset c*1024
  auto stageA = [&](int ts) {             // 128 rows = chunks 0-15
    if (ts >= NT) return;
    int buf = ts & 1, k0 = ts * 64;
#pragma unroll
    for (int rr = 0; rr < 2; ++rr) {
      int c = w + rr * 8;
      int row = c * 8 + srow8;
      gload16(A + (size_t)(m0 + row) * EMB + k0 + sslot * 8, (char*)&At[buf][0] + c * 1024);
    }
  };
  auto stageBlow = [&](int ts) {          // rows with (row&63)<32: chunks (c&7)<4
    if (ts >= NT) return;
    int buf = ts & 1, k0 = ts * 64;
#pragma unroll
    for (int rr = 0; rr < 2; ++rr) {
      int i = w + rr * 8;                 // 0..15
      int c = (i >> 2) * 8 + (i & 3);
      int row = c * 8 + srow8;
      gload16(Bm + (size_t)(n0 + row) * EMB + k0 + sslot * 8, (char*)&Bt[buf][0] + c * 1024);
    }
  };
  auto stageBhigh = [&](int ts) {         // rows with (row&63)>=32: chunks (c&7)>=4
    if (ts >= NT) return;
    int buf = ts & 1, k0 = ts * 64;
#pragma unroll
    for (int rr = 0; rr < 2; ++rr) {
      int i = w + rr * 8;
      int c = (i >> 2) * 8 + 4 + (i & 3);
      int row = c * 8 + srow8;
      gload16(Bm + (size_t)(n0 + row) * EMB + k0 + sslot * 8, (char*)&Bt[buf][0] + c * 1024);
    }
  };

  f32x4 acc[4][4] = {};
  bf16x8 afr[4][2], bfr0[2][2], bfr1[2][2];

  // prologue: A(0),Blow(0) | Bhigh(0) | A(1),Blow(1) = 10 loads; retire first 4
  stageA(0); stageBlow(0); stageBhigh(0); stageA(1); stageBlow(1);
  asm volatile("s_waitcnt vmcnt(6)" ::: "memory");
  __builtin_amdgcn_s_barrier();

  for (int t = 0; t < NT; ++t) {
    const char* ab = (const char*)&At[t & 1][0];
    const char* bb = (const char*)&Bt[t & 1][0];

    // ---------- phase 0: ni 0-1 (B-low) x all A ----------
#pragma unroll
    for (int ni = 0; ni < 2; ++ni)
#pragma unroll
      for (int kk = 0; kk < 2; ++kk) {
        int row = wc * 64 + ni * 16 + lc;
        bfr0[ni][kk] = *(const bf16x8*)(bb + row * 128 + ((((kk << 2) | lg) ^ (lc & 7)) << 4));
      }
#pragma unroll
    for (int mi = 0; mi < 4; ++mi)
#pragma unroll
      for (int kk = 0; kk < 2; ++kk) {
        int row = wr * 64 + mi * 16 + lc;
        afr[mi][kk] = *(const bf16x8*)(ab + row * 128 + ((((kk << 2) | lg) ^ (lc & 7)) << 4));
      }
    stageBhigh(t + 1);
    __builtin_amdgcn_s_barrier();
    asm volatile("s_waitcnt lgkmcnt(0)" ::: "memory");
    __builtin_amdgcn_sched_barrier(0);
    __builtin_amdgcn_s_setprio(1);
#pragma unroll
    for (int mi = 0; mi < 4; ++mi)
#pragma unroll
      for (int ni = 0; ni < 2; ++ni)
#pragma unroll
        for (int kk = 0; kk < 2; ++kk)
          acc[mi][ni] = __builtin_amdgcn_mfma_f32_16x16x32_bf16(
              afr[mi][kk], bfr0[ni][kk], acc[mi][ni], 0, 0, 0);
    __builtin_amdgcn_s_setprio(0);
    if (t + 1 < NT) asm volatile("s_waitcnt vmcnt(6)" ::: "memory");
    else            asm volatile("s_waitcnt vmcnt(0)" ::: "memory");
    __builtin_amdgcn_s_barrier();

    // ---------- phase 1: ni 2-3 (B-high) x A (regs) ----------
#pragma unroll
    for (int ni = 0; ni < 2; ++ni)
#pragma unroll
      for (int kk = 0; kk < 2; ++kk) {
        int row = wc * 64 + 32 + ni * 16 + lc;
        bfr1[ni][kk] = *(const bf16x8*)(bb + row * 128 + ((((kk << 2) | lg) ^ (lc & 7)) << 4));
      }
    stageA(t + 2); stageBlow(t + 2);
    __builtin_amdgcn_s_barrier();
    asm volatile("s_waitcnt lgkmcnt(0)" ::: "memory");
    __builtin_amdgcn_sched_barrier(0);
    __builtin_amdgcn_s_setprio(1);
#pragma unroll
    for (int mi = 0; mi < 4; ++mi)
#pragma unroll
      for (int ni = 0; ni < 2; ++ni)
#pragma unroll
        for (int kk = 0; kk < 2; ++kk)
          acc[mi][2 + ni] = __builtin_amdgcn_mfma_f32_16x16x32_bf16(
              afr[mi][kk], bfr1[ni][kk], acc[mi][2 + ni], 0, 0, 0);
    __builtin_amdgcn_s_setprio(0);
    if (t + 2 < NT)      asm volatile("s_waitcnt vmcnt(6)" ::: "memory");
    else if (t + 1 < NT) asm volatile("s_waitcnt vmcnt(2)" ::: "memory");
    __builtin_amdgcn_s_barrier();
  }

  // epilogue (verified C-layout: row = lg*4+rr, col = lc within each 16x16)
#pragma unroll
  for (int mi = 0; mi < 4; ++mi)
#pragma unroll
    for (int ni = 0; ni < 4; ++ni) {
      int col = n0 + wc * 64 + ((ni >> 1) * 32) + (ni & 1) * 16 + lc;
#pragma unroll
      for (int rr = 0; rr < 4; ++rr) {
        int row = m0 + wr * 64 + mi * 16 + lg * 4 + rr;
        if (STORE_F32) {
          ((float*)Cbase)[(size_t)row * EMB + col] = acc[mi][ni][rr] + bias[col];
        } else {
          ((unsigned short*)Cbase + (size_t)blockIdx.z * ROWSM * EMB)
              [(size_t)row * EMB + col] = f2bf(acc[mi][ni][rr]);
        }
      }
    }
}

// Causal flash attention, swapped-QK form, KVBLK=128 — round-9 proven, verbatim.
__global__ __launch_bounds__(256, 2) void attn_causal(
    const unsigned short* __restrict__ Pq, const unsigned short* __restrict__ Pk,
    const unsigned short* __restrict__ Pv, unsigned short* __restrict__ ctx) {
  __shared__ __align__(16) unsigned short Ks[128 * 128];
  __shared__ __align__(16) unsigned short Vt[128 * 128];

  const int tid  = threadIdx.x;
  const int lane = tid & 63;
  const int w    = tid >> 6;
  const int ql   = lane & 31;
  const int hi   = lane >> 5;
  const int lg   = lane >> 4;
  const int lc   = lane & 15;

  const int bid = blockIdx.x;
  const int xcd = bid & 7;
  const int jj_ = bid >> 3;
  const int hh  = jj_ >> 4;
  const int bh  = xcd * 4 + hh;
  const int b   = bh >> 4;
  const int h   = bh & 15;
  const int qtr = jj_ & 15;
  const int qt  = (hh >= 2) ? (15 - qtr) : qtr;
  const int q0 = qt * 128;
  const int qw = q0 + w * 32;
  const int qg = qw + ql;

  const size_t hoff = (size_t)bh * SEQ * HDIM;
  const unsigned short* Q  = Pq + hoff;
  const unsigned short* Kh = Pk + hoff;
  const unsigned short* Vh = Pv + hoff;

  bf16x8 bq[8];
#pragma unroll
  for (int d8 = 0; d8 < 8; ++d8)
    bq[d8] = *(const bf16x8*)(Q + (size_t)qg * HDIM + d8 * 16 + hi * 8);

  const float NEG = -3.0e38f;
  f32x16 o[4];
#pragma unroll
  for (int dt = 0; dt < 4; ++dt)
#pragma unroll
    for (int r = 0; r < 16; ++r) o[dt][r] = 0.f;
  float m_r = NEG, l_r = 0.f;

  const float Cs   = 0.12753123161692858f;
  const float TDEF = 62.7f;

  const int nt128 = qt + 1;
  for (int tt = 0; tt < nt128; ++tt) {
    const int kv0 = tt * 128;
    if (tt) __syncthreads();
#pragma unroll
    for (int ii = 0; ii < 8; ++ii) {
      int i = w * 8 + ii;
      int r = i * 4 + lg;
      int sd = lc ^ (r & 7);
      gload16(Kh + (size_t)(kv0 + r) * HDIM + sd * 8, (char*)Ks + i * 1024);
    }
#pragma unroll 1
    for (int hv = 0; hv < 2; ++hv) {
      uint4 vr[4];
      const unsigned short* Vs = Vh + (size_t)(kv0 + hv * 64) * HDIM;
#pragma unroll
      for (int uu = 0; uu < 2; ++uu) {
        int u = tid + uu * 256;
        int kp = u >> 4, dg = u & 15;
        int k = kp * 2, d0 = dg * 8;
        vr[uu * 2]     = *(const uint4*)(Vs + (size_t)k * HDIM + d0);
        vr[uu * 2 + 1] = *(const uint4*)(Vs + (size_t)(k + 1) * HDIM + d0);
      }
#pragma unroll
      for (int uu = 0; uu < 2; ++uu) {
        int u = tid + uu * 256;
        int kp = u >> 4, dg = u & 15;
        int k = kp * 2, d0 = dg * 8;
        const unsigned short* e0 = (const unsigned short*)&vr[uu * 2];
        const unsigned short* e1 = (const unsigned short*)&vr[uu * 2 + 1];
#pragma unroll
        for (int jj = 0; jj < 8; ++jj) {
          int d = d0 + jj;
          int slot = ((hv << 3) | (k >> 3)) ^ jj ^ (dg & 7);
          int byteoff = d * 256 + (slot << 4) + (k & 7) * 2;
          *(unsigned int*)((char*)Vt + byteoff) =
              (unsigned int)e0[jj] | ((unsigned int)e1[jj] << 16);
        }
      }
    }
    __syncthreads();

#pragma unroll 1
    for (int hf = 0; hf < 2; ++hf) {
      const int kv0h = kv0 + hf * 64;
      if (kv0h > qw + 31) continue;
      const bool s1on = (kv0h + 32 <= qw + 31);
      const bool diag = (kv0h + 63 > qw);
      const char* ksb = (const char*)Ks + hf * 64 * 256;

      f32x16 c0, c1;
#pragma unroll
      for (int r = 0; r < 16; ++r) { c0[r] = 0.f; c1[r] = s1on ? 0.f : NEG; }
      __builtin_amdgcn_s_setprio(1);
#pragma unroll
      for (int d8 = 0; d8 < 8; ++d8) {
        bf16x8 ak = *(const bf16x8*)(ksb + ql * 256 +
                                     (((d8 * 2 + hi) ^ (ql & 7)) << 4));
        c0 = __builtin_amdgcn_mfma_f32_32x32x16_bf16(ak, bq[d8], c0, 0, 0, 0);
      }
      if (s1on) {
#pragma unroll
        for (int d8 = 0; d8 < 8; ++d8) {
          bf16x8 ak = *(const bf16x8*)(ksb + (32 + ql) * 256 +
                                       (((d8 * 2 + hi) ^ (ql & 7)) << 4));
          c1 = __builtin_amdgcn_mfma_f32_32x32x16_bf16(ak, bq[d8], c1, 0, 0, 0);
        }
      }
      __builtin_amdgcn_s_setprio(0);

      if (diag) {
#pragma unroll
        for (int r = 0; r < 16; ++r) {
          int kvl = (r & 3) + 8 * (r >> 2) + 4 * hi;
          if (kv0h + kvl > qg) c0[r] = NEG;
          if (s1on && kv0h + 32 + kvl > qg) c1[r] = NEG;
        }
      }
      float rm = c0[0];
#pragma unroll
      for (int r = 1; r < 16; ++r) rm = fmaxf(rm, c0[r]);
#pragma unroll
      for (int r = 0; r < 16; ++r) rm = fmaxf(rm, c1[r]);
      rm = fmaxf(rm, __shfl_xor(rm, 32));

      if (__any(rm > m_r + TDEF)) {
        float mnew = fmaxf(m_r, rm);
        float alpha = exp2f((m_r - mnew) * Cs);
        m_r = mnew;
        l_r *= alpha;
#pragma unroll
        for (int r = 0; r < 16; ++r) {
          float ar = __shfl(alpha, (r & 3) + 8 * (r >> 2) + 4 * hi);
#pragma unroll
          for (int dt = 0; dt < 4; ++dt) o[dt][r] *= ar;
        }
      }
#pragma unroll
      for (int r = 0; r < 16; ++r) {
        c0[r] = exp2f((c0[r] - m_r) * Cs);
        c1[r] = exp2f((c1[r] - m_r) * Cs);
      }
      float ps = 0.f;
#pragma unroll
      for (int r = 0; r < 16; ++r) ps += c0[r] + c1[r];
      ps += __shfl_xor(ps, 32);
      l_r += ps;

      bf16x8 pa[4];
#pragma unroll
      for (int t4 = 0; t4 < 4; ++t4) {
        const f32x16& cc = (t4 < 2) ? c0 : c1;
        const int rA = (t4 & 1) * 8;
        unsigned int pkL0 = pk2(cc[rA + 0], cc[rA + 1]);
        unsigned int pkL1 = pk2(cc[rA + 2], cc[rA + 3]);
        unsigned int pkH0 = pk2(cc[rA + 4], cc[rA + 5]);
        unsigned int pkH1 = pk2(cc[rA + 6], cc[rA + 7]);
        unsigned int give0 = hi ? pkL0 : pkH0;
        unsigned int give1 = hi ? pkL1 : pkH1;
        unsigned int keep0 = hi ? pkH0 : pkL0;
        unsigned int keep1 = hi ? pkH1 : pkL1;
        unsigned int recv0 = __shfl_xor(give0, 32);
        unsigned int recv1 = __shfl_xor(give1, 32);
        union { unsigned int u[4]; bf16x8 v; } pu;
        pu.u[0] = hi ? recv0 : keep0;
        pu.u[1] = hi ? recv1 : keep1;
        pu.u[2] = hi ? keep0 : recv0;
        pu.u[3] = hi ? keep1 : recv1;
        pa[t4] = pu.v;
      }
      __builtin_amdgcn_s_setprio(1);
#pragma unroll
      for (int t4 = 0; t4 < 4; ++t4) {
        if (diag && kv0h + t4 * 16 > qw + 31) continue;
#pragma unroll
        for (int dt = 0; dt < 4; ++dt) {
          int d = dt * 32 + ql;
          int slot = ((hf << 3) | (t4 << 1) | hi) ^ (d & 7) ^ ((d >> 3) & 7);
          bf16x8 bv = *(const bf16x8*)((const char*)Vt + d * 256 + (slot << 4));
          o[dt] = __builtin_amdgcn_mfma_f32_32x32x16_bf16(pa[t4], bv, o[dt], 0, 0, 0);
        }
      }
      __builtin_amdgcn_s_setprio(0);
    }
  }

  float linv = 1.0f / l_r;
  unsigned short* outp = ctx + (size_t)b * SEQ * EMB + (size_t)h * HDIM;
#pragma unroll
  for (int r = 0; r < 16; ++r) {
    int kvl = (r & 3) + 8 * (r >> 2) + 4 * hi;
    float lr = __shfl(linv, kvl);
    int qrow = qw + kvl;
#pragma unroll
    for (int dt = 0; dt < 4; ++dt)
      outp[(size_t)qrow * EMB + dt * 32 + ql] = f2bf(o[dt][r] * lr);
  }
}

extern "C" void kernel_launch(void* const* d_in, const int* in_sizes, int n_in,
                              void* d_out, int out_size, void* d_ws, size_t ws_size,
                              hipStream_t stream) {
  const float* x  = (const float*)d_in[0];
  const float* Wq = (const float*)d_in[1];
  const float* Wk = (const float*)d_in[2];
  const float* Wv = (const float*)d_in[3];
  const float* Wp = (const float*)d_in[4];
  const float* bp = (const float*)d_in[5];

  char* ws = (char*)d_ws;
  unsigned short* xb = (unsigned short*)ws;                         // 16MB, reused as ctx
  unsigned short* Wb = (unsigned short*)(ws + (size_t)(16u << 20)); // 8MB (Wq, then Wp)
  unsigned short* Pq = (unsigned short*)(ws + (size_t)(24u << 20)); // 3x16MB contiguous
  unsigned short* Pk = (unsigned short*)(ws + (size_t)(40u << 20));
  unsigned short* Pv = (unsigned short*)(ws + (size_t)(56u << 20));
  // d_out (33.5MB fp32) fully rewritten by final GEMM -> first 16MB doubles as
  // scratch for Wv/Wk bf16 during the QKV phase.
  unsigned short* WvS = (unsigned short*)d_out;
  unsigned short* WkS = (unsigned short*)d_out + (size_t)4 * 1024 * 1024;

  const int nX4 = ROWSM * EMB / 4;
  const int nW4 = EMB * EMB / 4;

  cvt_bf16<<<nX4 / 256, 256, 0, stream>>>(x, xb, nX4);
  cvt_bf16_3<<<dim3(nW4 / 256, 1, 3), 256, 0, stream>>>(Wq, Wk, Wv, Wb, WkS, WvS, nW4);

  // QKV: 128x256 tiles, 256 blocks per z (XCD m-band) -> 768 = 3 exact rounds
  gemm8<0><<<dim3(256, 1, 3), 512, 0, stream>>>(xb, Wb, WkS, WvS, Pq, nullptr);

  attn_causal<<<512, 256, 0, stream>>>(Pq, Pk, Pv, xb);

  cvt_bf16<<<nW4 / 256, 256, 0, stream>>>(Wp, Wb, nW4);
  // P: 256 blocks = 1 exact round
  gemm8<1><<<dim3(256, 1, 1), 512, 0, stream>>>(xb, Wb, Wb, Wb, d_out, bp);
}

// Round 16
// 260.946 us; speedup vs baseline: 1.4531x; 1.0051x over previous
//
#include <hip/hip_runtime.h>

#define SEQ   2048
#define EMB   2048
#define NHEAD 16
#define HDIM  128
#define ROWSM 4096  // B*SEQ

typedef float  f32x4   __attribute__((ext_vector_type(4)));
typedef float  f32x16  __attribute__((ext_vector_type(16)));
typedef __bf16 bf16x8  __attribute__((ext_vector_type(8)));

// NATIVE RNE f32->bf16: compiler fuses pairs into v_cvt_pk_bf16_f32 (m240).
// Round-6..15 regression: manual 4-op bit-RNE sat in attn's per-tile pack path
// (~160 VALU ops/half-tile). Native cast = same rounding, ~5x fewer ops.
__device__ __forceinline__ unsigned short f2bf(float f) {
  union { __bf16 b; unsigned short u; } v; v.b = (__bf16)f; return v.u;
}
__device__ __forceinline__ unsigned int pk2(float a, float b) {
  return (unsigned int)f2bf(a) | ((unsigned int)f2bf(b) << 16);
}
__device__ __forceinline__ float max3f(float a, float b, float c) {
  return fmaxf(fmaxf(a, b), c);   // clang fuses to v_max3_f32 (T17)
}

__device__ __forceinline__ void gload16(const void* g, void* l) {
  __builtin_amdgcn_global_load_lds(
      (__attribute__((address_space(1))) const unsigned int*)g,
      (__attribute__((address_space(3))) unsigned int*)l,
      16, 0, 0);
}

// fp32 -> bf16 bulk convert, 4 elems/thread
__global__ void cvt_bf16(const float* __restrict__ in,
                         unsigned short* __restrict__ out, int n4) {
  int i = blockIdx.x * 256 + threadIdx.x;
  if (i >= n4) return;
  float4 v = ((const float4*)in)[i];
  ushort4 o;
  o.x = f2bf(v.x); o.y = f2bf(v.y); o.z = f2bf(v.z); o.w = f2bf(v.w);
  ((ushort4*)out)[i] = o;
}

// three same-size fp32->bf16 converts in one launch (z selects)
__global__ void cvt_bf16_3(const float* __restrict__ i0, const float* __restrict__ i1,
                           const float* __restrict__ i2, unsigned short* __restrict__ o0,
                           unsigned short* __restrict__ o1, unsigned short* __restrict__ o2,
                           int n4) {
  const float* in = (blockIdx.z == 0) ? i0 : (blockIdx.z == 1) ? i1 : i2;
  unsigned short* out = (blockIdx.z == 0) ? o0 : (blockIdx.z == 1) ? o1 : o2;
  int i = blockIdx.x * 256 + threadIdx.x;
  if (i >= n4) return;
  float4 v = ((const float4*)in)[i];
  ushort4 o;
  o.x = f2bf(v.x); o.y = f2bf(v.y); o.z = f2bf(v.z); o.w = f2bf(v.w);
  ((ushort4*)out)[i] = o;
}

// ====== 8-phase BM=128 x BN=256 GEMM (round-15, frozen at ~855 TF) ======
// Rounds 12-15 structural search all land 120-124us / ~37% MfmaUtil: this
// 2-phase ledger schedule is pinned here for K=2048. Frozen.
template <int STORE_F32>
__global__ __launch_bounds__(512, 1) void gemm8(
    const unsigned short* __restrict__ A,
    const unsigned short* __restrict__ B0, const unsigned short* __restrict__ B1,
    const unsigned short* __restrict__ B2,
    void* __restrict__ Cbase, const float* __restrict__ bias) {
  __shared__ __align__(16) unsigned short At[2][128 * 64];  // 32KB
  __shared__ __align__(16) unsigned short Bt[2][256 * 64];  // 64KB
  const unsigned short* Bm = (blockIdx.z == 0) ? B0 : (blockIdx.z == 1) ? B1 : B2;

  const int tid  = threadIdx.x;
  const int lane = tid & 63;
  const int w    = tid >> 6;        // 0..7
  const int wr   = w >> 2;          // 0..1 (m half of 128)
  const int wc   = w & 3;           // 0..3 (n quarter of 256)
  const int lg   = lane >> 4;
  const int lc   = lane & 15;

  // XCD m-band decode: 256 blocks, xcd owns 4 consecutive m-tiles
  const int bid = blockIdx.x;
  const int xcd = bid & 7;
  const int j   = bid >> 3;         // 0..31
  const int mt  = xcd * 4 + (j >> 3);
  const int nt  = j & 7;
  const int m0 = mt * 128;
  const int n0 = nt * 256;

  const int srow8 = lane >> 3;            // row within 8-row chunk
  const int sslot = (lane & 7) ^ srow8;   // pre-swizzled global 16B slot
  const int NT = EMB / 64;                // 32 K-tiles

  auto stageA = [&](int ts) {             // 128 rows = chunks 0-15
    if (ts >= NT) return;
    int buf = ts & 1, k0 = ts * 64;
#pragma unroll
    for (int rr = 0; rr < 2; ++rr) {
      int c = w + rr * 8;
      int row = c * 8 + srow8;
      gload16(A + (size_t)(m0 + row) * EMB + k0 + sslot * 8, (char*)&At[buf][0] + c * 1024);
    }
  };
  auto stageBlow = [&](int ts) {          // rows with (row&63)<32
    if (ts >= NT) return;
    int buf = ts & 1, k0 = ts * 64;
#pragma unroll
    for (int rr = 0; rr < 2; ++rr) {
      int i = w + rr * 8;
      int c = (i >> 2) * 8 + (i & 3);
      int row = c * 8 + srow8;
      gload16(Bm + (size_t)(n0 + row) * EMB + k0 + sslot * 8, (char*)&Bt[buf][0] + c * 1024);
    }
  };
  auto stageBhigh = [&](int ts) {         // rows with (row&63)>=32
    if (ts >= NT) return;
    int buf = ts & 1, k0 = ts * 64;
#pragma unroll
    for (int rr = 0; rr < 2; ++rr) {
      int i = w + rr * 8;
      int c = (i >> 2) * 8 + 4 + (i & 3);
      int row = c * 8 + srow8;
      gload16(Bm + (size_t)(n0 + row) * EMB + k0 + sslot * 8, (char*)&Bt[buf][0] + c * 1024);
    }
  };

  f32x4 acc[4][4] = {};
  bf16x8 afr[4][2], bfr0[2][2], bfr1[2][2];

  stageA(0); stageBlow(0); stageBhigh(0); stageA(1); stageBlow(1);
  asm volatile("s_waitcnt vmcnt(6)" ::: "memory");
  __builtin_amdgcn_s_barrier();

  for (int t = 0; t < NT; ++t) {
    const char* ab = (const char*)&At[t & 1][0];
    const char* bb = (const char*)&Bt[t & 1][0];

    // ---------- phase 0: ni 0-1 (B-low) x all A ----------
#pragma unroll
    for (int ni = 0; ni < 2; ++ni)
#pragma unroll
      for (int kk = 0; kk < 2; ++kk) {
        int row = wc * 64 + ni * 16 + lc;
        bfr0[ni][kk] = *(const bf16x8*)(bb + row * 128 + ((((kk << 2) | lg) ^ (lc & 7)) << 4));
      }
#pragma unroll
    for (int mi = 0; mi < 4; ++mi)
#pragma unroll
      for (int kk = 0; kk < 2; ++kk) {
        int row = wr * 64 + mi * 16 + lc;
        afr[mi][kk] = *(const bf16x8*)(ab + row * 128 + ((((kk << 2) | lg) ^ (lc & 7)) << 4));
      }
    stageBhigh(t + 1);
    __builtin_amdgcn_s_barrier();
    asm volatile("s_waitcnt lgkmcnt(0)" ::: "memory");
    __builtin_amdgcn_sched_barrier(0);
    __builtin_amdgcn_s_setprio(1);
#pragma unroll
    for (int mi = 0; mi < 4; ++mi)
#pragma unroll
      for (int ni = 0; ni < 2; ++ni)
#pragma unroll
        for (int kk = 0; kk < 2; ++kk)
          acc[mi][ni] = __builtin_amdgcn_mfma_f32_16x16x32_bf16(
              afr[mi][kk], bfr0[ni][kk], acc[mi][ni], 0, 0, 0);
    __builtin_amdgcn_s_setprio(0);
    if (t + 1 < NT) asm volatile("s_waitcnt vmcnt(6)" ::: "memory");
    else            asm volatile("s_waitcnt vmcnt(0)" ::: "memory");
    __builtin_amdgcn_s_barrier();

    // ---------- phase 1: ni 2-3 (B-high) x A (regs) ----------
#pragma unroll
    for (int ni = 0; ni < 2; ++ni)
#pragma unroll
      for (int kk = 0; kk < 2; ++kk) {
        int row = wc * 64 + 32 + ni * 16 + lc;
        bfr1[ni][kk] = *(const bf16x8*)(bb + row * 128 + ((((kk << 2) | lg) ^ (lc & 7)) << 4));
      }
    stageA(t + 2); stageBlow(t + 2);
    __builtin_amdgcn_s_barrier();
    asm volatile("s_waitcnt lgkmcnt(0)" ::: "memory");
    __builtin_amdgcn_sched_barrier(0);
    __builtin_amdgcn_s_setprio(1);
#pragma unroll
    for (int mi = 0; mi < 4; ++mi)
#pragma unroll
      for (int ni = 0; ni < 2; ++ni)
#pragma unroll
        for (int kk = 0; kk < 2; ++kk)
          acc[mi][2 + ni] = __builtin_amdgcn_mfma_f32_16x16x32_bf16(
              afr[mi][kk], bfr1[ni][kk], acc[mi][2 + ni], 0, 0, 0);
    __builtin_amdgcn_s_setprio(0);
    if (t + 2 < NT)      asm volatile("s_waitcnt vmcnt(6)" ::: "memory");
    else if (t + 1 < NT) asm volatile("s_waitcnt vmcnt(2)" ::: "memory");
    __builtin_amdgcn_s_barrier();
  }

  // epilogue (verified C-layout: row = lg*4+rr, col = lc within each 16x16)
#pragma unroll
  for (int mi = 0; mi < 4; ++mi)
#pragma unroll
    for (int ni = 0; ni < 4; ++ni) {
      int col = n0 + wc * 64 + ((ni >> 1) * 32) + (ni & 1) * 16 + lc;
#pragma unroll
      for (int rr = 0; rr < 4; ++rr) {
        int row = m0 + wr * 64 + mi * 16 + lg * 4 + rr;
        if (STORE_F32) {
          ((float*)Cbase)[(size_t)row * EMB + col] = acc[mi][ni][rr] + bias[col];
        } else {
          ((unsigned short*)Cbase + (size_t)blockIdx.z * ROWSM * EMB)
              [(size_t)row * EMB + col] = f2bf(acc[mi][ni][rr]);
        }
      }
    }
}

// Causal flash attention, swapped-QK form, KVBLK=128.
// This round: native-cast pack (v_cvt_pk via compiler) + max3 tree — cuts the
// per-half-tile VALU budget ~30% (pack was ~160 ops with manual 4-op f2bf).
__global__ __launch_bounds__(256, 2) void attn_causal(
    const unsigned short* __restrict__ Pq, const unsigned short* __restrict__ Pk,
    const unsigned short* __restrict__ Pv, unsigned short* __restrict__ ctx) {
  __shared__ __align__(16) unsigned short Ks[128 * 128];
  __shared__ __align__(16) unsigned short Vt[128 * 128];

  const int tid  = threadIdx.x;
  const int lane = tid & 63;
  const int w    = tid >> 6;
  const int ql   = lane & 31;
  const int hi   = lane >> 5;
  const int lg   = lane >> 4;
  const int lc   = lane & 15;

  const int bid = blockIdx.x;
  const int xcd = bid & 7;
  const int jj_ = bid >> 3;
  const int hh  = jj_ >> 4;
  const int bh  = xcd * 4 + hh;
  const int b   = bh >> 4;
  const int h   = bh & 15;
  const int qtr = jj_ & 15;
  const int qt  = (hh >= 2) ? (15 - qtr) : qtr;
  const int q0 = qt * 128;
  const int qw = q0 + w * 32;
  const int qg = qw + ql;

  const size_t hoff = (size_t)bh * SEQ * HDIM;
  const unsigned short* Q  = Pq + hoff;
  const unsigned short* Kh = Pk + hoff;
  const unsigned short* Vh = Pv + hoff;

  bf16x8 bq[8];
#pragma unroll
  for (int d8 = 0; d8 < 8; ++d8)
    bq[d8] = *(const bf16x8*)(Q + (size_t)qg * HDIM + d8 * 16 + hi * 8);

  const float NEG = -3.0e38f;
  f32x16 o[4];
#pragma unroll
  for (int dt = 0; dt < 4; ++dt)
#pragma unroll
    for (int r = 0; r < 16; ++r) o[dt][r] = 0.f;
  float m_r = NEG, l_r = 0.f;

  const float Cs   = 0.12753123161692858f;
  const float TDEF = 62.7f;

  const int nt128 = qt + 1;
  for (int tt = 0; tt < nt128; ++tt) {
    const int kv0 = tt * 128;
    if (tt) __syncthreads();
#pragma unroll
    for (int ii = 0; ii < 8; ++ii) {
      int i = w * 8 + ii;
      int r = i * 4 + lg;
      int sd = lc ^ (r & 7);
      gload16(Kh + (size_t)(kv0 + r) * HDIM + sd * 8, (char*)Ks + i * 1024);
    }
#pragma unroll 1
    for (int hv = 0; hv < 2; ++hv) {
      uint4 vr[4];
      const unsigned short* Vs = Vh + (size_t)(kv0 + hv * 64) * HDIM;
#pragma unroll
      for (int uu = 0; uu < 2; ++uu) {
        int u = tid + uu * 256;
        int kp = u >> 4, dg = u & 15;
        int k = kp * 2, d0 = dg * 8;
        vr[uu * 2]     = *(const uint4*)(Vs + (size_t)k * HDIM + d0);
        vr[uu * 2 + 1] = *(const uint4*)(Vs + (size_t)(k + 1) * HDIM + d0);
      }
#pragma unroll
      for (int uu = 0; uu < 2; ++uu) {
        int u = tid + uu * 256;
        int kp = u >> 4, dg = u & 15;
        int k = kp * 2, d0 = dg * 8;
        const unsigned short* e0 = (const unsigned short*)&vr[uu * 2];
        const unsigned short* e1 = (const unsigned short*)&vr[uu * 2 + 1];
#pragma unroll
        for (int jj = 0; jj < 8; ++jj) {
          int d = d0 + jj;
          int slot = ((hv << 3) | (k >> 3)) ^ jj ^ (dg & 7);
          int byteoff = d * 256 + (slot << 4) + (k & 7) * 2;
          *(unsigned int*)((char*)Vt + byteoff) =
              (unsigned int)e0[jj] | ((unsigned int)e1[jj] << 16);
        }
      }
    }
    __syncthreads();

#pragma unroll 1
    for (int hf = 0; hf < 2; ++hf) {
      const int kv0h = kv0 + hf * 64;
      if (kv0h > qw + 31) continue;
      const bool s1on = (kv0h + 32 <= qw + 31);
      const bool diag = (kv0h + 63 > qw);
      const char* ksb = (const char*)Ks + hf * 64 * 256;

      f32x16 c0, c1;
#pragma unroll
      for (int r = 0; r < 16; ++r) { c0[r] = 0.f; c1[r] = s1on ? 0.f : NEG; }
      __builtin_amdgcn_s_setprio(1);
#pragma unroll
      for (int d8 = 0; d8 < 8; ++d8) {
        bf16x8 ak = *(const bf16x8*)(ksb + ql * 256 +
                                     (((d8 * 2 + hi) ^ (ql & 7)) << 4));
        c0 = __builtin_amdgcn_mfma_f32_32x32x16_bf16(ak, bq[d8], c0, 0, 0, 0);
      }
      if (s1on) {
#pragma unroll
        for (int d8 = 0; d8 < 8; ++d8) {
          bf16x8 ak = *(const bf16x8*)(ksb + (32 + ql) * 256 +
                                       (((d8 * 2 + hi) ^ (ql & 7)) << 4));
          c1 = __builtin_amdgcn_mfma_f32_32x32x16_bf16(ak, bq[d8], c1, 0, 0, 0);
        }
      }
      __builtin_amdgcn_s_setprio(0);

      if (diag) {
#pragma unroll
        for (int r = 0; r < 16; ++r) {
          int kvl = (r & 3) + 8 * (r >> 2) + 4 * hi;
          if (kv0h + kvl > qg) c0[r] = NEG;
          if (s1on && kv0h + 32 + kvl > qg) c1[r] = NEG;
        }
      }
      // row-max via v_max3 tree (T17)
      float rm;
      {
        float a0 = max3f(c0[0],  c0[1],  c0[2]);
        float a1 = max3f(c0[3],  c0[4],  c0[5]);
        float a2 = max3f(c0[6],  c0[7],  c0[8]);
        float a3 = max3f(c0[9],  c0[10], c0[11]);
        float a4 = max3f(c0[12], c0[13], c0[14]);
        float a5 = max3f(c0[15], c1[0],  c1[1]);
        float a6 = max3f(c1[2],  c1[3],  c1[4]);
        float a7 = max3f(c1[5],  c1[6],  c1[7]);
        float a8 = max3f(c1[8],  c1[9],  c1[10]);
        float a9 = max3f(c1[11], c1[12], c1[13]);
        float aa = fmaxf(c1[14], c1[15]);
        float b0 = max3f(a0, a1, a2);
        float b1 = max3f(a3, a4, a5);
        float b2 = max3f(a6, a7, a8);
        float b3 = max3f(a9, aa, NEG);
        rm = fmaxf(fmaxf(b0, b1), fmaxf(b2, b3));
      }
      rm = fmaxf(rm, __shfl_xor(rm, 32));

      if (__any(rm > m_r + TDEF)) {
        float mnew = fmaxf(m_r, rm);
        float alpha = exp2f((m_r - mnew) * Cs);
        m_r = mnew;
        l_r *= alpha;
#pragma unroll
        for (int r = 0; r < 16; ++r) {
          float ar = __shfl(alpha, (r & 3) + 8 * (r >> 2) + 4 * hi);
#pragma unroll
          for (int dt = 0; dt < 4; ++dt) o[dt][r] *= ar;
        }
      }
#pragma unroll
      for (int r = 0; r < 16; ++r) {
        c0[r] = exp2f((c0[r] - m_r) * Cs);
        c1[r] = exp2f((c1[r] - m_r) * Cs);
      }
      float ps = 0.f;
#pragma unroll
      for (int r = 0; r < 16; ++r) ps += c0[r] + c1[r];
      ps += __shfl_xor(ps, 32);
      l_r += ps;

      bf16x8 pa[4];
#pragma unroll
      for (int t4 = 0; t4 < 4; ++t4) {
        const f32x16& cc = (t4 < 2) ? c0 : c1;
        const int rA = (t4 & 1) * 8;
        unsigned int pkL0 = pk2(cc[rA + 0], cc[rA + 1]);
        unsigned int pkL1 = pk2(cc[rA + 2], cc[rA + 3]);
        unsigned int pkH0 = pk2(cc[rA + 4], cc[rA + 5]);
        unsigned int pkH1 = pk2(cc[rA + 6], cc[rA + 7]);
        unsigned int give0 = hi ? pkL0 : pkH0;
        unsigned int give1 = hi ? pkL1 : pkH1;
        unsigned int keep0 = hi ? pkH0 : pkL0;
        unsigned int keep1 = hi ? pkH1 : pkL1;
        unsigned int recv0 = __shfl_xor(give0, 32);
        unsigned int recv1 = __shfl_xor(give1, 32);
        union { unsigned int u[4]; bf16x8 v; } pu;
        pu.u[0] = hi ? recv0 : keep0;
        pu.u[1] = hi ? recv1 : keep1;
        pu.u[2] = hi ? keep0 : recv0;
        pu.u[3] = hi ? keep1 : recv1;
        pa[t4] = pu.v;
      }
      __builtin_amdgcn_s_setprio(1);
#pragma unroll
      for (int t4 = 0; t4 < 4; ++t4) {
        if (diag && kv0h + t4 * 16 > qw + 31) continue;
#pragma unroll
        for (int dt = 0; dt < 4; ++dt) {
          int d = dt * 32 + ql;
          int slot = ((hf << 3) | (t4 << 1) | hi) ^ (d & 7) ^ ((d >> 3) & 7);
          bf16x8 bv = *(const bf16x8*)((const char*)Vt + d * 256 + (slot << 4));
          o[dt] = __builtin_amdgcn_mfma_f32_32x32x16_bf16(pa[t4], bv, o[dt], 0, 0, 0);
        }
      }
      __builtin_amdgcn_s_setprio(0);
    }
  }

  float linv = 1.0f / l_r;
  unsigned short* outp = ctx + (size_t)b * SEQ * EMB + (size_t)h * HDIM;
#pragma unroll
  for (int r = 0; r < 16; ++r) {
    int kvl = (r & 3) + 8 * (r >> 2) + 4 * hi;
    float lr = __shfl(linv, kvl);
    int qrow = qw + kvl;
#pragma unroll
    for (int dt = 0; dt < 4; ++dt)
      outp[(size_t)qrow * EMB + dt * 32 + ql] = f2bf(o[dt][r] * lr);
  }
}

extern "C" void kernel_launch(void* const* d_in, const int* in_sizes, int n_in,
                              void* d_out, int out_size, void* d_ws, size_t ws_size,
                              hipStream_t stream) {
  const float* x  = (const float*)d_in[0];
  const float* Wq = (const float*)d_in[1];
  const float* Wk = (const float*)d_in[2];
  const float* Wv = (const float*)d_in[3];
  const float* Wp = (const float*)d_in[4];
  const float* bp = (const float*)d_in[5];

  char* ws = (char*)d_ws;
  unsigned short* xb = (unsigned short*)ws;                         // 16MB, reused as ctx
  unsigned short* Wb = (unsigned short*)(ws + (size_t)(16u << 20)); // 8MB (Wq, then Wp)
  unsigned short* Pq = (unsigned short*)(ws + (size_t)(24u << 20)); // 3x16MB contiguous
  unsigned short* Pk = (unsigned short*)(ws + (size_t)(40u << 20));
  unsigned short* Pv = (unsigned short*)(ws + (size_t)(56u << 20));
  // d_out (33.5MB fp32) fully rewritten by final GEMM -> first 16MB doubles as
  // scratch for Wv/Wk bf16 during the QKV phase.
  unsigned short* WvS = (unsigned short*)d_out;
  unsigned short* WkS = (unsigned short*)d_out + (size_t)4 * 1024 * 1024;

  const int nX4 = ROWSM * EMB / 4;
  const int nW4 = EMB * EMB / 4;

  cvt_bf16<<<nX4 / 256, 256, 0, stream>>>(x, xb, nX4);
  cvt_bf16_3<<<dim3(nW4 / 256, 1, 3), 256, 0, stream>>>(Wq, Wk, Wv, Wb, WkS, WvS, nW4);

  // QKV: 128x256 tiles, 256 blocks per z (XCD m-band) -> 768 = 3 exact rounds
  gemm8<0><<<dim3(256, 1, 3), 512, 0, stream>>>(xb, Wb, WkS, WvS, Pq, nullptr);

  attn_causal<<<512, 256, 0, stream>>>(Pq, Pk, Pv, xb);

  cvt_bf16<<<nW4 / 256, 256, 0, stream>>>(Wp, Wb, nW4);
  // P: 256 blocks = 1 exact round
  gemm8<1><<<dim3(256, 1, 1), 512, 0, stream>>>(xb, Wb, Wb, Wb, d_out, bp);
}

// Round 17
// 256.900 us; speedup vs baseline: 1.4760x; 1.0158x over previous
//
#include <hip/hip_runtime.h>

#define SEQ   2048
#define EMB   2048
#define NHEAD 16
#define HDIM  128
#define ROWSM 4096  // B*SEQ

typedef float  f32x4   __attribute__((ext_vector_type(4)));
typedef float  f32x16  __attribute__((ext_vector_type(16)));
typedef __bf16 bf16x8  __attribute__((ext_vector_type(8)));

__device__ __forceinline__ unsigned short f2bf(float f) {
  union { __bf16 b; unsigned short u; } v; v.b = (__bf16)f; return v.u;
}
__device__ __forceinline__ unsigned int pk2(float a, float b) {
  return (unsigned int)f2bf(a) | ((unsigned int)f2bf(b) << 16);
}
__device__ __forceinline__ float max3f(float a, float b, float c) {
  return fmaxf(fmaxf(a, b), c);   // clang fuses to v_max3_f32 (T17)
}

__device__ __forceinline__ void gload16(const void* g, void* l) {
  __builtin_amdgcn_global_load_lds(
      (__attribute__((address_space(1))) const unsigned int*)g,
      (__attribute__((address_space(3))) unsigned int*)l,
      16, 0, 0);
}

// fp32 -> bf16 bulk convert, 4 elems/thread
__global__ void cvt_bf16(const float* __restrict__ in,
                         unsigned short* __restrict__ out, int n4) {
  int i = blockIdx.x * 256 + threadIdx.x;
  if (i >= n4) return;
  float4 v = ((const float4*)in)[i];
  ushort4 o;
  o.x = f2bf(v.x); o.y = f2bf(v.y); o.z = f2bf(v.z); o.w = f2bf(v.w);
  ((ushort4*)out)[i] = o;
}

// three same-size fp32->bf16 converts in one launch (z selects, contiguous dst)
__global__ void cvt_bf16_3(const float* __restrict__ i0, const float* __restrict__ i1,
                           const float* __restrict__ i2, unsigned short* __restrict__ o,
                           int n4) {
  const float* in = (blockIdx.z == 0) ? i0 : (blockIdx.z == 1) ? i1 : i2;
  unsigned short* out = o + (size_t)blockIdx.z * EMB * EMB;
  int i = blockIdx.x * 256 + threadIdx.x;
  if (i >= n4) return;
  float4 v = ((const float4*)in)[i];
  ushort4 o4;
  o4.x = f2bf(v.x); o4.y = f2bf(v.y); o4.z = f2bf(v.z); o4.w = f2bf(v.w);
  ((ushort4*)out)[i] = o4;
}

// ====== QKV fused GEMM: BM=256 x BN=192, N=6144, 512 blocks = 2 exact rounds.
// Rationale (r12 vs r13 per-block normalization): 256^2 tile = 1134 TF/45.5%
// per-block vs 256x128 = 831/33% — AI (128 vs 87 FLOP/B) is the lever. 256x192
// keeps AI=107 AND divides the fused N=6144 grid into exact rounds.
// B = [Wq;Wk;Wv] contiguous bf16 [6144][2048]; epilogue splits col>>11 into
// Pq/Pk/Pv (each row-major [4096][2048]).
// Schedule = round-13 proven ledger, stageB widened to 3 sweeps -> vmcnt(7):
//   prologue Ae(0)2,B(0)3,Aodd(0)2,Ae(1)2,B(1)3 = 12; vmcnt(7) retires Ae+B(0).
//   ph0(t): reads Ae(t)+all B(t); stages Aodd(t+1)[2]; end: 9 out, vmcnt(7).
//   ph1(t): reads Aodd(t); stages Ae(t+2)[2]+B(t+2)[3]; end: 12 out, vmcnt(7).
//   tail 7 -> 2 -> 0; NEVER a mid-loop drain (T4).
// T2 swizzle both-sides; T5 setprio; lgkmcnt(0)+sched_barrier(0) (rule #18).
// XCD m-band: xcd owns 2 m-tiles (512 rows, 2MB A -> L2-fit).
__global__ __launch_bounds__(512, 1) void gemm192_qkv(
    const unsigned short* __restrict__ A, const unsigned short* __restrict__ B,
    unsigned short* __restrict__ Cb) {
  __shared__ __align__(16) unsigned short At[2][256 * 64];  // 64KB
  __shared__ __align__(16) unsigned short Bt[2][192 * 64];  // 48KB

  const int tid  = threadIdx.x;
  const int lane = tid & 63;
  const int w    = tid >> 6;        // 0..7
  const int wr   = w >> 2;          // 0..1 (m half of 256)
  const int wc   = w & 3;           // 0..3 (n quarter of 192 -> 48 each)
  const int lg   = lane >> 4;
  const int lc   = lane & 15;

  // XCD m-band: 512 blocks; xcd owns 2 m-tiles x 32 n-tiles
  const int bid = blockIdx.x;
  const int xcd = bid & 7;
  const int j   = bid >> 3;         // 0..63
  const int mt  = xcd * 2 + (j >> 5);
  const int nt  = j & 31;
  const int m0 = mt * 256;
  const int n0 = nt * 192;

  const int srow8 = lane >> 3;
  const int sslot = (lane & 7) ^ srow8;   // pre-swizzled global 16B slot
  const int NT = EMB / 64;                // 32 K-tiles

  auto stageAeven = [&](int ts) {         // rows 0-63 (chunks 0-7) + 128-191 (16-23)
    if (ts >= NT) return;
    int buf = ts & 1, k0 = ts * 64;
    { int c = w;      int row = c * 8 + srow8;
      gload16(A + (size_t)(m0 + row) * EMB + k0 + sslot * 8, (char*)&At[buf][0] + c * 1024); }
    { int c = 16 + w; int row = c * 8 + srow8;
      gload16(A + (size_t)(m0 + row) * EMB + k0 + sslot * 8, (char*)&At[buf][0] + c * 1024); }
  };
  auto stageAodd = [&](int ts) {          // rows 64-127 (8-15) + 192-255 (24-31)
    if (ts >= NT) return;
    int buf = ts & 1, k0 = ts * 64;
    { int c = 8 + w;  int row = c * 8 + srow8;
      gload16(A + (size_t)(m0 + row) * EMB + k0 + sslot * 8, (char*)&At[buf][0] + c * 1024); }
    { int c = 24 + w; int row = c * 8 + srow8;
      gload16(A + (size_t)(m0 + row) * EMB + k0 + sslot * 8, (char*)&At[buf][0] + c * 1024); }
  };
  auto stageB = [&](int ts) {             // 192 rows = chunks 0-23, 3 sweeps
    if (ts >= NT) return;
    int buf = ts & 1, k0 = ts * 64;
#pragma unroll
    for (int s = 0; s < 3; ++s) {
      int c = w + s * 8;
      int row = c * 8 + srow8;
      gload16(B + (size_t)(n0 + row) * EMB + k0 + sslot * 8, (char*)&Bt[buf][0] + c * 1024);
    }
  };

  f32x4 acc[8][3] = {};
  bf16x8 afr[4][2], bfr[3][2];

  stageAeven(0); stageB(0); stageAodd(0); stageAeven(1); stageB(1);
  asm volatile("s_waitcnt vmcnt(7)" ::: "memory");
  __builtin_amdgcn_s_barrier();

  for (int t = 0; t < NT; ++t) {
    const char* ab = (const char*)&At[t & 1][0];
    const char* bb = (const char*)&Bt[t & 1][0];

    // ---------- phase 0: mi 0-3 (A-even) x all 3 B frags ----------
#pragma unroll
    for (int ni = 0; ni < 3; ++ni)
#pragma unroll
      for (int kk = 0; kk < 2; ++kk) {
        int row = wc * 48 + ni * 16 + lc;
        bfr[ni][kk] = *(const bf16x8*)(bb + row * 128 + ((((kk << 2) | lg) ^ (lc & 7)) << 4));
      }
#pragma unroll
    for (int mi = 0; mi < 4; ++mi)
#pragma unroll
      for (int kk = 0; kk < 2; ++kk) {
        int row = wr * 128 + mi * 16 + lc;
        afr[mi][kk] = *(const bf16x8*)(ab + row * 128 + ((((kk << 2) | lg) ^ (lc & 7)) << 4));
      }
    stageAodd(t + 1);
    __builtin_amdgcn_s_barrier();
    asm volatile("s_waitcnt lgkmcnt(0)" ::: "memory");
    __builtin_amdgcn_sched_barrier(0);
    __builtin_amdgcn_s_setprio(1);
#pragma unroll
    for (int mi = 0; mi < 4; ++mi)
#pragma unroll
      for (int ni = 0; ni < 3; ++ni)
#pragma unroll
        for (int kk = 0; kk < 2; ++kk)
          acc[mi][ni] = __builtin_amdgcn_mfma_f32_16x16x32_bf16(
              afr[mi][kk], bfr[ni][kk], acc[mi][ni], 0, 0, 0);
    __builtin_amdgcn_s_setprio(0);
    if (t + 1 < NT) asm volatile("s_waitcnt vmcnt(7)" ::: "memory");
    else            asm volatile("s_waitcnt vmcnt(0)" ::: "memory");
    __builtin_amdgcn_s_barrier();

    // ---------- phase 1: mi 4-7 (A-odd) x B (regs) ----------
#pragma unroll
    for (int mi = 0; mi < 4; ++mi)
#pragma unroll
      for (int kk = 0; kk < 2; ++kk) {
        int row = wr * 128 + 64 + mi * 16 + lc;
        afr[mi][kk] = *(const bf16x8*)(ab + row * 128 + ((((kk << 2) | lg) ^ (lc & 7)) << 4));
      }
    stageAeven(t + 2); stageB(t + 2);
    __builtin_amdgcn_s_barrier();
    asm volatile("s_waitcnt lgkmcnt(0)" ::: "memory");
    __builtin_amdgcn_sched_barrier(0);
    __builtin_amdgcn_s_setprio(1);
#pragma unroll
    for (int mi = 0; mi < 4; ++mi)
#pragma unroll
      for (int ni = 0; ni < 3; ++ni)
#pragma unroll
        for (int kk = 0; kk < 2; ++kk)
          acc[4 + mi][ni] = __builtin_amdgcn_mfma_f32_16x16x32_bf16(
              afr[mi][kk], bfr[ni][kk], acc[4 + mi][ni], 0, 0, 0);
    __builtin_amdgcn_s_setprio(0);
    if (t + 2 < NT)      asm volatile("s_waitcnt vmcnt(7)" ::: "memory");
    else if (t + 1 < NT) asm volatile("s_waitcnt vmcnt(2)" ::: "memory");
    __builtin_amdgcn_s_barrier();
  }

  // epilogue: col in [0,6144) -> matrix col>>11, inner col&2047
#pragma unroll
  for (int mi = 0; mi < 8; ++mi)
#pragma unroll
    for (int ni = 0; ni < 3; ++ni) {
      int col = n0 + wc * 48 + ni * 16 + lc;
      unsigned short* dst = Cb + (size_t)(col >> 11) * ROWSM * EMB + (col & 2047);
#pragma unroll
      for (int rr = 0; rr < 4; ++rr) {
        int row = m0 + wr * 128 + mi * 16 + lg * 4 + rr;
        dst[(size_t)row * EMB] = f2bf(acc[mi][ni][rr]);
      }
    }
}

// ====== Final projection GEMM: BM=256 x BN=128 (round-15 proven, frozen) =====
__global__ __launch_bounds__(512, 1) void gemm_p8(
    const unsigned short* __restrict__ A, const unsigned short* __restrict__ B,
    float* __restrict__ Cout, const float* __restrict__ bias) {
  __shared__ __align__(16) unsigned short At[2][128 * 64];
  __shared__ __align__(16) unsigned short Bt[2][256 * 64];

  const int tid  = threadIdx.x;
  const int lane = tid & 63;
  const int w    = tid >> 6;
  const int wr   = w >> 2;
  const int wc   = w & 3;
  const int lg   = lane >> 4;
  const int lc   = lane & 15;

  const int bid = blockIdx.x;
  const int xcd = bid & 7;
  const int j   = bid >> 3;
  const int mt  = xcd * 4 + (j >> 3);
  const int nt  = j & 7;
  const int m0 = mt * 128;
  const int n0 = nt * 256;

  const int srow8 = lane >> 3;
  const int sslot = (lane & 7) ^ srow8;
  const int NT = EMB / 64;

  auto stageA = [&](int ts) {
    if (ts >= NT) return;
    int buf = ts & 1, k0 = ts * 64;
#pragma unroll
    for (int rr = 0; rr < 2; ++rr) {
      int c = w + rr * 8;
      int row = c * 8 + srow8;
      gload16(A + (size_t)(m0 + row) * EMB + k0 + sslot * 8, (char*)&At[buf][0] + c * 1024);
    }
  };
  auto stageBlow = [&](int ts) {
    if (ts >= NT) return;
    int buf = ts & 1, k0 = ts * 64;
#pragma unroll
    for (int rr = 0; rr < 2; ++rr) {
      int i = w + rr * 8;
      int c = (i >> 2) * 8 + (i & 3);
      int row = c * 8 + srow8;
      gload16(B + (size_t)(n0 + row) * EMB + k0 + sslot * 8, (char*)&Bt[buf][0] + c * 1024);
    }
  };
  auto stageBhigh = [&](int ts) {
    if (ts >= NT) return;
    int buf = ts & 1, k0 = ts * 64;
#pragma unroll
    for (int rr = 0; rr < 2; ++rr) {
      int i = w + rr * 8;
      int c = (i >> 2) * 8 + 4 + (i & 3);
      int row = c * 8 + srow8;
      gload16(B + (size_t)(n0 + row) * EMB + k0 + sslot * 8, (char*)&Bt[buf][0] + c * 1024);
    }
  };

  f32x4 acc[4][4] = {};
  bf16x8 afr[4][2], bfr0[2][2], bfr1[2][2];

  stageA(0); stageBlow(0); stageBhigh(0); stageA(1); stageBlow(1);
  asm volatile("s_waitcnt vmcnt(6)" ::: "memory");
  __builtin_amdgcn_s_barrier();

  for (int t = 0; t < NT; ++t) {
    const char* ab = (const char*)&At[t & 1][0];
    const char* bb = (const char*)&Bt[t & 1][0];

#pragma unroll
    for (int ni = 0; ni < 2; ++ni)
#pragma unroll
      for (int kk = 0; kk < 2; ++kk) {
        int row = wc * 64 + ni * 16 + lc;
        bfr0[ni][kk] = *(const bf16x8*)(bb + row * 128 + ((((kk << 2) | lg) ^ (lc & 7)) << 4));
      }
#pragma unroll
    for (int mi = 0; mi < 4; ++mi)
#pragma unroll
      for (int kk = 0; kk < 2; ++kk) {
        int row = wr * 64 + mi * 16 + lc;
        afr[mi][kk] = *(const bf16x8*)(ab + row * 128 + ((((kk << 2) | lg) ^ (lc & 7)) << 4));
      }
    stageBhigh(t + 1);
    __builtin_amdgcn_s_barrier();
    asm volatile("s_waitcnt lgkmcnt(0)" ::: "memory");
    __builtin_amdgcn_sched_barrier(0);
    __builtin_amdgcn_s_setprio(1);
#pragma unroll
    for (int mi = 0; mi < 4; ++mi)
#pragma unroll
      for (int ni = 0; ni < 2; ++ni)
#pragma unroll
        for (int kk = 0; kk < 2; ++kk)
          acc[mi][ni] = __builtin_amdgcn_mfma_f32_16x16x32_bf16(
              afr[mi][kk], bfr0[ni][kk], acc[mi][ni], 0, 0, 0);
    __builtin_amdgcn_s_setprio(0);
    if (t + 1 < NT) asm volatile("s_waitcnt vmcnt(6)" ::: "memory");
    else            asm volatile("s_waitcnt vmcnt(0)" ::: "memory");
    __builtin_amdgcn_s_barrier();

#pragma unroll
    for (int ni = 0; ni < 2; ++ni)
#pragma unroll
      for (int kk = 0; kk < 2; ++kk) {
        int row = wc * 64 + 32 + ni * 16 + lc;
        bfr1[ni][kk] = *(const bf16x8*)(bb + row * 128 + ((((kk << 2) | lg) ^ (lc & 7)) << 4));
      }
    stageA(t + 2); stageBlow(t + 2);
    __builtin_amdgcn_s_barrier();
    asm volatile("s_waitcnt lgkmcnt(0)" ::: "memory");
    __builtin_amdgcn_sched_barrier(0);
    __builtin_amdgcn_s_setprio(1);
#pragma unroll
    for (int mi = 0; mi < 4; ++mi)
#pragma unroll
      for (int ni = 0; ni < 2; ++ni)
#pragma unroll
        for (int kk = 0; kk < 2; ++kk)
          acc[mi][2 + ni] = __builtin_amdgcn_mfma_f32_16x16x32_bf16(
              afr[mi][kk], bfr1[ni][kk], acc[mi][2 + ni], 0, 0, 0);
    __builtin_amdgcn_s_setprio(0);
    if (t + 2 < NT)      asm volatile("s_waitcnt vmcnt(6)" ::: "memory");
    else if (t + 1 < NT) asm volatile("s_waitcnt vmcnt(2)" ::: "memory");
    __builtin_amdgcn_s_barrier();
  }

#pragma unroll
  for (int mi = 0; mi < 4; ++mi)
#pragma unroll
    for (int ni = 0; ni < 4; ++ni) {
      int col = n0 + wc * 64 + ((ni >> 1) * 32) + (ni & 1) * 16 + lc;
#pragma unroll
      for (int rr = 0; rr < 4; ++rr) {
        int row = m0 + wr * 64 + mi * 16 + lg * 4 + rr;
        Cout[(size_t)row * EMB + col] = acc[mi][ni][rr] + bias[col];
      }
    }
}

// Causal flash attention, swapped-QK form, KVBLK=128 — round-16, frozen.
__global__ __launch_bounds__(256, 2) void attn_causal(
    const unsigned short* __restrict__ Pq, const unsigned short* __restrict__ Pk,
    const unsigned short* __restrict__ Pv, unsigned short* __restrict__ ctx) {
  __shared__ __align__(16) unsigned short Ks[128 * 128];
  __shared__ __align__(16) unsigned short Vt[128 * 128];

  const int tid  = threadIdx.x;
  const int lane = tid & 63;
  const int w    = tid >> 6;
  const int ql   = lane & 31;
  const int hi   = lane >> 5;
  const int lg   = lane >> 4;
  const int lc   = lane & 15;

  const int bid = blockIdx.x;
  const int xcd = bid & 7;
  const int jj_ = bid >> 3;
  const int hh  = jj_ >> 4;
  const int bh  = xcd * 4 + hh;
  const int b   = bh >> 4;
  const int h   = bh & 15;
  const int qtr = jj_ & 15;
  const int qt  = (hh >= 2) ? (15 - qtr) : qtr;
  const int q0 = qt * 128;
  const int qw = q0 + w * 32;
  const int qg = qw + ql;

  const size_t hoff = (size_t)bh * SEQ * HDIM;
  const unsigned short* Q  = Pq + hoff;
  const unsigned short* Kh = Pk + hoff;
  const unsigned short* Vh = Pv + hoff;

  bf16x8 bq[8];
#pragma unroll
  for (int d8 = 0; d8 < 8; ++d8)
    bq[d8] = *(const bf16x8*)(Q + (size_t)qg * HDIM + d8 * 16 + hi * 8);

  const float NEG = -3.0e38f;
  f32x16 o[4];
#pragma unroll
  for (int dt = 0; dt < 4; ++dt)
#pragma unroll
    for (int r = 0; r < 16; ++r) o[dt][r] = 0.f;
  float m_r = NEG, l_r = 0.f;

  const float Cs   = 0.12753123161692858f;
  const float TDEF = 62.7f;

  const int nt128 = qt + 1;
  for (int tt = 0; tt < nt128; ++tt) {
    const int kv0 = tt * 128;
    if (tt) __syncthreads();
#pragma unroll
    for (int ii = 0; ii < 8; ++ii) {
      int i = w * 8 + ii;
      int r = i * 4 + lg;
      int sd = lc ^ (r & 7);
      gload16(Kh + (size_t)(kv0 + r) * HDIM + sd * 8, (char*)Ks + i * 1024);
    }
#pragma unroll 1
    for (int hv = 0; hv < 2; ++hv) {
      uint4 vr[4];
      const unsigned short* Vs = Vh + (size_t)(kv0 + hv * 64) * HDIM;
#pragma unroll
      for (int uu = 0; uu < 2; ++uu) {
        int u = tid + uu * 256;
        int kp = u >> 4, dg = u & 15;
        int k = kp * 2, d0 = dg * 8;
        vr[uu * 2]     = *(const uint4*)(Vs + (size_t)k * HDIM + d0);
        vr[uu * 2 + 1] = *(const uint4*)(Vs + (size_t)(k + 1) * HDIM + d0);
      }
#pragma unroll
      for (int uu = 0; uu < 2; ++uu) {
        int u = tid + uu * 256;
        int kp = u >> 4, dg = u & 15;
        int k = kp * 2, d0 = dg * 8;
        const unsigned short* e0 = (const unsigned short*)&vr[uu * 2];
        const unsigned short* e1 = (const unsigned short*)&vr[uu * 2 + 1];
#pragma unroll
        for (int jj = 0; jj < 8; ++jj) {
          int d = d0 + jj;
          int slot = ((hv << 3) | (k >> 3)) ^ jj ^ (dg & 7);
          int byteoff = d * 256 + (slot << 4) + (k & 7) * 2;
          *(unsigned int*)((char*)Vt + byteoff) =
              (unsigned int)e0[jj] | ((unsigned int)e1[jj] << 16);
        }
      }
    }
    __syncthreads();

#pragma unroll 1
    for (int hf = 0; hf < 2; ++hf) {
      const int kv0h = kv0 + hf * 64;
      if (kv0h > qw + 31) continue;
      const bool s1on = (kv0h + 32 <= qw + 31);
      const bool diag = (kv0h + 63 > qw);
      const char* ksb = (const char*)Ks + hf * 64 * 256;

      f32x16 c0, c1;
#pragma unroll
      for (int r = 0; r < 16; ++r) { c0[r] = 0.f; c1[r] = s1on ? 0.f : NEG; }
      __builtin_amdgcn_s_setprio(1);
#pragma unroll
      for (int d8 = 0; d8 < 8; ++d8) {
        bf16x8 ak = *(const bf16x8*)(ksb + ql * 256 +
                                     (((d8 * 2 + hi) ^ (ql & 7)) << 4));
        c0 = __builtin_amdgcn_mfma_f32_32x32x16_bf16(ak, bq[d8], c0, 0, 0, 0);
      }
      if (s1on) {
#pragma unroll
        for (int d8 = 0; d8 < 8; ++d8) {
          bf16x8 ak = *(const bf16x8*)(ksb + (32 + ql) * 256 +
                                       (((d8 * 2 + hi) ^ (ql & 7)) << 4));
          c1 = __builtin_amdgcn_mfma_f32_32x32x16_bf16(ak, bq[d8], c1, 0, 0, 0);
        }
      }
      __builtin_amdgcn_s_setprio(0);

      if (diag) {
#pragma unroll
        for (int r = 0; r < 16; ++r) {
          int kvl = (r & 3) + 8 * (r >> 2) + 4 * hi;
          if (kv0h + kvl > qg) c0[r] = NEG;
          if (s1on && kv0h + 32 + kvl > qg) c1[r] = NEG;
        }
      }
      float rm;
      {
        float a0 = max3f(c0[0],  c0[1],  c0[2]);
        float a1 = max3f(c0[3],  c0[4],  c0[5]);
        float a2 = max3f(c0[6],  c0[7],  c0[8]);
        float a3 = max3f(c0[9],  c0[10], c0[11]);
        float a4 = max3f(c0[12], c0[13], c0[14]);
        float a5 = max3f(c0[15], c1[0],  c1[1]);
        float a6 = max3f(c1[2],  c1[3],  c1[4]);
        float a7 = max3f(c1[5],  c1[6],  c1[7]);
        float a8 = max3f(c1[8],  c1[9],  c1[10]);
        float a9 = max3f(c1[11], c1[12], c1[13]);
        float aa = fmaxf(c1[14], c1[15]);
        float b0 = max3f(a0, a1, a2);
        float b1 = max3f(a3, a4, a5);
        float b2 = max3f(a6, a7, a8);
        float b3 = max3f(a9, aa, NEG);
        rm = fmaxf(fmaxf(b0, b1), fmaxf(b2, b3));
      }
      rm = fmaxf(rm, __shfl_xor(rm, 32));

      if (__any(rm > m_r + TDEF)) {
        float mnew = fmaxf(m_r, rm);
        float alpha = exp2f((m_r - mnew) * Cs);
        m_r = mnew;
        l_r *= alpha;
#pragma unroll
        for (int r = 0; r < 16; ++r) {
          float ar = __shfl(alpha, (r & 3) + 8 * (r >> 2) + 4 * hi);
#pragma unroll
          for (int dt = 0; dt < 4; ++dt) o[dt][r] *= ar;
        }
      }
#pragma unroll
      for (int r = 0; r < 16; ++r) {
        c0[r] = exp2f((c0[r] - m_r) * Cs);
        c1[r] = exp2f((c1[r] - m_r) * Cs);
      }
      float ps = 0.f;
#pragma unroll
      for (int r = 0; r < 16; ++r) ps += c0[r] + c1[r];
      ps += __shfl_xor(ps, 32);
      l_r += ps;

      bf16x8 pa[4];
#pragma unroll
      for (int t4 = 0; t4 < 4; ++t4) {
        const f32x16& cc = (t4 < 2) ? c0 : c1;
        const int rA = (t4 & 1) * 8;
        unsigned int pkL0 = pk2(cc[rA + 0], cc[rA + 1]);
        unsigned int pkL1 = pk2(cc[rA + 2], cc[rA + 3]);
        unsigned int pkH0 = pk2(cc[rA + 4], cc[rA + 5]);
        unsigned int pkH1 = pk2(cc[rA + 6], cc[rA + 7]);
        unsigned int give0 = hi ? pkL0 : pkH0;
        unsigned int give1 = hi ? pkL1 : pkH1;
        unsigned int keep0 = hi ? pkH0 : pkL0;
        unsigned int keep1 = hi ? pkH1 : pkL1;
        unsigned int recv0 = __shfl_xor(give0, 32);
        unsigned int recv1 = __shfl_xor(give1, 32);
        union { unsigned int u[4]; bf16x8 v; } pu;
        pu.u[0] = hi ? recv0 : keep0;
        pu.u[1] = hi ? recv1 : keep1;
        pu.u[2] = hi ? keep0 : recv0;
        pu.u[3] = hi ? keep1 : recv1;
        pa[t4] = pu.v;
      }
      __builtin_amdgcn_s_setprio(1);
#pragma unroll
      for (int t4 = 0; t4 < 4; ++t4) {
        if (diag && kv0h + t4 * 16 > qw + 31) continue;
#pragma unroll
        for (int dt = 0; dt < 4; ++dt) {
          int d = dt * 32 + ql;
          int slot = ((hf << 3) | (t4 << 1) | hi) ^ (d & 7) ^ ((d >> 3) & 7);
          bf16x8 bv = *(const bf16x8*)((const char*)Vt + d * 256 + (slot << 4));
          o[dt] = __builtin_amdgcn_mfma_f32_32x32x16_bf16(pa[t4], bv, o[dt], 0, 0, 0);
        }
      }
      __builtin_amdgcn_s_setprio(0);
    }
  }

  float linv = 1.0f / l_r;
  unsigned short* outp = ctx + (size_t)b * SEQ * EMB + (size_t)h * HDIM;
#pragma unroll
  for (int r = 0; r < 16; ++r) {
    int kvl = (r & 3) + 8 * (r >> 2) + 4 * hi;
    float lr = __shfl(linv, kvl);
    int qrow = qw + kvl;
#pragma unroll
    for (int dt = 0; dt < 4; ++dt)
      outp[(size_t)qrow * EMB + dt * 32 + ql] = f2bf(o[dt][r] * lr);
  }
}

extern "C" void kernel_launch(void* const* d_in, const int* in_sizes, int n_in,
                              void* d_out, int out_size, void* d_ws, size_t ws_size,
                              hipStream_t stream) {
  const float* x  = (const float*)d_in[0];
  const float* Wq = (const float*)d_in[1];
  const float* Wk = (const float*)d_in[2];
  const float* Wv = (const float*)d_in[3];
  const float* Wp = (const float*)d_in[4];
  const float* bp = (const float*)d_in[5];

  char* ws = (char*)d_ws;
  unsigned short* xb = (unsigned short*)ws;                         // 16MB, reused as ctx
  unsigned short* Wb = (unsigned short*)(ws + (size_t)(16u << 20)); // 8MB (Wp bf16)
  unsigned short* Pq = (unsigned short*)(ws + (size_t)(24u << 20)); // 3x16MB contiguous
  unsigned short* Pk = (unsigned short*)(ws + (size_t)(40u << 20));
  unsigned short* Pv = (unsigned short*)(ws + (size_t)(56u << 20));
  // d_out (32MB fp32) fully rewritten by final GEMM -> first 24MB holds the
  // CONTIGUOUS [Wq;Wk;Wv] bf16 B matrix during the QKV phase.
  unsigned short* WB3 = (unsigned short*)d_out;

  const int nX4 = ROWSM * EMB / 4;
  const int nW4 = EMB * EMB / 4;

  cvt_bf16<<<nX4 / 256, 256, 0, stream>>>(x, xb, nX4);
  cvt_bf16_3<<<dim3(nW4 / 256, 1, 3), 256, 0, stream>>>(Wq, Wk, Wv, WB3, nW4);

  // QKV fused: M=4096, N=6144, 256x192 tiles -> 512 blocks = 2 exact rounds
  gemm192_qkv<<<512, 512, 0, stream>>>(xb, WB3, Pq);

  attn_causal<<<512, 256, 0, stream>>>(Pq, Pk, Pv, xb);

  cvt_bf16<<<nW4 / 256, 256, 0, stream>>>(Wp, Wb, nW4);
  // P: 256 blocks = 1 exact round
  gemm_p8<<<256, 512, 0, stream>>>(xb, Wb, (float*)d_out, bp);
}

// Round 18
// 256.889 us; speedup vs baseline: 1.4760x; 1.0000x over previous
//
#include <hip/hip_runtime.h>

#define SEQ   2048
#define EMB   2048
#define NHEAD 16
#define HDIM  128
#define ROWSM 4096  // B*SEQ

typedef float  f32x4   __attribute__((ext_vector_type(4)));
typedef float  f32x16  __attribute__((ext_vector_type(16)));
typedef __bf16 bf16x8  __attribute__((ext_vector_type(8)));

__device__ __forceinline__ unsigned short f2bf(float f) {
  union { __bf16 b; unsigned short u; } v; v.b = (__bf16)f; return v.u;
}
__device__ __forceinline__ unsigned int pk2(float a, float b) {
  return (unsigned int)f2bf(a) | ((unsigned int)f2bf(b) << 16);
}
__device__ __forceinline__ float max3f(float a, float b, float c) {
  return fmaxf(fmaxf(a, b), c);   // clang fuses to v_max3_f32 (T17)
}

__device__ __forceinline__ void gload16(const void* g, void* l) {
  __builtin_amdgcn_global_load_lds(
      (__attribute__((address_space(1))) const unsigned int*)g,
      (__attribute__((address_space(3))) unsigned int*)l,
      16, 0, 0);
}

// ALL fp32->bf16 converts in ONE launch: z=0 x(2M f4), z=1..3 Wq/Wk/Wv -> WB3
// contiguous, z=4 Wp -> Wb. Saves 2 launch gaps vs 3 separate kernels.
__global__ void cvt_all(const float* __restrict__ x,  const float* __restrict__ Wq,
                        const float* __restrict__ Wk, const float* __restrict__ Wv,
                        const float* __restrict__ Wp, unsigned short* __restrict__ xb,
                        unsigned short* __restrict__ WB3, unsigned short* __restrict__ Wb,
                        int nX4, int nW4) {
  const int z = blockIdx.z;
  const float* in;
  unsigned short* out;
  int n4;
  if (z == 0)      { in = x;  out = xb;  n4 = nX4; }
  else if (z == 1) { in = Wq; out = WB3;                          n4 = nW4; }
  else if (z == 2) { in = Wk; out = WB3 + (size_t)EMB * EMB;      n4 = nW4; }
  else if (z == 3) { in = Wv; out = WB3 + (size_t)2 * EMB * EMB;  n4 = nW4; }
  else             { in = Wp; out = Wb;  n4 = nW4; }
  int i = blockIdx.x * 256 + threadIdx.x;
  if (i >= n4) return;
  float4 v = ((const float4*)in)[i];
  ushort4 o4;
  o4.x = f2bf(v.x); o4.y = f2bf(v.y); o4.z = f2bf(v.z); o4.w = f2bf(v.w);
  ((ushort4*)out)[i] = o4;
}

// ====== QKV fused GEMM: BM=256 x BN=192, N=6144 (round-17 proven, frozen) ====
__global__ __launch_bounds__(512, 1) void gemm192_qkv(
    const unsigned short* __restrict__ A, const unsigned short* __restrict__ B,
    unsigned short* __restrict__ Cb) {
  __shared__ __align__(16) unsigned short At[2][256 * 64];  // 64KB
  __shared__ __align__(16) unsigned short Bt[2][192 * 64];  // 48KB

  const int tid  = threadIdx.x;
  const int lane = tid & 63;
  const int w    = tid >> 6;
  const int wr   = w >> 2;
  const int wc   = w & 3;
  const int lg   = lane >> 4;
  const int lc   = lane & 15;

  const int bid = blockIdx.x;
  const int xcd = bid & 7;
  const int j   = bid >> 3;
  const int mt  = xcd * 2 + (j >> 5);
  const int nt  = j & 31;
  const int m0 = mt * 256;
  const int n0 = nt * 192;

  const int srow8 = lane >> 3;
  const int sslot = (lane & 7) ^ srow8;
  const int NT = EMB / 64;

  auto stageAeven = [&](int ts) {
    if (ts >= NT) return;
    int buf = ts & 1, k0 = ts * 64;
    { int c = w;      int row = c * 8 + srow8;
      gload16(A + (size_t)(m0 + row) * EMB + k0 + sslot * 8, (char*)&At[buf][0] + c * 1024); }
    { int c = 16 + w; int row = c * 8 + srow8;
      gload16(A + (size_t)(m0 + row) * EMB + k0 + sslot * 8, (char*)&At[buf][0] + c * 1024); }
  };
  auto stageAodd = [&](int ts) {
    if (ts >= NT) return;
    int buf = ts & 1, k0 = ts * 64;
    { int c = 8 + w;  int row = c * 8 + srow8;
      gload16(A + (size_t)(m0 + row) * EMB + k0 + sslot * 8, (char*)&At[buf][0] + c * 1024); }
    { int c = 24 + w; int row = c * 8 + srow8;
      gload16(A + (size_t)(m0 + row) * EMB + k0 + sslot * 8, (char*)&At[buf][0] + c * 1024); }
  };
  auto stageB = [&](int ts) {
    if (ts >= NT) return;
    int buf = ts & 1, k0 = ts * 64;
#pragma unroll
    for (int s = 0; s < 3; ++s) {
      int c = w + s * 8;
      int row = c * 8 + srow8;
      gload16(B + (size_t)(n0 + row) * EMB + k0 + sslot * 8, (char*)&Bt[buf][0] + c * 1024);
    }
  };

  f32x4 acc[8][3] = {};
  bf16x8 afr[4][2], bfr[3][2];

  stageAeven(0); stageB(0); stageAodd(0); stageAeven(1); stageB(1);
  asm volatile("s_waitcnt vmcnt(7)" ::: "memory");
  __builtin_amdgcn_s_barrier();

  for (int t = 0; t < NT; ++t) {
    const char* ab = (const char*)&At[t & 1][0];
    const char* bb = (const char*)&Bt[t & 1][0];

#pragma unroll
    for (int ni = 0; ni < 3; ++ni)
#pragma unroll
      for (int kk = 0; kk < 2; ++kk) {
        int row = wc * 48 + ni * 16 + lc;
        bfr[ni][kk] = *(const bf16x8*)(bb + row * 128 + ((((kk << 2) | lg) ^ (lc & 7)) << 4));
      }
#pragma unroll
    for (int mi = 0; mi < 4; ++mi)
#pragma unroll
      for (int kk = 0; kk < 2; ++kk) {
        int row = wr * 128 + mi * 16 + lc;
        afr[mi][kk] = *(const bf16x8*)(ab + row * 128 + ((((kk << 2) | lg) ^ (lc & 7)) << 4));
      }
    stageAodd(t + 1);
    __builtin_amdgcn_s_barrier();
    asm volatile("s_waitcnt lgkmcnt(0)" ::: "memory");
    __builtin_amdgcn_sched_barrier(0);
    __builtin_amdgcn_s_setprio(1);
#pragma unroll
    for (int mi = 0; mi < 4; ++mi)
#pragma unroll
      for (int ni = 0; ni < 3; ++ni)
#pragma unroll
        for (int kk = 0; kk < 2; ++kk)
          acc[mi][ni] = __builtin_amdgcn_mfma_f32_16x16x32_bf16(
              afr[mi][kk], bfr[ni][kk], acc[mi][ni], 0, 0, 0);
    __builtin_amdgcn_s_setprio(0);
    if (t + 1 < NT) asm volatile("s_waitcnt vmcnt(7)" ::: "memory");
    else            asm volatile("s_waitcnt vmcnt(0)" ::: "memory");
    __builtin_amdgcn_s_barrier();

#pragma unroll
    for (int mi = 0; mi < 4; ++mi)
#pragma unroll
      for (int kk = 0; kk < 2; ++kk) {
        int row = wr * 128 + 64 + mi * 16 + lc;
        afr[mi][kk] = *(const bf16x8*)(ab + row * 128 + ((((kk << 2) | lg) ^ (lc & 7)) << 4));
      }
    stageAeven(t + 2); stageB(t + 2);
    __builtin_amdgcn_s_barrier();
    asm volatile("s_waitcnt lgkmcnt(0)" ::: "memory");
    __builtin_amdgcn_sched_barrier(0);
    __builtin_amdgcn_s_setprio(1);
#pragma unroll
    for (int mi = 0; mi < 4; ++mi)
#pragma unroll
      for (int ni = 0; ni < 3; ++ni)
#pragma unroll
        for (int kk = 0; kk < 2; ++kk)
          acc[4 + mi][ni] = __builtin_amdgcn_mfma_f32_16x16x32_bf16(
              afr[mi][kk], bfr[ni][kk], acc[4 + mi][ni], 0, 0, 0);
    __builtin_amdgcn_s_setprio(0);
    if (t + 2 < NT)      asm volatile("s_waitcnt vmcnt(7)" ::: "memory");
    else if (t + 1 < NT) asm volatile("s_waitcnt vmcnt(2)" ::: "memory");
    __builtin_amdgcn_s_barrier();
  }

#pragma unroll
  for (int mi = 0; mi < 8; ++mi)
#pragma unroll
    for (int ni = 0; ni < 3; ++ni) {
      int col = n0 + wc * 48 + ni * 16 + lc;
      unsigned short* dst = Cb + (size_t)(col >> 11) * ROWSM * EMB + (col & 2047);
#pragma unroll
      for (int rr = 0; rr < 4; ++rr) {
        int row = m0 + wr * 128 + mi * 16 + lg * 4 + rr;
        dst[(size_t)row * EMB] = f2bf(acc[mi][ni][rr]);
      }
    }
}

// ====== Final projection GEMM: BM=128 x BN=256 (round-15 proven, frozen) =====
__global__ __launch_bounds__(512, 1) void gemm_p8(
    const unsigned short* __restrict__ A, const unsigned short* __restrict__ B,
    float* __restrict__ Cout, const float* __restrict__ bias) {
  __shared__ __align__(16) unsigned short At[2][128 * 64];
  __shared__ __align__(16) unsigned short Bt[2][256 * 64];

  const int tid  = threadIdx.x;
  const int lane = tid & 63;
  const int w    = tid >> 6;
  const int wr   = w >> 2;
  const int wc   = w & 3;
  const int lg   = lane >> 4;
  const int lc   = lane & 15;

  const int bid = blockIdx.x;
  const int xcd = bid & 7;
  const int j   = bid >> 3;
  const int mt  = xcd * 4 + (j >> 3);
  const int nt  = j & 7;
  const int m0 = mt * 128;
  const int n0 = nt * 256;

  const int srow8 = lane >> 3;
  const int sslot = (lane & 7) ^ srow8;
  const int NT = EMB / 64;

  auto stageA = [&](int ts) {
    if (ts >= NT) return;
    int buf = ts & 1, k0 = ts * 64;
#pragma unroll
    for (int rr = 0; rr < 2; ++rr) {
      int c = w + rr * 8;
      int row = c * 8 + srow8;
      gload16(A + (size_t)(m0 + row) * EMB + k0 + sslot * 8, (char*)&At[buf][0] + c * 1024);
    }
  };
  auto stageBlow = [&](int ts) {
    if (ts >= NT) return;
    int buf = ts & 1, k0 = ts * 64;
#pragma unroll
    for (int rr = 0; rr < 2; ++rr) {
      int i = w + rr * 8;
      int c = (i >> 2) * 8 + (i & 3);
      int row = c * 8 + srow8;
      gload16(B + (size_t)(n0 + row) * EMB + k0 + sslot * 8, (char*)&Bt[buf][0] + c * 1024);
    }
  };
  auto stageBhigh = [&](int ts) {
    if (ts >= NT) return;
    int buf = ts & 1, k0 = ts * 64;
#pragma unroll
    for (int rr = 0; rr < 2; ++rr) {
      int i = w + rr * 8;
      int c = (i >> 2) * 8 + 4 + (i & 3);
      int row = c * 8 + srow8;
      gload16(B + (size_t)(n0 + row) * EMB + k0 + sslot * 8, (char*)&Bt[buf][0] + c * 1024);
    }
  };

  f32x4 acc[4][4] = {};
  bf16x8 afr[4][2], bfr0[2][2], bfr1[2][2];

  stageA(0); stageBlow(0); stageBhigh(0); stageA(1); stageBlow(1);
  asm volatile("s_waitcnt vmcnt(6)" ::: "memory");
  __builtin_amdgcn_s_barrier();

  for (int t = 0; t < NT; ++t) {
    const char* ab = (const char*)&At[t & 1][0];
    const char* bb = (const char*)&Bt[t & 1][0];

#pragma unroll
    for (int ni = 0; ni < 2; ++ni)
#pragma unroll
      for (int kk = 0; kk < 2; ++kk) {
        int row = wc * 64 + ni * 16 + lc;
        bfr0[ni][kk] = *(const bf16x8*)(bb + row * 128 + ((((kk << 2) | lg) ^ (lc & 7)) << 4));
      }
#pragma unroll
    for (int mi = 0; mi < 4; ++mi)
#pragma unroll
      for (int kk = 0; kk < 2; ++kk) {
        int row = wr * 64 + mi * 16 + lc;
        afr[mi][kk] = *(const bf16x8*)(ab + row * 128 + ((((kk << 2) | lg) ^ (lc & 7)) << 4));
      }
    stageBhigh(t + 1);
    __builtin_amdgcn_s_barrier();
    asm volatile("s_waitcnt lgkmcnt(0)" ::: "memory");
    __builtin_amdgcn_sched_barrier(0);
    __builtin_amdgcn_s_setprio(1);
#pragma unroll
    for (int mi = 0; mi < 4; ++mi)
#pragma unroll
      for (int ni = 0; ni < 2; ++ni)
#pragma unroll
        for (int kk = 0; kk < 2; ++kk)
          acc[mi][ni] = __builtin_amdgcn_mfma_f32_16x16x32_bf16(
              afr[mi][kk], bfr0[ni][kk], acc[mi][ni], 0, 0, 0);
    __builtin_amdgcn_s_setprio(0);
    if (t + 1 < NT) asm volatile("s_waitcnt vmcnt(6)" ::: "memory");
    else            asm volatile("s_waitcnt vmcnt(0)" ::: "memory");
    __builtin_amdgcn_s_barrier();

#pragma unroll
    for (int ni = 0; ni < 2; ++ni)
#pragma unroll
      for (int kk = 0; kk < 2; ++kk) {
        int row = wc * 64 + 32 + ni * 16 + lc;
        bfr1[ni][kk] = *(const bf16x8*)(bb + row * 128 + ((((kk << 2) | lg) ^ (lc & 7)) << 4));
      }
    stageA(t + 2); stageBlow(t + 2);
    __builtin_amdgcn_s_barrier();
    asm volatile("s_waitcnt lgkmcnt(0)" ::: "memory");
    __builtin_amdgcn_sched_barrier(0);
    __builtin_amdgcn_s_setprio(1);
#pragma unroll
    for (int mi = 0; mi < 4; ++mi)
#pragma unroll
      for (int ni = 0; ni < 2; ++ni)
#pragma unroll
        for (int kk = 0; kk < 2; ++kk)
          acc[mi][2 + ni] = __builtin_amdgcn_mfma_f32_16x16x32_bf16(
              afr[mi][kk], bfr1[ni][kk], acc[mi][2 + ni], 0, 0, 0);
    __builtin_amdgcn_s_setprio(0);
    if (t + 2 < NT)      asm volatile("s_waitcnt vmcnt(6)" ::: "memory");
    else if (t + 1 < NT) asm volatile("s_waitcnt vmcnt(2)" ::: "memory");
    __builtin_amdgcn_s_barrier();
  }

#pragma unroll
  for (int mi = 0; mi < 4; ++mi)
#pragma unroll
    for (int ni = 0; ni < 4; ++ni) {
      int col = n0 + wc * 64 + ((ni >> 1) * 32) + (ni & 1) * 16 + lc;
#pragma unroll
      for (int rr = 0; rr < 4; ++rr) {
        int row = m0 + wr * 64 + mi * 16 + lg * 4 + rr;
        Cout[(size_t)row * EMB + col] = acc[mi][ni][rr] + bias[col];
      }
    }
}

// ====== Causal flash attention: swapped-QK, KVBLK=64 DOUBLE-BUFFERED with
// counted-vmcnt pipeline (the GEMM rounds-13..17 machinery applied to attn).
// LDS = Ks[2][64x128] + Vt[2][128x64] = 64KB -> 2 blocks/CU.
// Per tile t (invariant at top: in-flight = [V(t+1) 4 loads, K(t+1) 4 DMA]):
//   vmcnt(4) -> retire V(t+1); packV(t+1) into buf^1 (readers done a barrier
//   ago); issue loadV(t+2); compute(t); issue stageK(t+2) into buf (same-
//   parity; compute's reads done); lgkmcnt(0); vmcnt(8) retires K(t+1) ONLY
//   (V/K(t+2) stay in flight -- T4, never a mid-loop drain); raw s_barrier.
// Rounds 4/6 dbuf failed via __syncthreads full-drain + spill; this uses raw
// barriers + counted vmcnt. VGPR: 108 + vr[4]=16 -> ~124 <= 128 cap (256,2).
__global__ __launch_bounds__(256, 2) void attn_causal(
    const unsigned short* __restrict__ Pq, const unsigned short* __restrict__ Pk,
    const unsigned short* __restrict__ Pv, unsigned short* __restrict__ ctx) {
  __shared__ __align__(16) unsigned short Ks[2][64 * 128];   // swizzled
  __shared__ __align__(16) unsigned short Vt[2][128 * 64];   // swizzled

  const int tid  = threadIdx.x;
  const int lane = tid & 63;
  const int w    = tid >> 6;
  const int ql   = lane & 31;
  const int hi   = lane >> 5;
  const int lg   = lane >> 4;
  const int lc   = lane & 15;

  // head-grouped XCD decode (round-8 proven)
  const int bid = blockIdx.x;
  const int xcd = bid & 7;
  const int jj_ = bid >> 3;
  const int hh  = jj_ >> 4;
  const int bh  = xcd * 4 + hh;
  const int b   = bh >> 4;
  const int h   = bh & 15;
  const int qtr = jj_ & 15;
  const int qt  = (hh >= 2) ? (15 - qtr) : qtr;
  const int q0 = qt * 128;
  const int qw = q0 + w * 32;
  const int qg = qw + ql;

  const size_t hoff = (size_t)bh * SEQ * HDIM;
  const unsigned short* Q  = Pq + hoff;
  const unsigned short* Kh = Pk + hoff;
  const unsigned short* Vh = Pv + hoff;

  bf16x8 bq[8];
#pragma unroll
  for (int d8 = 0; d8 < 8; ++d8)
    bq[d8] = *(const bf16x8*)(Q + (size_t)qg * HDIM + d8 * 16 + hi * 8);

  const float NEG = -3.0e38f;
  f32x16 o[4];
#pragma unroll
  for (int dt = 0; dt < 4; ++dt)
#pragma unroll
    for (int r = 0; r < 16; ++r) o[dt][r] = 0.f;
  float m_r = NEG, l_r = 0.f;

  const float Cs   = 0.12753123161692858f;
  const float TDEF = 62.7f;

  auto stageK = [&](int buf, int t) {     // 16 chunks of 1KB (4 rows x 256B)
    int kv0 = t * 64;
#pragma unroll
    for (int ii = 0; ii < 4; ++ii) {
      int i = w * 4 + ii;
      int r = i * 4 + lg;
      int sd = lc ^ (r & 7);
      gload16(Kh + (size_t)(kv0 + r) * HDIM + sd * 8, (char*)&Ks[buf][0] + i * 1024);
    }
  };
  auto loadV = [&](uint4* vr, int t) {    // 4 x 16B loads per thread
    int kv0 = t * 64;
#pragma unroll
    for (int uu = 0; uu < 2; ++uu) {
      int u = tid + uu * 256;
      int kp = u >> 4, dg = u & 15;
      int k = kp * 2, d0 = dg * 8;
      vr[uu * 2]     = *(const uint4*)(Vh + (size_t)(kv0 + k) * HDIM + d0);
      vr[uu * 2 + 1] = *(const uint4*)(Vh + (size_t)(kv0 + k + 1) * HDIM + d0);
    }
  };
  auto packV = [&](int buf, const uint4* vr) {
#pragma unroll
    for (int uu = 0; uu < 2; ++uu) {
      int u = tid + uu * 256;
      int kp = u >> 4, dg = u & 15;
      int k = kp * 2, d0 = dg * 8;
      const unsigned short* e0 = (const unsigned short*)&vr[uu * 2];
      const unsigned short* e1 = (const unsigned short*)&vr[uu * 2 + 1];
#pragma unroll
      for (int jj = 0; jj < 8; ++jj) {    // STATIC index only (round-2 lesson)
        int d = d0 + jj;
        int slot = (k >> 3) ^ jj ^ (dg & 7);
        int byteoff = d * 128 + (slot << 4) + (k & 7) * 2;
        *(unsigned int*)((char*)&Vt[buf][0] + byteoff) =
            (unsigned int)e0[jj] | ((unsigned int)e1[jj] << 16);
      }
    }
  };

  const int ntiles = 2 * qt + 2;   // 64-kv tiles (>=2)
  uint4 vr[4];

  // prologue: V0,K0 issued; retire V0; pack; issue V1,K1; retire K0; barrier
  loadV(vr, 0); stageK(0, 0);
  asm volatile("s_waitcnt vmcnt(4)" ::: "memory");
  packV(0, vr);
  loadV(vr, 1); stageK(1, 1);            // ntiles >= 2 always
  asm volatile("s_waitcnt vmcnt(8)" ::: "memory");
  asm volatile("s_waitcnt lgkmcnt(0)" ::: "memory");
  __builtin_amdgcn_s_barrier();

  for (int t = 0; t < ntiles; ++t) {
    const int buf = t & 1;
    const bool hasN1 = (t + 1 < ntiles);
    const bool hasN2 = (t + 2 < ntiles);
    const int kv0 = t * 64;

    if (hasN1) {
      asm volatile("s_waitcnt vmcnt(4)" ::: "memory");  // retire V(t+1) loads
      packV(buf ^ 1, vr);
      if (hasN2) loadV(vr, t + 2);
    }

    if (kv0 <= qw + 31) {                 // wave-uniform tile skip
      const bool s1on = (kv0 + 32 <= qw + 31);
      const bool diag = (kv0 + 63 > qw);
      const char* ksb = (const char*)&Ks[buf][0];
      const char* vtb = (const char*)&Vt[buf][0];

      f32x16 c0, c1;
#pragma unroll
      for (int r = 0; r < 16; ++r) { c0[r] = 0.f; c1[r] = s1on ? 0.f : NEG; }
      __builtin_amdgcn_s_setprio(1);
#pragma unroll
      for (int d8 = 0; d8 < 8; ++d8) {
        bf16x8 ak = *(const bf16x8*)(ksb + ql * 256 +
                                     (((d8 * 2 + hi) ^ (ql & 7)) << 4));
        c0 = __builtin_amdgcn_mfma_f32_32x32x16_bf16(ak, bq[d8], c0, 0, 0, 0);
      }
      if (s1on) {
#pragma unroll
        for (int d8 = 0; d8 < 8; ++d8) {
          bf16x8 ak = *(const bf16x8*)(ksb + (32 + ql) * 256 +
                                       (((d8 * 2 + hi) ^ (ql & 7)) << 4));
          c1 = __builtin_amdgcn_mfma_f32_32x32x16_bf16(ak, bq[d8], c1, 0, 0, 0);
        }
      }
      __builtin_amdgcn_s_setprio(0);

      if (diag) {
#pragma unroll
        for (int r = 0; r < 16; ++r) {
          int kvl = (r & 3) + 8 * (r >> 2) + 4 * hi;
          if (kv0 + kvl > qg) c0[r] = NEG;
          if (s1on && kv0 + 32 + kvl > qg) c1[r] = NEG;
        }
      }
      float rm;
      {
        float a0 = max3f(c0[0],  c0[1],  c0[2]);
        float a1 = max3f(c0[3],  c0[4],  c0[5]);
        float a2 = max3f(c0[6],  c0[7],  c0[8]);
        float a3 = max3f(c0[9],  c0[10], c0[11]);
        float a4 = max3f(c0[12], c0[13], c0[14]);
        float a5 = max3f(c0[15], c1[0],  c1[1]);
        float a6 = max3f(c1[2],  c1[3],  c1[4]);
        float a7 = max3f(c1[5],  c1[6],  c1[7]);
        float a8 = max3f(c1[8],  c1[9],  c1[10]);
        float a9 = max3f(c1[11], c1[12], c1[13]);
        float aa = fmaxf(c1[14], c1[15]);
        float b0 = max3f(a0, a1, a2);
        float b1 = max3f(a3, a4, a5);
        float b2 = max3f(a6, a7, a8);
        float b3 = max3f(a9, aa, NEG);
        rm = fmaxf(fmaxf(b0, b1), fmaxf(b2, b3));
      }
      rm = fmaxf(rm, __shfl_xor(rm, 32));

      if (__any(rm > m_r + TDEF)) {       // T13 defer-max
        float mnew = fmaxf(m_r, rm);
        float alpha = exp2f((m_r - mnew) * Cs);
        m_r = mnew;
        l_r *= alpha;
#pragma unroll
        for (int r = 0; r < 16; ++r) {
          float ar = __shfl(alpha, (r & 3) + 8 * (r >> 2) + 4 * hi);
#pragma unroll
          for (int dt = 0; dt < 4; ++dt) o[dt][r] *= ar;
        }
      }
#pragma unroll
      for (int r = 0; r < 16; ++r) {
        c0[r] = exp2f((c0[r] - m_r) * Cs);
        c1[r] = exp2f((c1[r] - m_r) * Cs);
      }
      float ps = 0.f;
#pragma unroll
      for (int r = 0; r < 16; ++r) ps += c0[r] + c1[r];
      ps += __shfl_xor(ps, 32);
      l_r += ps;

      bf16x8 pa[4];
#pragma unroll
      for (int t4 = 0; t4 < 4; ++t4) {
        const f32x16& cc = (t4 < 2) ? c0 : c1;
        const int rA = (t4 & 1) * 8;
        unsigned int pkL0 = pk2(cc[rA + 0], cc[rA + 1]);
        unsigned int pkL1 = pk2(cc[rA + 2], cc[rA + 3]);
        unsigned int pkH0 = pk2(cc[rA + 4], cc[rA + 5]);
        unsigned int pkH1 = pk2(cc[rA + 6], cc[rA + 7]);
        unsigned int give0 = hi ? pkL0 : pkH0;
        unsigned int give1 = hi ? pkL1 : pkH1;
        unsigned int keep0 = hi ? pkH0 : pkL0;
        unsigned int keep1 = hi ? pkH1 : pkL1;
        unsigned int recv0 = __shfl_xor(give0, 32);
        unsigned int recv1 = __shfl_xor(give1, 32);
        union { unsigned int u[4]; bf16x8 v; } pu;
        pu.u[0] = hi ? recv0 : keep0;
        pu.u[1] = hi ? recv1 : keep1;
        pu.u[2] = hi ? keep0 : recv0;
        pu.u[3] = hi ? keep1 : recv1;
        pa[t4] = pu.v;
      }
      __builtin_amdgcn_s_setprio(1);
#pragma unroll
      for (int t4 = 0; t4 < 4; ++t4) {
        if (diag && kv0 + t4 * 16 > qw + 31) continue;
#pragma unroll
        for (int dt = 0; dt < 4; ++dt) {
          int d = dt * 32 + ql;
          int slot = ((t4 << 1) | hi) ^ (d & 7) ^ ((d >> 3) & 7);
          bf16x8 bv = *(const bf16x8*)(vtb + d * 128 + (slot << 4));
          o[dt] = __builtin_amdgcn_mfma_f32_32x32x16_bf16(pa[t4], bv, o[dt], 0, 0, 0);
        }
      }
      __builtin_amdgcn_s_setprio(0);
    }

    if (hasN2) stageK(buf, t + 2);        // same-parity buf; reads of t done
    asm volatile("s_waitcnt lgkmcnt(0)" ::: "memory");
    if (hasN1) {
      if (hasN2) asm volatile("s_waitcnt vmcnt(8)" ::: "memory");  // retire K(t+1)
      else       asm volatile("s_waitcnt vmcnt(0)" ::: "memory");
    }
    __builtin_amdgcn_s_barrier();
  }

  float linv = 1.0f / l_r;
  unsigned short* outp = ctx + (size_t)b * SEQ * EMB + (size_t)h * HDIM;
#pragma unroll
  for (int r = 0; r < 16; ++r) {
    int kvl = (r & 3) + 8 * (r >> 2) + 4 * hi;
    float lr = __shfl(linv, kvl);
    int qrow = qw + kvl;
#pragma unroll
    for (int dt = 0; dt < 4; ++dt)
      outp[(size_t)qrow * EMB + dt * 32 + ql] = f2bf(o[dt][r] * lr);
  }
}

extern "C" void kernel_launch(void* const* d_in, const int* in_sizes, int n_in,
                              void* d_out, int out_size, void* d_ws, size_t ws_size,
                              hipStream_t stream) {
  const float* x  = (const float*)d_in[0];
  const float* Wq = (const float*)d_in[1];
  const float* Wk = (const float*)d_in[2];
  const float* Wv = (const float*)d_in[3];
  const float* Wp = (const float*)d_in[4];
  const float* bp = (const float*)d_in[5];

  char* ws = (char*)d_ws;
  unsigned short* xb = (unsigned short*)ws;                         // 16MB, reused as ctx
  unsigned short* Wb = (unsigned short*)(ws + (size_t)(16u << 20)); // 8MB (Wp bf16)
  unsigned short* Pq = (unsigned short*)(ws + (size_t)(24u << 20)); // 3x16MB contiguous
  unsigned short* Pk = (unsigned short*)(ws + (size_t)(40u << 20));
  unsigned short* Pv = (unsigned short*)(ws + (size_t)(56u << 20));
  // d_out (32MB fp32) fully rewritten by final GEMM -> first 24MB holds the
  // CONTIGUOUS [Wq;Wk;Wv] bf16 B matrix during the QKV phase.
  unsigned short* WB3 = (unsigned short*)d_out;

  const int nX4 = ROWSM * EMB / 4;
  const int nW4 = EMB * EMB / 4;

  // single conversion launch (x + 3 QKV weights + Wp)
  cvt_all<<<dim3(nX4 / 256, 1, 5), 256, 0, stream>>>(
      x, Wq, Wk, Wv, Wp, xb, WB3, Wb, nX4, nW4);

  // QKV fused: M=4096, N=6144, 256x192 tiles -> 512 blocks = 2 exact rounds
  gemm192_qkv<<<512, 512, 0, stream>>>(xb, WB3, Pq);

  attn_causal<<<512, 256, 0, stream>>>(Pq, Pk, Pv, xb);

  // P: 256 blocks = 1 exact round
  gemm_p8<<<256, 512, 0, stream>>>(xb, Wb, (float*)d_out, bp);
}